// Round 4
// baseline (6346.967 us; speedup 1.0000x reference)
//
#include <hip/hip_runtime.h>
#include <math.h>

namespace {

typedef unsigned short u16;
typedef __attribute__((ext_vector_type(8))) short bf16x8;   // 8 bf16 = 4 VGPRs
typedef __attribute__((ext_vector_type(4))) float f32x4;
typedef __attribute__((ext_vector_type(8))) _Float16 f16x8;

constexpr int B = 32;
constexpr int M = 600;
constexpr int H = 256;
constexpr int TSTEPS = 4;
constexpr int HP = 4096;          // H*P
constexpr int BM = B * M;         // 19200
constexpr int TWOH = 512;
constexpr int THREEH = 768;
constexpr int FOURH = 1024;
constexpr int FIVEH = 1280;

__device__ __forceinline__ float sigf(float x) { return 1.0f / (1.0f + expf(-x)); }

// ---- bf16 helpers (bit-level, RTN) ----
__device__ __forceinline__ u16 bf16rtn(float x) {
    unsigned u = __float_as_uint(x);
    unsigned r = (u + 0x7FFFu + ((u >> 16) & 1u)) >> 16;
    return (u16)r;
}
__device__ __forceinline__ float fromb(u16 h) {
    return __uint_as_float(((unsigned)h) << 16);
}

__device__ __forceinline__ void gload16(const u16* g, u16* l) {
    __builtin_amdgcn_global_load_lds(
        (const __attribute__((address_space(1))) void*)g,
        (__attribute__((address_space(3))) void*)l, 16, 0, 0);
}

// ---------------- init ----------------
__global__ void k_init(const int* __restrict__ d_mask,
                       float* __restrict__ h, float* __restrict__ c,
                       float* __restrict__ loss_vec,
                       int* __restrict__ s_i, int* __restrict__ e_i,
                       int* __restrict__ p1r, int* __restrict__ p2r)
{
    int tid = threadIdx.x;
    for (int i = tid; i < B * H; i += 256) { h[i] = 0.f; c[i] = 0.f; }
    if (tid < B) {
        loss_vec[tid] = 0.f;
        s_i[tid] = 0;
        int s = 0;
        const int* row = d_mask + tid * M;
        for (int m = 0; m < M; ++m) s += row[m];
        e_i[tid] = s - 1;
        p1r[tid] = 0; p2r[tid] = 0;
    }
}

// ---------------- gather u_cat = [U[b, s_i], U[b, e_i]] ----------------
__global__ __launch_bounds__(256) void k_gather(
    const float* __restrict__ U, const int* __restrict__ s_i,
    const int* __restrict__ e_i, float* __restrict__ u_cat)
{
    int idx = blockIdx.x * 256 + threadIdx.x;   // B*512 threads
    int b = idx >> 9, k = idx & 511;
    u_cat[b * FOURH + k]       = U[((size_t)b * M + s_i[b]) * TWOH + k];
    u_cat[b * FOURH + 512 + k] = U[((size_t)b * M + e_i[b]) * TWOH + k];
}

// ---------------- LSTM ----------------
__global__ __launch_bounds__(256) void k_lstm_gemm(
    const float* __restrict__ u_cat, const float* __restrict__ h,
    const float* __restrict__ W_ih, const float* __restrict__ W_hh,
    const float* __restrict__ b_ih, const float* __restrict__ b_hh,
    float* __restrict__ g)
{
    int idx = blockIdx.x * 256 + threadIdx.x;   // B*1024 threads
    int b = idx >> 10, j = idx & 1023;
    float acc = 0.f;
    const float4* x4 = (const float4*)(u_cat + b * FOURH);
    const float4* wi4 = (const float4*)(W_ih + (size_t)j * FOURH);
    #pragma unroll 4
    for (int k = 0; k < FOURH / 4; ++k) {
        float4 a = x4[k], w = wi4[k];
        acc += a.x * w.x + a.y * w.y + a.z * w.z + a.w * w.w;
    }
    const float4* h4 = (const float4*)(h + b * H);
    const float4* wh4 = (const float4*)(W_hh + (size_t)j * H);
    #pragma unroll 4
    for (int k = 0; k < H / 4; ++k) {
        float4 a = h4[k], w = wh4[k];
        acc += a.x * w.x + a.y * w.y + a.z * w.z + a.w * w.w;
    }
    g[idx] = acc + b_ih[j] + b_hh[j];
}

__global__ __launch_bounds__(256) void k_lstm_gates(
    const float* __restrict__ g, float* __restrict__ h, float* __restrict__ c)
{
    int idx = blockIdx.x * 256 + threadIdx.x;   // B*H
    int b = idx >> 8, i = idx & (H - 1);
    const float* gr = g + b * FOURH;
    float gi = gr[i], gf = gr[H + i], gg = gr[2 * H + i], go = gr[3 * H + i];
    float cn = sigf(gf) * c[idx] + sigf(gi) * tanhf(gg);
    c[idx] = cn;
    h[idx] = sigf(go) * tanhf(cn);
}

// ---------------- r = tanh(concat([h, u_cat]) @ W_lin.T) ----------------
__global__ __launch_bounds__(256) void k_r(
    const float* __restrict__ h, const float* __restrict__ u_cat,
    const float* __restrict__ W_lin, float* __restrict__ r)
{
    int idx = blockIdx.x * 256 + threadIdx.x;   // B*H
    int b = idx >> 8, i = idx & (H - 1);
    const float* w = W_lin + (size_t)i * FIVEH;
    float acc = 0.f;
    const float4* h4 = (const float4*)(h + b * H);
    const float4* w4 = (const float4*)w;
    #pragma unroll 4
    for (int k = 0; k < H / 4; ++k) {
        float4 a = h4[k], ww = w4[k];
        acc += a.x * ww.x + a.y * ww.y + a.z * ww.z + a.w * ww.w;
    }
    const float4* x4 = (const float4*)(u_cat + b * FOURH);
    const float4* w4b = (const float4*)(w + H);
    #pragma unroll 4
    for (int k = 0; k < FOURH / 4; ++k) {
        float4 a = x4[k], ww = w4b[k];
        acc += a.x * ww.x + a.y * ww.y + a.z * ww.z + a.w * ww.w;
    }
    r[idx] = tanhf(acc);
}

// ---------------- old strided rW (tier 3) ----------------
__global__ __launch_bounds__(256) void k_rW(
    const float* __restrict__ r, const float* __restrict__ W1,
    const float* __restrict__ b1, float* __restrict__ rW)
{
    int idx = blockIdx.x * 256 + threadIdx.x;   // B*HP
    int b = idx >> 12, j = idx & (HP - 1);
    const float4* r4 = (const float4*)(r + b * H);
    const float4* w4 = (const float4*)(W1 + (size_t)j * THREEH + TWOH);
    float acc = 0.f;
    #pragma unroll 4
    for (int k = 0; k < H / 4; ++k) {
        float4 a = r4[k], w = w4[k];
        acc += a.x * w.x + a.y * w.y + a.z * w.z + a.w * w.w;
    }
    rW[idx] = acc + b1[j];
}

// ---------------- coalesced rW via transposed weight (tiers 1/2) ----------------
__global__ __launch_bounds__(256) void k_rW2(
    const float* __restrict__ r, const float* __restrict__ Wt,
    const float* __restrict__ b1, float* __restrict__ rW)
{
    const int b = blockIdx.y;
    const int j = blockIdx.x * 256 + threadIdx.x;
    __shared__ float sr[256];
    sr[threadIdx.x] = r[b * H + threadIdx.x];
    __syncthreads();
    float acc = b1[j];
    #pragma unroll 4
    for (int k = 0; k < H; ++k) acc += sr[k] * Wt[(size_t)k * HP + j];
    rW[(size_t)b * HP + j] = acc;
}

// ---------------- transpose W1[:, 512:768] -> Wt[256][4096] ----------------
__global__ __launch_bounds__(256) void k_transp(
    const float* __restrict__ W, float* __restrict__ Wt)
{
    int idx = blockIdx.x * 256 + threadIdx.x;   // HP*H
    int k = idx >> 12, j = idx & (HP - 1);
    Wt[idx] = W[(size_t)j * THREEH + TWOH + k];
}

// ---------------- fp32 -> bf16 hi/lo split converter ----------------
__global__ __launch_bounds__(256) void k_cvt(
    const float* __restrict__ src, int ld, int Kc,
    u16* __restrict__ dh, u16* __restrict__ dl)
{
    int i4 = blockIdx.x * 256 + threadIdx.x;    // over N*Kc/4
    int perrow = Kc >> 2;
    int row = i4 / perrow;
    int kc = (i4 - row * perrow) << 2;
    float4 v = *(const float4*)(src + (size_t)row * ld + kc);
    u16 h0 = bf16rtn(v.x), h1 = bf16rtn(v.y), h2 = bf16rtn(v.z), h3 = bf16rtn(v.w);
    u16 l0 = bf16rtn(v.x - fromb(h0)), l1 = bf16rtn(v.y - fromb(h1));
    u16 l2 = bf16rtn(v.z - fromb(h2)), l3 = bf16rtn(v.w - fromb(h3));
    ushort4 hv = make_ushort4(h0, h1, h2, h3);
    ushort4 lv = make_ushort4(l0, l1, l2, l3);
    *(ushort4*)(dh + (size_t)row * Kc + kc) = hv;
    *(ushort4*)(dl + (size_t)row * Kc + kc) = lv;
}

// ---------------- split-bf16 x3 MFMA GEMM: C = A @ B^T ----------------
// Tile 128x128, BK=32. A:[rows x K] hi/lo bf16; B:[N x K] hi/lo bf16.
// EPI=1: +bias[col], max over 16-col groups -> Cf [rows x 256] fp32      (m2)
// EPI=3: +rW[row/M][col], max over 16-col groups -> Ch/Cl bf16 [rows x 256] (m1, tier2)
// EPI=4: store fp16 C [rows x 4096] into (Ch as _Float16*)               (tier-1.5 precompute)
template <int EPI>
__global__ __launch_bounds__(256) void gemmMF(
    const u16* __restrict__ Ah, const u16* __restrict__ Al,
    const u16* __restrict__ Bh, const u16* __restrict__ Bl,
    int K, const float* __restrict__ extra,
    float* __restrict__ Cf, u16* __restrict__ Ch, u16* __restrict__ Cl)
{
    __shared__ __align__(16) u16 sAh[128 * 32];
    __shared__ __align__(16) u16 sAl[128 * 32];
    __shared__ __align__(16) u16 sBh[128 * 32];
    __shared__ __align__(16) u16 sBl[128 * 32];
    const int tid = threadIdx.x;
    const int w = tid >> 6, lane = tid & 63;
    const int row0 = blockIdx.y * 128, col0 = blockIdx.x * 128;
    const int wm = w & 1, wn = w >> 1;
    const int rt0 = w * 32;
    const int lrow = lane >> 2;
    const int lk = (lane & 3) << 3;

    f32x4 acc[4][4] = {};

    for (int k0 = 0; k0 < K; k0 += 32) {
        __syncthreads();
        #pragma unroll
        for (int c = 0; c < 2; ++c) {
            const int rt = rt0 + c * 16 + lrow;
            const size_t ga = (size_t)(row0 + rt) * K + k0 + lk;
            const size_t gb = (size_t)(col0 + rt) * K + k0 + lk;
            u16* la = &sAh[(rt0 + c * 16) * 32];
            u16* lb = &sAl[(rt0 + c * 16) * 32];
            u16* lc = &sBh[(rt0 + c * 16) * 32];
            u16* ld = &sBl[(rt0 + c * 16) * 32];
            gload16(Ah + ga, la);
            gload16(Al + ga, lb);
            gload16(Bh + gb, lc);
            gload16(Bl + gb, ld);
        }
        __syncthreads();
        bf16x8 fah[4], fal[4], fbh[4], fbl[4];
        const int ko = (lane >> 4) << 3;
        #pragma unroll
        for (int f = 0; f < 4; ++f) {
            int ra = (wm * 64 + f * 16 + (lane & 15)) * 32 + ko;
            int rb = (wn * 64 + f * 16 + (lane & 15)) * 32 + ko;
            fah[f] = *(const bf16x8*)&sAh[ra];
            fal[f] = *(const bf16x8*)&sAl[ra];
            fbh[f] = *(const bf16x8*)&sBh[rb];
            fbl[f] = *(const bf16x8*)&sBl[rb];
        }
        #pragma unroll
        for (int i = 0; i < 4; ++i) {
            #pragma unroll
            for (int j = 0; j < 4; ++j) {
                acc[i][j] = __builtin_amdgcn_mfma_f32_16x16x32_bf16(fah[i], fbh[j], acc[i][j], 0, 0, 0);
                acc[i][j] = __builtin_amdgcn_mfma_f32_16x16x32_bf16(fah[i], fbl[j], acc[i][j], 0, 0, 0);
                acc[i][j] = __builtin_amdgcn_mfma_f32_16x16x32_bf16(fal[i], fbh[j], acc[i][j], 0, 0, 0);
            }
        }
    }

    // epilogue — C/D layout: col = lane&15, row = (lane>>4)*4 + reg
    const int cq = lane & 15, rq = lane >> 4;
    if (EPI == 4) {
        _Float16* C16 = (_Float16*)Ch;
        #pragma unroll
        for (int i = 0; i < 4; ++i) {
            #pragma unroll
            for (int j = 0; j < 4; ++j) {
                int col = col0 + wn * 64 + j * 16 + cq;
                #pragma unroll
                for (int rr = 0; rr < 4; ++rr) {
                    int row = row0 + wm * 64 + i * 16 + rq * 4 + rr;
                    C16[(size_t)row * HP + col] = (_Float16)acc[i][j][rr];
                }
            }
        }
    } else if (EPI == 1) {
        #pragma unroll
        for (int j = 0; j < 4; ++j) {
            int col = col0 + wn * 64 + j * 16 + cq;
            int gcol = (col0 >> 4) + wn * 4 + j;
            float bv = extra[col];
            #pragma unroll
            for (int i = 0; i < 4; ++i) {
                #pragma unroll
                for (int rr = 0; rr < 4; ++rr) {
                    float v = acc[i][j][rr] + bv;
                    v = fmaxf(v, __shfl_xor(v, 1));
                    v = fmaxf(v, __shfl_xor(v, 2));
                    v = fmaxf(v, __shfl_xor(v, 4));
                    v = fmaxf(v, __shfl_xor(v, 8));
                    if (cq == 0) {
                        int row = row0 + wm * 64 + i * 16 + rq * 4 + rr;
                        Cf[(size_t)row * H + gcol] = v;
                    }
                }
            }
        }
    } else {  // EPI == 3
        #pragma unroll
        for (int j = 0; j < 4; ++j) {
            int col = col0 + wn * 64 + j * 16 + cq;
            int gcol = (col0 >> 4) + wn * 4 + j;
            #pragma unroll
            for (int i = 0; i < 4; ++i) {
                #pragma unroll
                for (int rr = 0; rr < 4; ++rr) {
                    int row = row0 + wm * 64 + i * 16 + rq * 4 + rr;
                    int b = row / M;
                    float v = acc[i][j][rr] + extra[(size_t)b * HP + col];
                    v = fmaxf(v, __shfl_xor(v, 1));
                    v = fmaxf(v, __shfl_xor(v, 2));
                    v = fmaxf(v, __shfl_xor(v, 4));
                    v = fmaxf(v, __shfl_xor(v, 8));
                    if (cq == 0) {
                        u16 hv = bf16rtn(v);
                        u16 lv = bf16rtn(v - fromb(hv));
                        Ch[(size_t)row * H + gcol] = hv;
                        Cl[(size_t)row * H + gcol] = lv;
                    }
                }
            }
        }
    }
}

// ---------------- tier 1.5: m1 = max16(A_f16 + rW), split to bf16 hi/lo ------------
__global__ __launch_bounds__(256) void k_m1A16(
    const _Float16* __restrict__ A, const float* __restrict__ rW,
    u16* __restrict__ m1h, u16* __restrict__ m1l)
{
    int idx = blockIdx.x * 256 + threadIdx.x;   // bm*H + h
    int bm = idx >> 8;
    int h = idx & (H - 1);
    int b = bm / M;
    const f16x8* a8 = (const f16x8*)(A + (size_t)bm * HP + (h << 4));
    const float4* r4 = (const float4*)(rW + (size_t)b * HP + (h << 4));
    f16x8 a0 = a8[0], a1 = a8[1];
    float mx = -INFINITY;
    #pragma unroll
    for (int q = 0; q < 2; ++q) {
        float4 r = r4[q];
        f16x8& a = q ? a1 : a0;
        mx = fmaxf(mx, fmaxf(fmaxf((float)a[0] + r.x, (float)a[1] + r.y),
                             fmaxf((float)a[2] + r.z, (float)a[3] + r.w)));
        float4 r2 = r4[q * 2 + 1];
        (void)r2;
    }
    // careful: 16 values = 2 f16x8, 4 float4. unrolled explicitly:
    {
        float4 ra = r4[0], rb = r4[1], rc = r4[2], rd = r4[3];
        mx = fmaxf(fmaxf(fmaxf((float)a0[0] + ra.x, (float)a0[1] + ra.y),
                         fmaxf((float)a0[2] + ra.z, (float)a0[3] + ra.w)),
             fmaxf(fmaxf((float)a0[4] + rb.x, (float)a0[5] + rb.y),
                   fmaxf((float)a0[6] + rb.z, (float)a0[7] + rb.w)));
        mx = fmaxf(mx,
             fmaxf(fmaxf(fmaxf((float)a1[0] + rc.x, (float)a1[1] + rc.y),
                         fmaxf((float)a1[2] + rc.z, (float)a1[3] + rc.w)),
                   fmaxf(fmaxf((float)a1[4] + rd.x, (float)a1[5] + rd.y),
                         fmaxf((float)a1[6] + rd.z, (float)a1[7] + rd.w))));
    }
    u16 hv = bf16rtn(mx);
    m1h[idx] = hv;
    m1l[idx] = bf16rtn(mx - fromb(hv));
}

// ---------------- tier 3 fp32 GEMM (round-2, known-pass) ----------------
template <int EPI>
__global__ __launch_bounds__(256) void gemm64(
    const float* __restrict__ Ag, int lda,
    const float* __restrict__ Bg, int ldb,
    const float* __restrict__ extra,
    float* __restrict__ C, int K, int ldc)
{
    __shared__ float As[16][68];
    __shared__ float Bs[16][68];
    const int tid = threadIdx.x;
    const int tx = tid & 15;
    const int ty = tid >> 4;
    const int row0 = blockIdx.y * 64;
    const int col0 = blockIdx.x * 64;
    const int lr = tid >> 2;
    const int lk = (tid & 3) << 2;
    const float* Aload = Ag + (size_t)(row0 + lr) * lda + lk;
    const float* Bload = Bg + (size_t)(col0 + lr) * ldb + lk;
    float acc[4][4] = {};
    for (int k0 = 0; k0 < K; k0 += 16) {
        float4 av = *(const float4*)(Aload + k0);
        float4 bv = *(const float4*)(Bload + k0);
        __syncthreads();
        As[lk + 0][lr] = av.x; As[lk + 1][lr] = av.y; As[lk + 2][lr] = av.z; As[lk + 3][lr] = av.w;
        Bs[lk + 0][lr] = bv.x; Bs[lk + 1][lr] = bv.y; Bs[lk + 2][lr] = bv.z; Bs[lk + 3][lr] = bv.w;
        __syncthreads();
        #pragma unroll
        for (int k = 0; k < 16; ++k) {
            float4 a4 = *(const float4*)(&As[k][ty << 2]);
            float4 b4 = *(const float4*)(&Bs[k][tx << 2]);
            acc[0][0] += a4.x * b4.x; acc[0][1] += a4.x * b4.y; acc[0][2] += a4.x * b4.z; acc[0][3] += a4.x * b4.w;
            acc[1][0] += a4.y * b4.x; acc[1][1] += a4.y * b4.y; acc[1][2] += a4.y * b4.z; acc[1][3] += a4.y * b4.w;
            acc[2][0] += a4.z * b4.x; acc[2][1] += a4.z * b4.y; acc[2][2] += a4.z * b4.z; acc[2][3] += a4.z * b4.w;
            acc[3][0] += a4.w * b4.x; acc[3][1] += a4.w * b4.y; acc[3][2] += a4.w * b4.z; acc[3][3] += a4.w * b4.w;
        }
    }
    if (EPI == 1) {
        const int cb = col0 + (tx << 2);
        float b0 = extra[cb], b1v = extra[cb + 1], b2v = extra[cb + 2], b3v = extra[cb + 3];
        #pragma unroll
        for (int i = 0; i < 4; ++i) {
            float mth = fmaxf(fmaxf(acc[i][0] + b0, acc[i][1] + b1v),
                              fmaxf(acc[i][2] + b2v, acc[i][3] + b3v));
            float r1 = fmaxf(mth, __shfl_xor(mth, 1));
            float r2 = fmaxf(r1, __shfl_xor(r1, 2));
            if ((tx & 3) == 0)
                C[(size_t)(row0 + (ty << 2) + i) * ldc + (col0 >> 4) + (tx >> 2)] = r2;
        }
    } else if (EPI == 2) {
        const int cb = col0 + (tx << 2);
        #pragma unroll
        for (int i = 0; i < 4; ++i) {
            int row = row0 + (ty << 2) + i;
            int b = row / M;
            const float* rw = extra + (size_t)b * HP + cb;
            float mth = fmaxf(fmaxf(acc[i][0] + rw[0], acc[i][1] + rw[1]),
                              fmaxf(acc[i][2] + rw[2], acc[i][3] + rw[3]));
            float r1 = fmaxf(mth, __shfl_xor(mth, 1));
            float r2 = fmaxf(r1, __shfl_xor(r1, 2));
            if ((tx & 3) == 0)
                C[(size_t)row * ldc + (col0 >> 4) + (tx >> 2)] = r2;
        }
    }
}

// ---------------- alpha (tier 3: fp32 m1) ----------------
__global__ __launch_bounds__(256) void k_alpha(
    const float* __restrict__ m1, const float* __restrict__ m2,
    const float* __restrict__ W12, const float* __restrict__ b12,
    const int* __restrict__ d_mask, float* __restrict__ alpha)
{
    __shared__ float Ws[16 * 512];
    const int tid = threadIdx.x;
    for (int i = tid; i < 16 * 512; i += 256) Ws[i] = W12[i];
    __syncthreads();
    const int wave = tid >> 6, lane = tid & 63;
    const int bm = blockIdx.x * 4 + wave;
    const float* r1 = m1 + (size_t)bm * H;
    const float* r2 = m2 + (size_t)bm * H;
    float acc[16] = {};
    #pragma unroll
    for (int q = 0; q < 4; ++q) {
        int k = lane + (q << 6);
        float x = r1[k];
        #pragma unroll
        for (int p = 0; p < 16; ++p) acc[p] += x * Ws[p * 512 + k];
    }
    #pragma unroll
    for (int q = 0; q < 4; ++q) {
        int k = lane + (q << 6);
        float x = r2[k];
        #pragma unroll
        for (int p = 0; p < 16; ++p) acc[p] += x * Ws[p * 512 + 256 + k];
    }
    #pragma unroll
    for (int p = 0; p < 16; ++p) {
        float v = acc[p];
        v += __shfl_xor(v, 1);  v += __shfl_xor(v, 2);  v += __shfl_xor(v, 4);
        v += __shfl_xor(v, 8);  v += __shfl_xor(v, 16); v += __shfl_xor(v, 32);
        acc[p] = v;
    }
    if (lane == 0) {
        float mx = -INFINITY;
        #pragma unroll
        for (int p = 0; p < 16; ++p) mx = fmaxf(mx, acc[p] + b12[p]);
        alpha[bm] = d_mask[bm] ? mx : -1e30f;
    }
}

// ---------------- alpha (tiers 1/2: m1 as bf16 hi/lo) ----------------
__global__ __launch_bounds__(256) void k_alpha2(
    const u16* __restrict__ m1h, const u16* __restrict__ m1l,
    const float* __restrict__ m2,
    const float* __restrict__ W12, const float* __restrict__ b12,
    const int* __restrict__ d_mask, float* __restrict__ alpha)
{
    __shared__ float Ws[16 * 512];
    const int tid = threadIdx.x;
    for (int i = tid; i < 16 * 512; i += 256) Ws[i] = W12[i];
    __syncthreads();
    const int wave = tid >> 6, lane = tid & 63;
    const int bm = blockIdx.x * 4 + wave;
    const u16* h1 = m1h + (size_t)bm * H;
    const u16* l1 = m1l + (size_t)bm * H;
    const float* r2 = m2 + (size_t)bm * H;
    float acc[16] = {};
    #pragma unroll
    for (int q = 0; q < 4; ++q) {
        int k = lane + (q << 6);
        float x = fromb(h1[k]) + fromb(l1[k]);
        #pragma unroll
        for (int p = 0; p < 16; ++p) acc[p] += x * Ws[p * 512 + k];
    }
    #pragma unroll
    for (int q = 0; q < 4; ++q) {
        int k = lane + (q << 6);
        float x = r2[k];
        #pragma unroll
        for (int p = 0; p < 16; ++p) acc[p] += x * Ws[p * 512 + 256 + k];
    }
    #pragma unroll
    for (int p = 0; p < 16; ++p) {
        float v = acc[p];
        v += __shfl_xor(v, 1);  v += __shfl_xor(v, 2);  v += __shfl_xor(v, 4);
        v += __shfl_xor(v, 8);  v += __shfl_xor(v, 16); v += __shfl_xor(v, 32);
        acc[p] = v;
    }
    if (lane == 0) {
        float mx = -INFINITY;
        #pragma unroll
        for (int p = 0; p < 16; ++p) mx = fmaxf(mx, acc[p] + b12[p]);
        alpha[bm] = d_mask[bm] ? mx : -1e30f;
    }
}

// ---------------- per-b: argmax + logsumexp + loss term ----------------
__global__ __launch_bounds__(256) void k_softmax(
    const float* __restrict__ alpha, const int* __restrict__ span, int phase,
    float* __restrict__ loss_term, int* __restrict__ idx_out)
{
    __shared__ float sv[256];
    __shared__ int si[256];
    const int b = blockIdx.x, tid = threadIdx.x;
    const float* row = alpha + b * M;
    float best = -INFINITY; int bidx = 0;
    for (int m = tid; m < M; m += 256) {
        float v = row[m];
        if (v > best) { best = v; bidx = m; }
    }
    sv[tid] = best; si[tid] = bidx;
    __syncthreads();
    for (int s = 128; s > 0; s >>= 1) {
        if (tid < s) {
            float v2 = sv[tid + s]; int i2 = si[tid + s];
            if (v2 > sv[tid] || (v2 == sv[tid] && i2 < si[tid])) { sv[tid] = v2; si[tid] = i2; }
        }
        __syncthreads();
    }
    float bmax = sv[0]; int amax = si[0];
    __syncthreads();
    float ps = 0.f;
    for (int m = tid; m < M; m += 256) ps += expf(row[m] - bmax);
    sv[tid] = ps;
    __syncthreads();
    for (int s = 128; s > 0; s >>= 1) {
        if (tid < s) sv[tid] += sv[tid + s];
        __syncthreads();
    }
    if (tid == 0) {
        float lse = bmax + logf(sv[0]);
        int tgt = span[b * 2 + phase];
        loss_term[b] = -(row[tgt] - lse);
        idx_out[b] = amax;
    }
}

// ---------------- sticky-mask pointer update + loss ----------------
__global__ void k_update(const int* __restrict__ idx_in, const float* __restrict__ loss_term,
                         int* __restrict__ pos, int* __restrict__ mask,
                         int* __restrict__ prun, float* __restrict__ loss_vec, int t)
{
    int b = threadIdx.x;
    int active = (b < B) ? 1 : 0;
    int ni = 0, nm = 0;
    if (active) {
        int id = idx_in[b];
        if (t == 0) { nm = 1; ni = id; }
        else {
            int om = mask[b];
            ni = id * om;
            int prev = pos[b] * om;
            nm = (ni != prev) ? 1 : 0;
        }
    }
    float v = active ? loss_term[b] : 0.f;
    #pragma unroll
    for (int off = 32; off > 0; off >>= 1) v += __shfl_xor(v, off);
    float S = v * (1.0f / (float)B);
    if (active) {
        pos[b] = ni;
        mask[b] = nm;
        if (nm) { prun[b] = ni; loss_vec[b] += S; }
    }
}

// ---------------- finalize ----------------
__global__ void k_finalize(const float* __restrict__ loss_vec, const int* __restrict__ p1r,
                           const int* __restrict__ p2r, float* __restrict__ out)
{
    int b = threadIdx.x;
    float v = (b < B) ? loss_vec[b] : 0.f;
    #pragma unroll
    for (int off = 32; off > 0; off >>= 1) v += __shfl_xor(v, off);
    if (b == 0) out[0] = v / (float)(B * TSTEPS);
    if (b < B) {
        out[1 + b] = (float)p1r[b];
        out[1 + B + b] = (float)p2r[b];
    }
}

}  // namespace

extern "C" void kernel_launch(void* const* d_in, const int* in_sizes, int n_in,
                              void* d_out, int out_size, void* d_ws, size_t ws_size,
                              hipStream_t stream)
{
    const float* U      = (const float*)d_in[0];
    const int*   d_mask = (const int*)d_in[1];
    const int*   span   = (const int*)d_in[2];
    const float* W_ih   = (const float*)d_in[3];
    const float* W_hh   = (const float*)d_in[4];
    const float* b_ih   = (const float*)d_in[5];
    const float* b_hh   = (const float*)d_in[6];
    const float* Ws_lin = (const float*)d_in[7];
    const float* Ws_m1  = (const float*)d_in[8];
    const float* bs_m1  = (const float*)d_in[9];
    const float* Ws_m2  = (const float*)d_in[10];
    const float* bs_m2  = (const float*)d_in[11];
    const float* Ws_m12 = (const float*)d_in[12];
    const float* bs_m12 = (const float*)d_in[13];
    const float* We_lin = (const float*)d_in[14];
    const float* We_m1  = (const float*)d_in[15];
    const float* be_m1  = (const float*)d_in[16];
    const float* We_m2  = (const float*)d_in[17];
    const float* be_m2  = (const float*)d_in[18];
    const float* We_m12 = (const float*)d_in[19];
    const float* be_m12 = (const float*)d_in[20];

    // ---- workspace layout ----
    float* ws = (float*)d_ws;
    size_t o = 0;
    float* m2b   = ws + o; o += (size_t)BM * H;
    float* alphab= ws + o; o += BM;
    float* u_cat = ws + o; o += B * FOURH;
    float* gbuf  = ws + o; o += B * FOURH;
    float* hbuf  = ws + o; o += B * H;
    float* cbuf  = ws + o; o += B * H;
    float* rbuf  = ws + o; o += B * H;
    float* rWb   = ws + o; o += B * HP;
    float* loss_term = ws + o; o += B;
    float* loss_vec  = ws + o; o += B;
    int* ib = (int*)(ws + o); o += 8 * B;
    int* idxb   = ib + 0 * B;
    int* s_i    = ib + 1 * B;
    int* e_i    = ib + 2 * B;
    int* mask_s = ib + 3 * B;
    int* mask_e = ib + 4 * B;
    int* p1r    = ib + 5 * B;
    int* p2r    = ib + 6 * B;
    size_t o_common = (o + 3) & ~(size_t)3;

    // tier 3 (fp32 fallback): m1b fp32
    float* m1b = ws + o_common;

    // tiers 1.5/2: transposed rW weights + bf16 hi/lo region
    size_t p = o_common;
    float* Wt_s = ws + p; p += (size_t)H * HP;
    float* Wt_e = ws + p; p += (size_t)H * HP;
    u16* us = (u16*)(ws + p);
    size_t q = 0;
    u16* Uh   = us + q; q += (size_t)BM * TWOH;
    u16* Ul   = us + q; q += (size_t)BM * TWOH;
    u16* W1sh = us + q; q += (size_t)HP * TWOH;
    u16* W1sl = us + q; q += (size_t)HP * TWOH;
    u16* W1eh = us + q; q += (size_t)HP * TWOH;
    u16* W1el = us + q; q += (size_t)HP * TWOH;
    u16* W2sh = us + q; q += (size_t)HP * H;
    u16* W2sl = us + q; q += (size_t)HP * H;
    u16* W2eh = us + q; q += (size_t)HP * H;
    u16* W2el = us + q; q += (size_t)HP * H;
    u16* m1h  = us + q; q += (size_t)BM * H;
    u16* m1l  = us + q; q += (size_t)BM * H;
    q = (q + 7) & ~(size_t)7;                 // 16B-align what follows
    const size_t need2 = p * sizeof(float) + q * sizeof(u16);
    _Float16* A_s16 = (_Float16*)(us + q);
    _Float16* A_e16 = A_s16 + (size_t)BM * HP;
    const size_t need15 = need2 + 2 * (size_t)BM * HP * sizeof(_Float16);

    const int tier = (ws_size >= need15) ? 15 : (ws_size >= need2) ? 2 : 3;

    k_init<<<1, 256, 0, stream>>>(d_mask, hbuf, cbuf, loss_vec, s_i, e_i, p1r, p2r);

    if (tier <= 15) {
        // rebuild every call (ws re-poisoned by harness)
        k_cvt<<<BM * TWOH / 4 / 256, 256, 0, stream>>>(U, TWOH, TWOH, Uh, Ul);
        k_cvt<<<HP * TWOH / 4 / 256, 256, 0, stream>>>(Ws_m1, THREEH, TWOH, W1sh, W1sl);
        k_cvt<<<HP * TWOH / 4 / 256, 256, 0, stream>>>(We_m1, THREEH, TWOH, W1eh, W1el);
        k_cvt<<<HP * H / 4 / 256, 256, 0, stream>>>(Ws_m2, H, H, W2sh, W2sl);
        k_cvt<<<HP * H / 4 / 256, 256, 0, stream>>>(We_m2, H, H, W2eh, W2el);
        k_transp<<<HP * H / 256, 256, 0, stream>>>(Ws_m1, Wt_s);
        k_transp<<<HP * H / 256, 256, 0, stream>>>(We_m1, Wt_e);

        dim3 g128(HP / 128, BM / 128);  // (32, 150)
        if (tier == 15) {
            // iteration-invariant A = U @ W1u.T, stored fp16 (2x157 MB)
            gemmMF<4><<<g128, 256, 0, stream>>>(Uh, Ul, W1sh, W1sl, TWOH, nullptr, nullptr, (u16*)A_s16, nullptr);
            gemmMF<4><<<g128, 256, 0, stream>>>(Uh, Ul, W1eh, W1el, TWOH, nullptr, nullptr, (u16*)A_e16, nullptr);
        }

        for (int t = 0; t < TSTEPS; ++t) {
            k_gather<<<64, 256, 0, stream>>>(U, s_i, e_i, u_cat);
            k_lstm_gemm<<<128, 256, 0, stream>>>(u_cat, hbuf, W_ih, W_hh, b_ih, b_hh, gbuf);
            k_lstm_gates<<<32, 256, 0, stream>>>(gbuf, hbuf, cbuf);

            // ---- start pointer ----
            k_r<<<32, 256, 0, stream>>>(hbuf, u_cat, Ws_lin, rbuf);
            k_rW2<<<dim3(HP / 256, B), 256, 0, stream>>>(rbuf, Wt_s, bs_m1, rWb);
            if (tier == 15)
                k_m1A16<<<BM * H / 256, 256, 0, stream>>>(A_s16, rWb, m1h, m1l);
            else
                gemmMF<3><<<g128, 256, 0, stream>>>(Uh, Ul, W1sh, W1sl, TWOH, rWb, nullptr, m1h, m1l);
            gemmMF<1><<<g128, 256, 0, stream>>>(m1h, m1l, W2sh, W2sl, H, bs_m2, m2b, nullptr, nullptr);
            k_alpha2<<<BM / 4, 256, 0, stream>>>(m1h, m1l, m2b, Ws_m12, bs_m12, d_mask, alphab);
            k_softmax<<<B, 256, 0, stream>>>(alphab, span, 0, loss_term, idxb);
            k_update<<<1, 64, 0, stream>>>(idxb, loss_term, s_i, mask_s, p1r, loss_vec, t);

            k_gather<<<64, 256, 0, stream>>>(U, s_i, e_i, u_cat);

            // ---- end pointer ----
            k_r<<<32, 256, 0, stream>>>(hbuf, u_cat, We_lin, rbuf);
            k_rW2<<<dim3(HP / 256, B), 256, 0, stream>>>(rbuf, Wt_e, be_m1, rWb);
            if (tier == 15)
                k_m1A16<<<BM * H / 256, 256, 0, stream>>>(A_e16, rWb, m1h, m1l);
            else
                gemmMF<3><<<g128, 256, 0, stream>>>(Uh, Ul, W1eh, W1el, TWOH, rWb, nullptr, m1h, m1l);
            gemmMF<1><<<g128, 256, 0, stream>>>(m1h, m1l, W2eh, W2el, H, be_m2, m2b, nullptr, nullptr);
            k_alpha2<<<BM / 4, 256, 0, stream>>>(m1h, m1l, m2b, We_m12, be_m12, d_mask, alphab);
            k_softmax<<<B, 256, 0, stream>>>(alphab, span, 1, loss_term, idxb);
            k_update<<<1, 64, 0, stream>>>(idxb, loss_term, e_i, mask_e, p2r, loss_vec, t);
        }
    } else {
        // ---- tier 3: round-2 fp32 path (known-pass) ----
        dim3 gemm_grid(HP / 64, BM / 64);
        for (int t = 0; t < TSTEPS; ++t) {
            k_gather<<<64, 256, 0, stream>>>(U, s_i, e_i, u_cat);
            k_lstm_gemm<<<128, 256, 0, stream>>>(u_cat, hbuf, W_ih, W_hh, b_ih, b_hh, gbuf);
            k_lstm_gates<<<32, 256, 0, stream>>>(gbuf, hbuf, cbuf);

            k_r<<<32, 256, 0, stream>>>(hbuf, u_cat, Ws_lin, rbuf);
            k_rW<<<512, 256, 0, stream>>>(rbuf, Ws_m1, bs_m1, rWb);
            gemm64<2><<<gemm_grid, 256, 0, stream>>>(U, TWOH, Ws_m1, THREEH, rWb, m1b, TWOH, H);
            gemm64<1><<<gemm_grid, 256, 0, stream>>>(m1b, H, Ws_m2, H, bs_m2, m2b, H, H);
            k_alpha<<<BM / 4, 256, 0, stream>>>(m1b, m2b, Ws_m12, bs_m12, d_mask, alphab);
            k_softmax<<<B, 256, 0, stream>>>(alphab, span, 0, loss_term, idxb);
            k_update<<<1, 64, 0, stream>>>(idxb, loss_term, s_i, mask_s, p1r, loss_vec, t);

            k_gather<<<64, 256, 0, stream>>>(U, s_i, e_i, u_cat);

            k_r<<<32, 256, 0, stream>>>(hbuf, u_cat, We_lin, rbuf);
            k_rW<<<512, 256, 0, stream>>>(rbuf, We_m1, be_m1, rWb);
            gemm64<2><<<gemm_grid, 256, 0, stream>>>(U, TWOH, We_m1, THREEH, rWb, m1b, TWOH, H);
            gemm64<1><<<gemm_grid, 256, 0, stream>>>(m1b, H, We_m2, H, be_m2, m2b, H, H);
            k_alpha<<<BM / 4, 256, 0, stream>>>(m1b, m2b, We_m12, be_m12, d_mask, alphab);
            k_softmax<<<B, 256, 0, stream>>>(alphab, span, 1, loss_term, idxb);
            k_update<<<1, 64, 0, stream>>>(idxb, loss_term, e_i, mask_e, p2r, loss_vec, t);
        }
    }

    k_finalize<<<1, 64, 0, stream>>>(loss_vec, p1r, p2r, (float*)d_out);
}

// Round 5
// 4583.405 us; speedup vs baseline: 1.3848x; 1.3848x over previous
//
#include <hip/hip_runtime.h>
#include <math.h>

namespace {

typedef unsigned short u16;
typedef __attribute__((ext_vector_type(4))) float f32x4;
typedef __attribute__((ext_vector_type(8))) _Float16 f16x8;
typedef __attribute__((ext_vector_type(4))) _Float16 f16x4;

constexpr int B = 32;
constexpr int M = 600;
constexpr int H = 256;
constexpr int TSTEPS = 4;
constexpr int HP = 4096;          // H*P
constexpr int BM = B * M;         // 19200
constexpr int TWOH = 512;
constexpr int THREEH = 768;
constexpr int FOURH = 1024;
constexpr int FIVEH = 1280;

__device__ __forceinline__ float sigf(float x) { return 1.0f / (1.0f + expf(-x)); }

__device__ __forceinline__ void gload16(const u16* g, u16* l) {
    __builtin_amdgcn_global_load_lds(
        (const __attribute__((address_space(1))) void*)g,
        (__attribute__((address_space(3))) void*)l, 16, 0, 0);
}

// ---------------- init ----------------
__global__ void k_init(const int* __restrict__ d_mask,
                       float* __restrict__ h, float* __restrict__ c,
                       float* __restrict__ loss_vec,
                       int* __restrict__ s_i, int* __restrict__ e_i,
                       int* __restrict__ p1r, int* __restrict__ p2r)
{
    int tid = threadIdx.x;
    for (int i = tid; i < B * H; i += 256) { h[i] = 0.f; c[i] = 0.f; }
    if (tid < B) {
        loss_vec[tid] = 0.f;
        s_i[tid] = 0;
        int s = 0;
        const int* row = d_mask + tid * M;
        for (int m = 0; m < M; ++m) s += row[m];
        e_i[tid] = s - 1;
        p1r[tid] = 0; p2r[tid] = 0;
    }
}

// ---------------- gather u_cat = [U[b, s_i], U[b, e_i]] ----------------
__global__ __launch_bounds__(256) void k_gather(
    const float* __restrict__ U, const int* __restrict__ s_i,
    const int* __restrict__ e_i, float* __restrict__ u_cat)
{
    int idx = blockIdx.x * 256 + threadIdx.x;   // B*512 threads
    int b = idx >> 9, k = idx & 511;
    u_cat[b * FOURH + k]       = U[((size_t)b * M + s_i[b]) * TWOH + k];
    u_cat[b * FOURH + 512 + k] = U[((size_t)b * M + e_i[b]) * TWOH + k];
}

// ---------------- LSTM ----------------
__global__ __launch_bounds__(256) void k_lstm_gemm(
    const float* __restrict__ u_cat, const float* __restrict__ h,
    const float* __restrict__ W_ih, const float* __restrict__ W_hh,
    const float* __restrict__ b_ih, const float* __restrict__ b_hh,
    float* __restrict__ g)
{
    int idx = blockIdx.x * 256 + threadIdx.x;   // B*1024 threads
    int b = idx >> 10, j = idx & 1023;
    float acc = 0.f;
    const float4* x4 = (const float4*)(u_cat + b * FOURH);
    const float4* wi4 = (const float4*)(W_ih + (size_t)j * FOURH);
    #pragma unroll 4
    for (int k = 0; k < FOURH / 4; ++k) {
        float4 a = x4[k], w = wi4[k];
        acc += a.x * w.x + a.y * w.y + a.z * w.z + a.w * w.w;
    }
    const float4* h4 = (const float4*)(h + b * H);
    const float4* wh4 = (const float4*)(W_hh + (size_t)j * H);
    #pragma unroll 4
    for (int k = 0; k < H / 4; ++k) {
        float4 a = h4[k], w = wh4[k];
        acc += a.x * w.x + a.y * w.y + a.z * w.z + a.w * w.w;
    }
    g[idx] = acc + b_ih[j] + b_hh[j];
}

__global__ __launch_bounds__(256) void k_lstm_gates(
    const float* __restrict__ g, float* __restrict__ h, float* __restrict__ c)
{
    int idx = blockIdx.x * 256 + threadIdx.x;   // B*H
    int b = idx >> 8, i = idx & (H - 1);
    const float* gr = g + b * FOURH;
    float gi = gr[i], gf = gr[H + i], gg = gr[2 * H + i], go = gr[3 * H + i];
    float cn = sigf(gf) * c[idx] + sigf(gi) * tanhf(gg);
    c[idx] = cn;
    h[idx] = sigf(go) * tanhf(cn);
}

// ---------------- r = tanh(concat([h, u_cat]) @ W_lin.T) ----------------
__global__ __launch_bounds__(256) void k_r(
    const float* __restrict__ h, const float* __restrict__ u_cat,
    const float* __restrict__ W_lin, float* __restrict__ r)
{
    int idx = blockIdx.x * 256 + threadIdx.x;   // B*H
    int b = idx >> 8, i = idx & (H - 1);
    const float* w = W_lin + (size_t)i * FIVEH;
    float acc = 0.f;
    const float4* h4 = (const float4*)(h + b * H);
    const float4* w4 = (const float4*)w;
    #pragma unroll 4
    for (int k = 0; k < H / 4; ++k) {
        float4 a = h4[k], ww = w4[k];
        acc += a.x * ww.x + a.y * ww.y + a.z * ww.z + a.w * ww.w;
    }
    const float4* x4 = (const float4*)(u_cat + b * FOURH);
    const float4* w4b = (const float4*)(w + H);
    #pragma unroll 4
    for (int k = 0; k < FOURH / 4; ++k) {
        float4 a = x4[k], ww = w4b[k];
        acc += a.x * ww.x + a.y * ww.y + a.z * ww.z + a.w * ww.w;
    }
    r[idx] = tanhf(acc);
}

// ---------------- old strided rW (tier 3) ----------------
__global__ __launch_bounds__(256) void k_rW(
    const float* __restrict__ r, const float* __restrict__ W1,
    const float* __restrict__ b1, float* __restrict__ rW)
{
    int idx = blockIdx.x * 256 + threadIdx.x;   // B*HP
    int b = idx >> 12, j = idx & (HP - 1);
    const float4* r4 = (const float4*)(r + b * H);
    const float4* w4 = (const float4*)(W1 + (size_t)j * THREEH + TWOH);
    float acc = 0.f;
    #pragma unroll 4
    for (int k = 0; k < H / 4; ++k) {
        float4 a = r4[k], w = w4[k];
        acc += a.x * w.x + a.y * w.y + a.z * w.z + a.w * w.w;
    }
    rW[idx] = acc + b1[j];
}

// ---------------- coalesced rW via transposed weight (tiers 15/2) ----------------
__global__ __launch_bounds__(256) void k_rW2(
    const float* __restrict__ r, const float* __restrict__ Wt,
    const float* __restrict__ b1, float* __restrict__ rW)
{
    const int b = blockIdx.y;
    const int j = blockIdx.x * 256 + threadIdx.x;
    __shared__ float sr[256];
    sr[threadIdx.x] = r[b * H + threadIdx.x];
    __syncthreads();
    float acc = b1[j];
    #pragma unroll 4
    for (int k = 0; k < H; ++k) acc += sr[k] * Wt[(size_t)k * HP + j];
    rW[(size_t)b * HP + j] = acc;
}

// ---------------- transpose W1[:, 512:768] -> Wt[256][4096] ----------------
__global__ __launch_bounds__(256) void k_transp(
    const float* __restrict__ W, float* __restrict__ Wt)
{
    int idx = blockIdx.x * 256 + threadIdx.x;   // HP*H
    int k = idx >> 12, j = idx & (HP - 1);
    Wt[idx] = W[(size_t)j * THREEH + TWOH + k];
}

// ---------------- fp32 -> fp16 converter (RTN via HW cvt) ----------------
__global__ __launch_bounds__(256) void k_cvtH(
    const float* __restrict__ src, int ld, int Kc, _Float16* __restrict__ dst)
{
    int i4 = blockIdx.x * 256 + threadIdx.x;    // over N*Kc/4
    int perrow = Kc >> 2;
    int row = i4 / perrow;
    int kc = (i4 - row * perrow) << 2;
    float4 v = *(const float4*)(src + (size_t)row * ld + kc);
    f16x4 o;
    o[0] = (_Float16)v.x; o[1] = (_Float16)v.y; o[2] = (_Float16)v.z; o[3] = (_Float16)v.w;
    *(f16x4*)(dst + (size_t)row * Kc + kc) = o;
}

// ---------------- fp16 MFMA GEMM: C = A @ B^T.  Tile 128x128, BK=32 ----------------
// EPI=1: +bias[col], max over 16-col groups -> Cf [rows x 256] fp32      (m2)
// EPI=3: +rW[row/M][col], max over 16-col groups -> Ch fp16 [rows x 256] (m1, tier2)
// EPI=4: store fp16 C [rows x 4096] into Ch                              (tier-15 precompute)
template <int EPI>
__global__ __launch_bounds__(256) void gemmH(
    const _Float16* __restrict__ A, const _Float16* __restrict__ Bw,
    int K, const float* __restrict__ extra,
    float* __restrict__ Cf, _Float16* __restrict__ Ch)
{
    __shared__ __align__(16) u16 sA[128 * 32];
    __shared__ __align__(16) u16 sB[128 * 32];
    const int tid = threadIdx.x;
    const int w = tid >> 6, lane = tid & 63;
    const int row0 = blockIdx.y * 128, col0 = blockIdx.x * 128;
    const int wm = w & 1, wn = w >> 1;
    const int rt0 = w * 32;
    const int lrow = lane >> 2;          // 0..15
    const int lk = (lane & 3) << 3;      // 0,8,16,24 elems (16B)

    f32x4 acc[4][4] = {};

    for (int k0 = 0; k0 < K; k0 += 32) {
        __syncthreads();
        #pragma unroll
        for (int c = 0; c < 2; ++c) {
            const int rt = rt0 + c * 16 + lrow;
            gload16((const u16*)(A  + (size_t)(row0 + rt) * K + k0 + lk), &sA[(rt0 + c * 16) * 32]);
            gload16((const u16*)(Bw + (size_t)(col0 + rt) * K + k0 + lk), &sB[(rt0 + c * 16) * 32]);
        }
        __syncthreads();
        f16x8 fa[4], fb[4];
        const int ko = (lane >> 4) << 3;
        #pragma unroll
        for (int f = 0; f < 4; ++f) {
            fa[f] = *(const f16x8*)&sA[(wm * 64 + f * 16 + (lane & 15)) * 32 + ko];
            fb[f] = *(const f16x8*)&sB[(wn * 64 + f * 16 + (lane & 15)) * 32 + ko];
        }
        #pragma unroll
        for (int i = 0; i < 4; ++i) {
            #pragma unroll
            for (int j = 0; j < 4; ++j) {
                acc[i][j] = __builtin_amdgcn_mfma_f32_16x16x32_f16(fa[i], fb[j], acc[i][j], 0, 0, 0);
            }
        }
    }

    // epilogue — C/D layout: col = lane&15, row = (lane>>4)*4 + reg
    const int cq = lane & 15, rq = lane >> 4;
    if (EPI == 4) {
        #pragma unroll
        for (int i = 0; i < 4; ++i) {
            #pragma unroll
            for (int j = 0; j < 4; ++j) {
                int col = col0 + wn * 64 + j * 16 + cq;
                #pragma unroll
                for (int rr = 0; rr < 4; ++rr) {
                    int row = row0 + wm * 64 + i * 16 + rq * 4 + rr;
                    Ch[(size_t)row * HP + col] = (_Float16)acc[i][j][rr];
                }
            }
        }
    } else if (EPI == 1) {
        #pragma unroll
        for (int j = 0; j < 4; ++j) {
            int col = col0 + wn * 64 + j * 16 + cq;
            int gcol = (col0 >> 4) + wn * 4 + j;
            float bv = extra[col];
            #pragma unroll
            for (int i = 0; i < 4; ++i) {
                #pragma unroll
                for (int rr = 0; rr < 4; ++rr) {
                    float v = acc[i][j][rr] + bv;
                    v = fmaxf(v, __shfl_xor(v, 1));
                    v = fmaxf(v, __shfl_xor(v, 2));
                    v = fmaxf(v, __shfl_xor(v, 4));
                    v = fmaxf(v, __shfl_xor(v, 8));
                    if (cq == 0) {
                        int row = row0 + wm * 64 + i * 16 + rq * 4 + rr;
                        Cf[(size_t)row * H + gcol] = v;
                    }
                }
            }
        }
    } else {  // EPI == 3
        #pragma unroll
        for (int j = 0; j < 4; ++j) {
            int col = col0 + wn * 64 + j * 16 + cq;
            int gcol = (col0 >> 4) + wn * 4 + j;
            #pragma unroll
            for (int i = 0; i < 4; ++i) {
                #pragma unroll
                for (int rr = 0; rr < 4; ++rr) {
                    int row = row0 + wm * 64 + i * 16 + rq * 4 + rr;
                    int b = row / M;
                    float v = acc[i][j][rr] + extra[(size_t)b * HP + col];
                    v = fmaxf(v, __shfl_xor(v, 1));
                    v = fmaxf(v, __shfl_xor(v, 2));
                    v = fmaxf(v, __shfl_xor(v, 4));
                    v = fmaxf(v, __shfl_xor(v, 8));
                    if (cq == 0)
                        Ch[(size_t)row * H + gcol] = (_Float16)v;
                }
            }
        }
    }
}

// ---------------- tier 15: m1 = max16(A_f16 + rW) -> fp16 ----------------
__global__ __launch_bounds__(256) void k_m1A16(
    const _Float16* __restrict__ A, const float* __restrict__ rW,
    _Float16* __restrict__ m1)
{
    int idx = blockIdx.x * 256 + threadIdx.x;   // bm*H + h
    int bm = idx >> 8;
    int h = idx & (H - 1);
    int b = bm / M;
    const f16x8* a8 = (const f16x8*)(A + (size_t)bm * HP + (h << 4));
    const float4* r4 = (const float4*)(rW + (size_t)b * HP + (h << 4));
    f16x8 a0 = a8[0], a1 = a8[1];
    float4 ra = r4[0], rb = r4[1], rc = r4[2], rd = r4[3];
    float mx;
    mx = fmaxf(fmaxf(fmaxf((float)a0[0] + ra.x, (float)a0[1] + ra.y),
                     fmaxf((float)a0[2] + ra.z, (float)a0[3] + ra.w)),
         fmaxf(fmaxf((float)a0[4] + rb.x, (float)a0[5] + rb.y),
               fmaxf((float)a0[6] + rb.z, (float)a0[7] + rb.w)));
    mx = fmaxf(mx,
         fmaxf(fmaxf(fmaxf((float)a1[0] + rc.x, (float)a1[1] + rc.y),
                     fmaxf((float)a1[2] + rc.z, (float)a1[3] + rc.w)),
               fmaxf(fmaxf((float)a1[4] + rd.x, (float)a1[5] + rd.y),
                     fmaxf((float)a1[6] + rd.z, (float)a1[7] + rd.w))));
    m1[idx] = (_Float16)mx;
}

// ---------------- tier 3 fp32 GEMM (round-2, known-pass) ----------------
template <int EPI>
__global__ __launch_bounds__(256) void gemm64(
    const float* __restrict__ Ag, int lda,
    const float* __restrict__ Bg, int ldb,
    const float* __restrict__ extra,
    float* __restrict__ C, int K, int ldc)
{
    __shared__ float As[16][68];
    __shared__ float Bs[16][68];
    const int tid = threadIdx.x;
    const int tx = tid & 15;
    const int ty = tid >> 4;
    const int row0 = blockIdx.y * 64;
    const int col0 = blockIdx.x * 64;
    const int lr = tid >> 2;
    const int lk = (tid & 3) << 2;
    const float* Aload = Ag + (size_t)(row0 + lr) * lda + lk;
    const float* Bload = Bg + (size_t)(col0 + lr) * ldb + lk;
    float acc[4][4] = {};
    for (int k0 = 0; k0 < K; k0 += 16) {
        float4 av = *(const float4*)(Aload + k0);
        float4 bv = *(const float4*)(Bload + k0);
        __syncthreads();
        As[lk + 0][lr] = av.x; As[lk + 1][lr] = av.y; As[lk + 2][lr] = av.z; As[lk + 3][lr] = av.w;
        Bs[lk + 0][lr] = bv.x; Bs[lk + 1][lr] = bv.y; Bs[lk + 2][lr] = bv.z; Bs[lk + 3][lr] = bv.w;
        __syncthreads();
        #pragma unroll
        for (int k = 0; k < 16; ++k) {
            float4 a4 = *(const float4*)(&As[k][ty << 2]);
            float4 b4 = *(const float4*)(&Bs[k][tx << 2]);
            acc[0][0] += a4.x * b4.x; acc[0][1] += a4.x * b4.y; acc[0][2] += a4.x * b4.z; acc[0][3] += a4.x * b4.w;
            acc[1][0] += a4.y * b4.x; acc[1][1] += a4.y * b4.y; acc[1][2] += a4.y * b4.z; acc[1][3] += a4.y * b4.w;
            acc[2][0] += a4.z * b4.x; acc[2][1] += a4.z * b4.y; acc[2][2] += a4.z * b4.z; acc[2][3] += a4.z * b4.w;
            acc[3][0] += a4.w * b4.x; acc[3][1] += a4.w * b4.y; acc[3][2] += a4.w * b4.z; acc[3][3] += a4.w * b4.w;
        }
    }
    if (EPI == 1) {
        const int cb = col0 + (tx << 2);
        float b0 = extra[cb], b1v = extra[cb + 1], b2v = extra[cb + 2], b3v = extra[cb + 3];
        #pragma unroll
        for (int i = 0; i < 4; ++i) {
            float mth = fmaxf(fmaxf(acc[i][0] + b0, acc[i][1] + b1v),
                              fmaxf(acc[i][2] + b2v, acc[i][3] + b3v));
            float r1 = fmaxf(mth, __shfl_xor(mth, 1));
            float r2 = fmaxf(r1, __shfl_xor(r1, 2));
            if ((tx & 3) == 0)
                C[(size_t)(row0 + (ty << 2) + i) * ldc + (col0 >> 4) + (tx >> 2)] = r2;
        }
    } else if (EPI == 2) {
        const int cb = col0 + (tx << 2);
        #pragma unroll
        for (int i = 0; i < 4; ++i) {
            int row = row0 + (ty << 2) + i;
            int b = row / M;
            const float* rw = extra + (size_t)b * HP + cb;
            float mth = fmaxf(fmaxf(acc[i][0] + rw[0], acc[i][1] + rw[1]),
                              fmaxf(acc[i][2] + rw[2], acc[i][3] + rw[3]));
            float r1 = fmaxf(mth, __shfl_xor(mth, 1));
            float r2 = fmaxf(r1, __shfl_xor(r1, 2));
            if ((tx & 3) == 0)
                C[(size_t)row * ldc + (col0 >> 4) + (tx >> 2)] = r2;
        }
    }
}

// ---------------- alpha (tier 3: fp32 m1) ----------------
__global__ __launch_bounds__(256) void k_alpha(
    const float* __restrict__ m1, const float* __restrict__ m2,
    const float* __restrict__ W12, const float* __restrict__ b12,
    const int* __restrict__ d_mask, float* __restrict__ alpha)
{
    __shared__ float Ws[16 * 512];
    const int tid = threadIdx.x;
    for (int i = tid; i < 16 * 512; i += 256) Ws[i] = W12[i];
    __syncthreads();
    const int wave = tid >> 6, lane = tid & 63;
    const int bm = blockIdx.x * 4 + wave;
    const float* r1 = m1 + (size_t)bm * H;
    const float* r2 = m2 + (size_t)bm * H;
    float acc[16] = {};
    #pragma unroll
    for (int q = 0; q < 4; ++q) {
        int k = lane + (q << 6);
        float x = r1[k];
        #pragma unroll
        for (int p = 0; p < 16; ++p) acc[p] += x * Ws[p * 512 + k];
    }
    #pragma unroll
    for (int q = 0; q < 4; ++q) {
        int k = lane + (q << 6);
        float x = r2[k];
        #pragma unroll
        for (int p = 0; p < 16; ++p) acc[p] += x * Ws[p * 512 + 256 + k];
    }
    #pragma unroll
    for (int p = 0; p < 16; ++p) {
        float v = acc[p];
        v += __shfl_xor(v, 1);  v += __shfl_xor(v, 2);  v += __shfl_xor(v, 4);
        v += __shfl_xor(v, 8);  v += __shfl_xor(v, 16); v += __shfl_xor(v, 32);
        acc[p] = v;
    }
    if (lane == 0) {
        float mx = -INFINITY;
        #pragma unroll
        for (int p = 0; p < 16; ++p) mx = fmaxf(mx, acc[p] + b12[p]);
        alpha[bm] = d_mask[bm] ? mx : -1e30f;
    }
}

// ---------------- alpha (tiers 15/2: m1 fp16, m2 fp32) ----------------
__global__ __launch_bounds__(256) void k_alpha2(
    const _Float16* __restrict__ m1, const float* __restrict__ m2,
    const float* __restrict__ W12, const float* __restrict__ b12,
    const int* __restrict__ d_mask, float* __restrict__ alpha)
{
    __shared__ float Ws[16 * 512];
    const int tid = threadIdx.x;
    for (int i = tid; i < 16 * 512; i += 256) Ws[i] = W12[i];
    __syncthreads();
    const int wave = tid >> 6, lane = tid & 63;
    const int bm = blockIdx.x * 4 + wave;
    const _Float16* r1 = m1 + (size_t)bm * H;
    const float* r2 = m2 + (size_t)bm * H;
    float acc[16] = {};
    #pragma unroll
    for (int q = 0; q < 4; ++q) {
        int k = lane + (q << 6);
        float x = (float)r1[k];
        #pragma unroll
        for (int p = 0; p < 16; ++p) acc[p] += x * Ws[p * 512 + k];
    }
    #pragma unroll
    for (int q = 0; q < 4; ++q) {
        int k = lane + (q << 6);
        float x = r2[k];
        #pragma unroll
        for (int p = 0; p < 16; ++p) acc[p] += x * Ws[p * 512 + 256 + k];
    }
    #pragma unroll
    for (int p = 0; p < 16; ++p) {
        float v = acc[p];
        v += __shfl_xor(v, 1);  v += __shfl_xor(v, 2);  v += __shfl_xor(v, 4);
        v += __shfl_xor(v, 8);  v += __shfl_xor(v, 16); v += __shfl_xor(v, 32);
        acc[p] = v;
    }
    if (lane == 0) {
        float mx = -INFINITY;
        #pragma unroll
        for (int p = 0; p < 16; ++p) mx = fmaxf(mx, acc[p] + b12[p]);
        alpha[bm] = d_mask[bm] ? mx : -1e30f;
    }
}

// ---------------- per-b: argmax + logsumexp + loss term ----------------
__global__ __launch_bounds__(256) void k_softmax(
    const float* __restrict__ alpha, const int* __restrict__ span, int phase,
    float* __restrict__ loss_term, int* __restrict__ idx_out)
{
    __shared__ float sv[256];
    __shared__ int si[256];
    const int b = blockIdx.x, tid = threadIdx.x;
    const float* row = alpha + b * M;
    float best = -INFINITY; int bidx = 0;
    for (int m = tid; m < M; m += 256) {
        float v = row[m];
        if (v > best) { best = v; bidx = m; }
    }
    sv[tid] = best; si[tid] = bidx;
    __syncthreads();
    for (int s = 128; s > 0; s >>= 1) {
        if (tid < s) {
            float v2 = sv[tid + s]; int i2 = si[tid + s];
            if (v2 > sv[tid] || (v2 == sv[tid] && i2 < si[tid])) { sv[tid] = v2; si[tid] = i2; }
        }
        __syncthreads();
    }
    float bmax = sv[0]; int amax = si[0];
    __syncthreads();
    float ps = 0.f;
    for (int m = tid; m < M; m += 256) ps += expf(row[m] - bmax);
    sv[tid] = ps;
    __syncthreads();
    for (int s = 128; s > 0; s >>= 1) {
        if (tid < s) sv[tid] += sv[tid + s];
        __syncthreads();
    }
    if (tid == 0) {
        float lse = bmax + logf(sv[0]);
        int tgt = span[b * 2 + phase];
        loss_term[b] = -(row[tgt] - lse);
        idx_out[b] = amax;
    }
}

// ---------------- sticky-mask pointer update + loss ----------------
__global__ void k_update(const int* __restrict__ idx_in, const float* __restrict__ loss_term,
                         int* __restrict__ pos, int* __restrict__ mask,
                         int* __restrict__ prun, float* __restrict__ loss_vec, int t)
{
    int b = threadIdx.x;
    int active = (b < B) ? 1 : 0;
    int ni = 0, nm = 0;
    if (active) {
        int id = idx_in[b];
        if (t == 0) { nm = 1; ni = id; }
        else {
            int om = mask[b];
            ni = id * om;
            int prev = pos[b] * om;
            nm = (ni != prev) ? 1 : 0;
        }
    }
    float v = active ? loss_term[b] : 0.f;
    #pragma unroll
    for (int off = 32; off > 0; off >>= 1) v += __shfl_xor(v, off);
    float S = v * (1.0f / (float)B);
    if (active) {
        pos[b] = ni;
        mask[b] = nm;
        if (nm) { prun[b] = ni; loss_vec[b] += S; }
    }
}

// ---------------- finalize ----------------
__global__ void k_finalize(const float* __restrict__ loss_vec, const int* __restrict__ p1r,
                           const int* __restrict__ p2r, float* __restrict__ out)
{
    int b = threadIdx.x;
    float v = (b < B) ? loss_vec[b] : 0.f;
    #pragma unroll
    for (int off = 32; off > 0; off >>= 1) v += __shfl_xor(v, off);
    if (b == 0) out[0] = v / (float)(B * TSTEPS);
    if (b < B) {
        out[1 + b] = (float)p1r[b];
        out[1 + B + b] = (float)p2r[b];
    }
}

}  // namespace

extern "C" void kernel_launch(void* const* d_in, const int* in_sizes, int n_in,
                              void* d_out, int out_size, void* d_ws, size_t ws_size,
                              hipStream_t stream)
{
    const float* U      = (const float*)d_in[0];
    const int*   d_mask = (const int*)d_in[1];
    const int*   span   = (const int*)d_in[2];
    const float* W_ih   = (const float*)d_in[3];
    const float* W_hh   = (const float*)d_in[4];
    const float* b_ih   = (const float*)d_in[5];
    const float* b_hh   = (const float*)d_in[6];
    const float* Ws_lin = (const float*)d_in[7];
    const float* Ws_m1  = (const float*)d_in[8];
    const float* bs_m1  = (const float*)d_in[9];
    const float* Ws_m2  = (const float*)d_in[10];
    const float* bs_m2  = (const float*)d_in[11];
    const float* Ws_m12 = (const float*)d_in[12];
    const float* bs_m12 = (const float*)d_in[13];
    const float* We_lin = (const float*)d_in[14];
    const float* We_m1  = (const float*)d_in[15];
    const float* be_m1  = (const float*)d_in[16];
    const float* We_m2  = (const float*)d_in[17];
    const float* be_m2  = (const float*)d_in[18];
    const float* We_m12 = (const float*)d_in[19];
    const float* be_m12 = (const float*)d_in[20];

    // ---- workspace layout ----
    float* ws = (float*)d_ws;
    size_t o = 0;
    float* m2b   = ws + o; o += (size_t)BM * H;
    float* alphab= ws + o; o += BM;
    float* u_cat = ws + o; o += B * FOURH;
    float* gbuf  = ws + o; o += B * FOURH;
    float* hbuf  = ws + o; o += B * H;
    float* cbuf  = ws + o; o += B * H;
    float* rbuf  = ws + o; o += B * H;
    float* rWb   = ws + o; o += B * HP;
    float* loss_term = ws + o; o += B;
    float* loss_vec  = ws + o; o += B;
    int* ib = (int*)(ws + o); o += 8 * B;
    int* idxb   = ib + 0 * B;
    int* s_i    = ib + 1 * B;
    int* e_i    = ib + 2 * B;
    int* mask_s = ib + 3 * B;
    int* mask_e = ib + 4 * B;
    int* p1r    = ib + 5 * B;
    int* p2r    = ib + 6 * B;
    size_t o_common = (o + 3) & ~(size_t)3;

    // tier 3 (fp32 fallback): m1b fp32
    float* m1b = ws + o_common;

    // tiers 15/2: transposed rW weights + fp16 region
    size_t p = o_common;
    float* Wt_s = ws + p; p += (size_t)H * HP;
    float* Wt_e = ws + p; p += (size_t)H * HP;
    _Float16* hs = (_Float16*)(ws + p);
    size_t q = 0;
    _Float16* Uh  = hs + q; q += (size_t)BM * TWOH;
    _Float16* W1s = hs + q; q += (size_t)HP * TWOH;
    _Float16* W1e = hs + q; q += (size_t)HP * TWOH;
    _Float16* W2s = hs + q; q += (size_t)HP * H;
    _Float16* W2e = hs + q; q += (size_t)HP * H;
    _Float16* m1b16 = hs + q; q += (size_t)BM * H;
    q = (q + 7) & ~(size_t)7;                 // 16B-align what follows
    const size_t need2 = p * sizeof(float) + q * sizeof(_Float16);
    _Float16* A_s16 = hs + q;
    _Float16* A_e16 = A_s16 + (size_t)BM * HP;
    const size_t need15 = need2 + 2 * (size_t)BM * HP * sizeof(_Float16);

    const int tier = (ws_size >= need15) ? 15 : (ws_size >= need2) ? 2 : 3;

    k_init<<<1, 256, 0, stream>>>(d_mask, hbuf, cbuf, loss_vec, s_i, e_i, p1r, p2r);

    if (tier <= 15) {
        // rebuild every call (ws re-poisoned by harness)
        k_cvtH<<<BM * TWOH / 4 / 256, 256, 0, stream>>>(U, TWOH, TWOH, Uh);
        k_cvtH<<<HP * TWOH / 4 / 256, 256, 0, stream>>>(Ws_m1, THREEH, TWOH, W1s);
        k_cvtH<<<HP * TWOH / 4 / 256, 256, 0, stream>>>(We_m1, THREEH, TWOH, W1e);
        k_cvtH<<<HP * H / 4 / 256, 256, 0, stream>>>(Ws_m2, H, H, W2s);
        k_cvtH<<<HP * H / 4 / 256, 256, 0, stream>>>(We_m2, H, H, W2e);
        k_transp<<<HP * H / 256, 256, 0, stream>>>(Ws_m1, Wt_s);
        k_transp<<<HP * H / 256, 256, 0, stream>>>(We_m1, Wt_e);

        dim3 g128(HP / 128, BM / 128);  // (32, 150)
        if (tier == 15) {
            // iteration-invariant A = U @ W1u.T, stored fp16 (2x157 MB)
            gemmH<4><<<g128, 256, 0, stream>>>(Uh, W1s, TWOH, nullptr, nullptr, A_s16);
            gemmH<4><<<g128, 256, 0, stream>>>(Uh, W1e, TWOH, nullptr, nullptr, A_e16);
        }

        for (int t = 0; t < TSTEPS; ++t) {
            k_gather<<<64, 256, 0, stream>>>(U, s_i, e_i, u_cat);
            k_lstm_gemm<<<128, 256, 0, stream>>>(u_cat, hbuf, W_ih, W_hh, b_ih, b_hh, gbuf);
            k_lstm_gates<<<32, 256, 0, stream>>>(gbuf, hbuf, cbuf);

            // ---- start pointer ----
            k_r<<<32, 256, 0, stream>>>(hbuf, u_cat, Ws_lin, rbuf);
            k_rW2<<<dim3(HP / 256, B), 256, 0, stream>>>(rbuf, Wt_s, bs_m1, rWb);
            if (tier == 15)
                k_m1A16<<<BM * H / 256, 256, 0, stream>>>(A_s16, rWb, m1b16);
            else
                gemmH<3><<<g128, 256, 0, stream>>>(Uh, W1s, TWOH, rWb, nullptr, m1b16);
            gemmH<1><<<g128, 256, 0, stream>>>(m1b16, W2s, H, bs_m2, m2b, nullptr);
            k_alpha2<<<BM / 4, 256, 0, stream>>>(m1b16, m2b, Ws_m12, bs_m12, d_mask, alphab);
            k_softmax<<<B, 256, 0, stream>>>(alphab, span, 0, loss_term, idxb);
            k_update<<<1, 64, 0, stream>>>(idxb, loss_term, s_i, mask_s, p1r, loss_vec, t);

            k_gather<<<64, 256, 0, stream>>>(U, s_i, e_i, u_cat);

            // ---- end pointer ----
            k_r<<<32, 256, 0, stream>>>(hbuf, u_cat, We_lin, rbuf);
            k_rW2<<<dim3(HP / 256, B), 256, 0, stream>>>(rbuf, Wt_e, be_m1, rWb);
            if (tier == 15)
                k_m1A16<<<BM * H / 256, 256, 0, stream>>>(A_e16, rWb, m1b16);
            else
                gemmH<3><<<g128, 256, 0, stream>>>(Uh, W1e, TWOH, rWb, nullptr, m1b16);
            gemmH<1><<<g128, 256, 0, stream>>>(m1b16, W2e, H, be_m2, m2b, nullptr);
            k_alpha2<<<BM / 4, 256, 0, stream>>>(m1b16, m2b, We_m12, be_m12, d_mask, alphab);
            k_softmax<<<B, 256, 0, stream>>>(alphab, span, 1, loss_term, idxb);
            k_update<<<1, 64, 0, stream>>>(idxb, loss_term, e_i, mask_e, p2r, loss_vec, t);
        }
    } else {
        // ---- tier 3: round-2 fp32 path (known-pass) ----
        dim3 gemm_grid(HP / 64, BM / 64);
        for (int t = 0; t < TSTEPS; ++t) {
            k_gather<<<64, 256, 0, stream>>>(U, s_i, e_i, u_cat);
            k_lstm_gemm<<<128, 256, 0, stream>>>(u_cat, hbuf, W_ih, W_hh, b_ih, b_hh, gbuf);
            k_lstm_gates<<<32, 256, 0, stream>>>(gbuf, hbuf, cbuf);

            k_r<<<32, 256, 0, stream>>>(hbuf, u_cat, Ws_lin, rbuf);
            k_rW<<<512, 256, 0, stream>>>(rbuf, Ws_m1, bs_m1, rWb);
            gemm64<2><<<gemm_grid, 256, 0, stream>>>(U, TWOH, Ws_m1, THREEH, rWb, m1b, TWOH, H);
            gemm64<1><<<gemm_grid, 256, 0, stream>>>(m1b, H, Ws_m2, H, bs_m2, m2b, H, H);
            k_alpha<<<BM / 4, 256, 0, stream>>>(m1b, m2b, Ws_m12, bs_m12, d_mask, alphab);
            k_softmax<<<B, 256, 0, stream>>>(alphab, span, 0, loss_term, idxb);
            k_update<<<1, 64, 0, stream>>>(idxb, loss_term, s_i, mask_s, p1r, loss_vec, t);

            k_gather<<<64, 256, 0, stream>>>(U, s_i, e_i, u_cat);

            k_r<<<32, 256, 0, stream>>>(hbuf, u_cat, We_lin, rbuf);
            k_rW<<<512, 256, 0, stream>>>(rbuf, We_m1, be_m1, rWb);
            gemm64<2><<<gemm_grid, 256, 0, stream>>>(U, TWOH, We_m1, THREEH, rWb, m1b, TWOH, H);
            gemm64<1><<<gemm_grid, 256, 0, stream>>>(m1b, H, We_m2, H, be_m2, m2b, H, H);
            k_alpha<<<BM / 4, 256, 0, stream>>>(m1b, m2b, We_m12, be_m12, d_mask, alphab);
            k_softmax<<<B, 256, 0, stream>>>(alphab, span, 1, loss_term, idxb);
            k_update<<<1, 64, 0, stream>>>(idxb, loss_term, e_i, mask_e, p2r, loss_vec, t);
        }
    }

    k_finalize<<<1, 64, 0, stream>>>(loss_vec, p1r, p2r, (float*)d_out);
}

// Round 6
// 3467.421 us; speedup vs baseline: 1.8305x; 1.3218x over previous
//
#include <hip/hip_runtime.h>
#include <math.h>

namespace {

typedef unsigned short u16;
typedef __attribute__((ext_vector_type(4))) float f32x4;
typedef __attribute__((ext_vector_type(8))) _Float16 f16x8;
typedef __attribute__((ext_vector_type(4))) _Float16 f16x4;

constexpr int B = 32;
constexpr int M = 600;
constexpr int H = 256;
constexpr int TSTEPS = 4;
constexpr int HP = 4096;          // H*P
constexpr int BM = B * M;         // 19200
constexpr int TWOH = 512;
constexpr int THREEH = 768;
constexpr int FOURH = 1024;
constexpr int FIVEH = 1280;

__device__ __forceinline__ float sigf(float x) { return 1.0f / (1.0f + expf(-x)); }

__device__ __forceinline__ void gload16(const u16* g, u16* l) {
    __builtin_amdgcn_global_load_lds(
        (const __attribute__((address_space(1))) void*)g,
        (__attribute__((address_space(3))) void*)l, 16, 0, 0);
}

// ---------------- init ----------------
__global__ void k_init(const int* __restrict__ d_mask,
                       float* __restrict__ h, float* __restrict__ c,
                       float* __restrict__ loss_vec,
                       int* __restrict__ s_i, int* __restrict__ e_i,
                       int* __restrict__ p1r, int* __restrict__ p2r)
{
    int tid = threadIdx.x;
    for (int i = tid; i < B * H; i += 256) { h[i] = 0.f; c[i] = 0.f; }
    if (tid < B) {
        loss_vec[tid] = 0.f;
        s_i[tid] = 0;
        int s = 0;
        const int* row = d_mask + tid * M;
        for (int m = 0; m < M; ++m) s += row[m];
        e_i[tid] = s - 1;
        p1r[tid] = 0; p2r[tid] = 0;
    }
}

// ---------------- gather u_cat = [U[b, s_i], U[b, e_i]] ----------------
__global__ __launch_bounds__(256) void k_gather(
    const float* __restrict__ U, const int* __restrict__ s_i,
    const int* __restrict__ e_i, float* __restrict__ u_cat)
{
    int idx = blockIdx.x * 256 + threadIdx.x;   // B*512 threads
    int b = idx >> 9, k = idx & 511;
    u_cat[b * FOURH + k]       = U[((size_t)b * M + s_i[b]) * TWOH + k];
    u_cat[b * FOURH + 512 + k] = U[((size_t)b * M + e_i[b]) * TWOH + k];
}

// ---------------- LSTM ----------------
__global__ __launch_bounds__(256) void k_lstm_gemm(
    const float* __restrict__ u_cat, const float* __restrict__ h,
    const float* __restrict__ W_ih, const float* __restrict__ W_hh,
    const float* __restrict__ b_ih, const float* __restrict__ b_hh,
    float* __restrict__ g)
{
    int idx = blockIdx.x * 256 + threadIdx.x;   // B*1024 threads
    int b = idx >> 10, j = idx & 1023;
    float acc = 0.f;
    const float4* x4 = (const float4*)(u_cat + b * FOURH);
    const float4* wi4 = (const float4*)(W_ih + (size_t)j * FOURH);
    #pragma unroll 4
    for (int k = 0; k < FOURH / 4; ++k) {
        float4 a = x4[k], w = wi4[k];
        acc += a.x * w.x + a.y * w.y + a.z * w.z + a.w * w.w;
    }
    const float4* h4 = (const float4*)(h + b * H);
    const float4* wh4 = (const float4*)(W_hh + (size_t)j * H);
    #pragma unroll 4
    for (int k = 0; k < H / 4; ++k) {
        float4 a = h4[k], w = wh4[k];
        acc += a.x * w.x + a.y * w.y + a.z * w.z + a.w * w.w;
    }
    g[idx] = acc + b_ih[j] + b_hh[j];
}

__global__ __launch_bounds__(256) void k_lstm_gates(
    const float* __restrict__ g, float* __restrict__ h, float* __restrict__ c)
{
    int idx = blockIdx.x * 256 + threadIdx.x;   // B*H
    int b = idx >> 8, i = idx & (H - 1);
    const float* gr = g + b * FOURH;
    float gi = gr[i], gf = gr[H + i], gg = gr[2 * H + i], go = gr[3 * H + i];
    float cn = sigf(gf) * c[idx] + sigf(gi) * tanhf(gg);
    c[idx] = cn;
    h[idx] = sigf(go) * tanhf(cn);
}

// ---------------- r = tanh(concat([h, u_cat]) @ W_lin.T) ----------------
__global__ __launch_bounds__(256) void k_r(
    const float* __restrict__ h, const float* __restrict__ u_cat,
    const float* __restrict__ W_lin, float* __restrict__ r)
{
    int idx = blockIdx.x * 256 + threadIdx.x;   // B*H
    int b = idx >> 8, i = idx & (H - 1);
    const float* w = W_lin + (size_t)i * FIVEH;
    float acc = 0.f;
    const float4* h4 = (const float4*)(h + b * H);
    const float4* w4 = (const float4*)w;
    #pragma unroll 4
    for (int k = 0; k < H / 4; ++k) {
        float4 a = h4[k], ww = w4[k];
        acc += a.x * ww.x + a.y * ww.y + a.z * ww.z + a.w * ww.w;
    }
    const float4* x4 = (const float4*)(u_cat + b * FOURH);
    const float4* w4b = (const float4*)(w + H);
    #pragma unroll 4
    for (int k = 0; k < FOURH / 4; ++k) {
        float4 a = x4[k], ww = w4b[k];
        acc += a.x * ww.x + a.y * ww.y + a.z * ww.z + a.w * ww.w;
    }
    r[idx] = tanhf(acc);
}

// ---------------- old strided rW (tier 3) ----------------
__global__ __launch_bounds__(256) void k_rW(
    const float* __restrict__ r, const float* __restrict__ W1,
    const float* __restrict__ b1, float* __restrict__ rW)
{
    int idx = blockIdx.x * 256 + threadIdx.x;   // B*HP
    int b = idx >> 12, j = idx & (HP - 1);
    const float4* r4 = (const float4*)(r + b * H);
    const float4* w4 = (const float4*)(W1 + (size_t)j * THREEH + TWOH);
    float acc = 0.f;
    #pragma unroll 4
    for (int k = 0; k < H / 4; ++k) {
        float4 a = r4[k], w = w4[k];
        acc += a.x * w.x + a.y * w.y + a.z * w.z + a.w * w.w;
    }
    rW[idx] = acc + b1[j];
}

// ---------------- coalesced rW via transposed weight (tier 2) ----------------
__global__ __launch_bounds__(256) void k_rW2(
    const float* __restrict__ r, const float* __restrict__ Wt,
    const float* __restrict__ b1, float* __restrict__ rW)
{
    const int b = blockIdx.y;
    const int j = blockIdx.x * 256 + threadIdx.x;
    __shared__ float sr[256];
    sr[threadIdx.x] = r[b * H + threadIdx.x];
    __syncthreads();
    float acc = b1[j];
    #pragma unroll 4
    for (int k = 0; k < H; ++k) acc += sr[k] * Wt[(size_t)k * HP + j];
    rW[(size_t)b * HP + j] = acc;
}

// ---------------- transpose W1[:, 512:768] -> Wt[256][4096] ----------------
__global__ __launch_bounds__(256) void k_transp(
    const float* __restrict__ W, float* __restrict__ Wt)
{
    int idx = blockIdx.x * 256 + threadIdx.x;   // HP*H
    int k = idx >> 12, j = idx & (HP - 1);
    Wt[idx] = W[(size_t)j * THREEH + TWOH + k];
}

// ---------------- fp32 -> fp16 converter ----------------
__global__ __launch_bounds__(256) void k_cvtH(
    const float* __restrict__ src, int ld, int Kc, _Float16* __restrict__ dst)
{
    int i4 = blockIdx.x * 256 + threadIdx.x;    // over N*Kc/4
    int perrow = Kc >> 2;
    int row = i4 / perrow;
    int kc = (i4 - row * perrow) << 2;
    float4 v = *(const float4*)(src + (size_t)row * ld + kc);
    f16x4 o;
    o[0] = (_Float16)v.x; o[1] = (_Float16)v.y; o[2] = (_Float16)v.z; o[3] = (_Float16)v.w;
    *(f16x4*)(dst + (size_t)row * Kc + kc) = o;
}

// ---------- fp16 MFMA GEMM, double-buffered: C = A @ B^T.  Tile 128x256, BK=32 ------
// 512 threads = 8 waves (2x4 wave grid). One barrier per K-iter; prefetch for k+1
// issued AFTER the barrier so the compiler's vmcnt(0)-before-barrier drain lands a
// full compute phase after issue (true overlap).
// EPI=1: +bias[col], max over 16-col groups -> Cf [rows x 256] fp32      (m2)
// EPI=3: +rW[row/M][col], max over 16-col groups -> Ch fp16 [rows x 256] (m1)
template <int EPI>
__global__ __launch_bounds__(512, 4) void gemmH2(
    const _Float16* __restrict__ A, const _Float16* __restrict__ Bw,
    int K, const float* __restrict__ extra,
    float* __restrict__ Cf, _Float16* __restrict__ Ch)
{
    __shared__ __align__(16) u16 sA[2][128 * 32];
    __shared__ __align__(16) u16 sB[2][256 * 32];
    const int tid = threadIdx.x;
    const int w = tid >> 6, lane = tid & 63;
    const int row0 = blockIdx.y * 128, col0 = blockIdx.x * 256;
    const int wm = w & 1, wn = w >> 1;          // 2x4 wave grid

    // staging: thread t loads 16B slots; LDS dst = base + t*16B (wave-uniform + lane*16)
    const int srow = tid >> 2;                  // 0..127
    const int scol = (tid & 3) << 3;            // 0,8,16,24 elems
    const size_t gA  = (size_t)(row0 + srow) * K + scol;
    const size_t gB0 = (size_t)(col0 + srow) * K + scol;
    const size_t gB1 = (size_t)(col0 + 128 + srow) * K + scol;

    f32x4 acc[4][4] = {};

    // prologue: fill buffer 0
    gload16((const u16*)(A  + gA),  &sA[0][tid * 8]);
    gload16((const u16*)(Bw + gB0), &sB[0][tid * 8]);
    gload16((const u16*)(Bw + gB1), &sB[0][(tid + 512) * 8]);

    const int iters = K >> 5;
    const int mrow = lane & 15;
    const int ko = (lane >> 4) << 3;

    for (int it = 0; it < iters; ++it) {
        const int cur = it & 1;
        __syncthreads();                        // drains loads into buf[cur]
        if (it + 1 < iters) {                   // prefetch k+1 into alt buffer (async)
            const int k0n = (it + 1) << 5;
            gload16((const u16*)(A  + gA  + k0n), &sA[1 - cur][tid * 8]);
            gload16((const u16*)(Bw + gB0 + k0n), &sB[1 - cur][tid * 8]);
            gload16((const u16*)(Bw + gB1 + k0n), &sB[1 - cur][(tid + 512) * 8]);
        }
        const u16* pa = &sA[cur][(wm * 64 + mrow) * 32 + ko];
        const u16* pb = &sB[cur][(wn * 64 + mrow) * 32 + ko];
        f16x8 fa[4], fb[4];
        #pragma unroll
        for (int f = 0; f < 4; ++f) {
            fa[f] = *(const f16x8*)(pa + f * 16 * 32);
            fb[f] = *(const f16x8*)(pb + f * 16 * 32);
        }
        #pragma unroll
        for (int i = 0; i < 4; ++i) {
            #pragma unroll
            for (int j = 0; j < 4; ++j) {
                acc[i][j] = __builtin_amdgcn_mfma_f32_16x16x32_f16(fa[i], fb[j], acc[i][j], 0, 0, 0);
            }
        }
    }

    // epilogue — C/D layout: col = lane&15, row = (lane>>4)*4 + reg
    const int cq = lane & 15, rq = lane >> 4;
    if (EPI == 1) {
        #pragma unroll
        for (int j = 0; j < 4; ++j) {
            int col = col0 + wn * 64 + j * 16 + cq;
            int gcol = (col0 >> 4) + wn * 4 + j;
            float bv = extra[col];
            #pragma unroll
            for (int i = 0; i < 4; ++i) {
                #pragma unroll
                for (int rr = 0; rr < 4; ++rr) {
                    float v = acc[i][j][rr] + bv;
                    v = fmaxf(v, __shfl_xor(v, 1));
                    v = fmaxf(v, __shfl_xor(v, 2));
                    v = fmaxf(v, __shfl_xor(v, 4));
                    v = fmaxf(v, __shfl_xor(v, 8));
                    if (cq == 0) {
                        int row = row0 + wm * 64 + i * 16 + rq * 4 + rr;
                        Cf[(size_t)row * H + gcol] = v;
                    }
                }
            }
        }
    } else {  // EPI == 3
        #pragma unroll
        for (int j = 0; j < 4; ++j) {
            int col = col0 + wn * 64 + j * 16 + cq;
            int gcol = (col0 >> 4) + wn * 4 + j;
            #pragma unroll
            for (int i = 0; i < 4; ++i) {
                #pragma unroll
                for (int rr = 0; rr < 4; ++rr) {
                    int row = row0 + wm * 64 + i * 16 + rq * 4 + rr;
                    int b = row / M;
                    float v = acc[i][j][rr] + extra[(size_t)b * HP + col];
                    v = fmaxf(v, __shfl_xor(v, 1));
                    v = fmaxf(v, __shfl_xor(v, 2));
                    v = fmaxf(v, __shfl_xor(v, 4));
                    v = fmaxf(v, __shfl_xor(v, 8));
                    if (cq == 0)
                        Ch[(size_t)row * H + gcol] = (_Float16)v;
                }
            }
        }
    }
}

// ---------------- tier 3 fp32 GEMM (round-2, known-pass) ----------------
template <int EPI>
__global__ __launch_bounds__(256) void gemm64(
    const float* __restrict__ Ag, int lda,
    const float* __restrict__ Bg, int ldb,
    const float* __restrict__ extra,
    float* __restrict__ C, int K, int ldc)
{
    __shared__ float As[16][68];
    __shared__ float Bs[16][68];
    const int tid = threadIdx.x;
    const int tx = tid & 15;
    const int ty = tid >> 4;
    const int row0 = blockIdx.y * 64;
    const int col0 = blockIdx.x * 64;
    const int lr = tid >> 2;
    const int lk = (tid & 3) << 2;
    const float* Aload = Ag + (size_t)(row0 + lr) * lda + lk;
    const float* Bload = Bg + (size_t)(col0 + lr) * ldb + lk;
    float acc[4][4] = {};
    for (int k0 = 0; k0 < K; k0 += 16) {
        float4 av = *(const float4*)(Aload + k0);
        float4 bv = *(const float4*)(Bload + k0);
        __syncthreads();
        As[lk + 0][lr] = av.x; As[lk + 1][lr] = av.y; As[lk + 2][lr] = av.z; As[lk + 3][lr] = av.w;
        Bs[lk + 0][lr] = bv.x; Bs[lk + 1][lr] = bv.y; Bs[lk + 2][lr] = bv.z; Bs[lk + 3][lr] = bv.w;
        __syncthreads();
        #pragma unroll
        for (int k = 0; k < 16; ++k) {
            float4 a4 = *(const float4*)(&As[k][ty << 2]);
            float4 b4 = *(const float4*)(&Bs[k][tx << 2]);
            acc[0][0] += a4.x * b4.x; acc[0][1] += a4.x * b4.y; acc[0][2] += a4.x * b4.z; acc[0][3] += a4.x * b4.w;
            acc[1][0] += a4.y * b4.x; acc[1][1] += a4.y * b4.y; acc[1][2] += a4.y * b4.z; acc[1][3] += a4.y * b4.w;
            acc[2][0] += a4.z * b4.x; acc[2][1] += a4.z * b4.y; acc[2][2] += a4.z * b4.z; acc[2][3] += a4.z * b4.w;
            acc[3][0] += a4.w * b4.x; acc[3][1] += a4.w * b4.y; acc[3][2] += a4.w * b4.z; acc[3][3] += a4.w * b4.w;
        }
    }
    if (EPI == 1) {
        const int cb = col0 + (tx << 2);
        float b0 = extra[cb], b1v = extra[cb + 1], b2v = extra[cb + 2], b3v = extra[cb + 3];
        #pragma unroll
        for (int i = 0; i < 4; ++i) {
            float mth = fmaxf(fmaxf(acc[i][0] + b0, acc[i][1] + b1v),
                              fmaxf(acc[i][2] + b2v, acc[i][3] + b3v));
            float r1 = fmaxf(mth, __shfl_xor(mth, 1));
            float r2 = fmaxf(r1, __shfl_xor(r1, 2));
            if ((tx & 3) == 0)
                C[(size_t)(row0 + (ty << 2) + i) * ldc + (col0 >> 4) + (tx >> 2)] = r2;
        }
    } else if (EPI == 2) {
        const int cb = col0 + (tx << 2);
        #pragma unroll
        for (int i = 0; i < 4; ++i) {
            int row = row0 + (ty << 2) + i;
            int b = row / M;
            const float* rw = extra + (size_t)b * HP + cb;
            float mth = fmaxf(fmaxf(acc[i][0] + rw[0], acc[i][1] + rw[1]),
                              fmaxf(acc[i][2] + rw[2], acc[i][3] + rw[3]));
            float r1 = fmaxf(mth, __shfl_xor(mth, 1));
            float r2 = fmaxf(r1, __shfl_xor(r1, 2));
            if ((tx & 3) == 0)
                C[(size_t)row * ldc + (col0 >> 4) + (tx >> 2)] = r2;
        }
    }
}

// ---------------- alpha (tier 3: fp32 m1) ----------------
__global__ __launch_bounds__(256) void k_alpha(
    const float* __restrict__ m1, const float* __restrict__ m2,
    const float* __restrict__ W12, const float* __restrict__ b12,
    const int* __restrict__ d_mask, float* __restrict__ alpha)
{
    __shared__ float Ws[16 * 512];
    const int tid = threadIdx.x;
    for (int i = tid; i < 16 * 512; i += 256) Ws[i] = W12[i];
    __syncthreads();
    const int wave = tid >> 6, lane = tid & 63;
    const int bm = blockIdx.x * 4 + wave;
    const float* r1 = m1 + (size_t)bm * H;
    const float* r2 = m2 + (size_t)bm * H;
    float acc[16] = {};
    #pragma unroll
    for (int q = 0; q < 4; ++q) {
        int k = lane + (q << 6);
        float x = r1[k];
        #pragma unroll
        for (int p = 0; p < 16; ++p) acc[p] += x * Ws[p * 512 + k];
    }
    #pragma unroll
    for (int q = 0; q < 4; ++q) {
        int k = lane + (q << 6);
        float x = r2[k];
        #pragma unroll
        for (int p = 0; p < 16; ++p) acc[p] += x * Ws[p * 512 + 256 + k];
    }
    #pragma unroll
    for (int p = 0; p < 16; ++p) {
        float v = acc[p];
        v += __shfl_xor(v, 1);  v += __shfl_xor(v, 2);  v += __shfl_xor(v, 4);
        v += __shfl_xor(v, 8);  v += __shfl_xor(v, 16); v += __shfl_xor(v, 32);
        acc[p] = v;
    }
    if (lane == 0) {
        float mx = -INFINITY;
        #pragma unroll
        for (int p = 0; p < 16; ++p) mx = fmaxf(mx, acc[p] + b12[p]);
        alpha[bm] = d_mask[bm] ? mx : -1e30f;
    }
}

// ---------------- alpha (tier 2: m1 fp16, m2 fp32) ----------------
__global__ __launch_bounds__(256) void k_alpha2(
    const _Float16* __restrict__ m1, const float* __restrict__ m2,
    const float* __restrict__ W12, const float* __restrict__ b12,
    const int* __restrict__ d_mask, float* __restrict__ alpha)
{
    __shared__ float Ws[16 * 512];
    const int tid = threadIdx.x;
    for (int i = tid; i < 16 * 512; i += 256) Ws[i] = W12[i];
    __syncthreads();
    const int wave = tid >> 6, lane = tid & 63;
    const int bm = blockIdx.x * 4 + wave;
    const _Float16* r1 = m1 + (size_t)bm * H;
    const float* r2 = m2 + (size_t)bm * H;
    float acc[16] = {};
    #pragma unroll
    for (int q = 0; q < 4; ++q) {
        int k = lane + (q << 6);
        float x = (float)r1[k];
        #pragma unroll
        for (int p = 0; p < 16; ++p) acc[p] += x * Ws[p * 512 + k];
    }
    #pragma unroll
    for (int q = 0; q < 4; ++q) {
        int k = lane + (q << 6);
        float x = r2[k];
        #pragma unroll
        for (int p = 0; p < 16; ++p) acc[p] += x * Ws[p * 512 + 256 + k];
    }
    #pragma unroll
    for (int p = 0; p < 16; ++p) {
        float v = acc[p];
        v += __shfl_xor(v, 1);  v += __shfl_xor(v, 2);  v += __shfl_xor(v, 4);
        v += __shfl_xor(v, 8);  v += __shfl_xor(v, 16); v += __shfl_xor(v, 32);
        acc[p] = v;
    }
    if (lane == 0) {
        float mx = -INFINITY;
        #pragma unroll
        for (int p = 0; p < 16; ++p) mx = fmaxf(mx, acc[p] + b12[p]);
        alpha[bm] = d_mask[bm] ? mx : -1e30f;
    }
}

// ---------------- per-b: argmax + logsumexp + loss term ----------------
__global__ __launch_bounds__(256) void k_softmax(
    const float* __restrict__ alpha, const int* __restrict__ span, int phase,
    float* __restrict__ loss_term, int* __restrict__ idx_out)
{
    __shared__ float sv[256];
    __shared__ int si[256];
    const int b = blockIdx.x, tid = threadIdx.x;
    const float* row = alpha + b * M;
    float best = -INFINITY; int bidx = 0;
    for (int m = tid; m < M; m += 256) {
        float v = row[m];
        if (v > best) { best = v; bidx = m; }
    }
    sv[tid] = best; si[tid] = bidx;
    __syncthreads();
    for (int s = 128; s > 0; s >>= 1) {
        if (tid < s) {
            float v2 = sv[tid + s]; int i2 = si[tid + s];
            if (v2 > sv[tid] || (v2 == sv[tid] && i2 < si[tid])) { sv[tid] = v2; si[tid] = i2; }
        }
        __syncthreads();
    }
    float bmax = sv[0]; int amax = si[0];
    __syncthreads();
    float ps = 0.f;
    for (int m = tid; m < M; m += 256) ps += expf(row[m] - bmax);
    sv[tid] = ps;
    __syncthreads();
    for (int s = 128; s > 0; s >>= 1) {
        if (tid < s) sv[tid] += sv[tid + s];
        __syncthreads();
    }
    if (tid == 0) {
        float lse = bmax + logf(sv[0]);
        int tgt = span[b * 2 + phase];
        loss_term[b] = -(row[tgt] - lse);
        idx_out[b] = amax;
    }
}

// ---------------- sticky-mask pointer update + loss ----------------
__global__ void k_update(const int* __restrict__ idx_in, const float* __restrict__ loss_term,
                         int* __restrict__ pos, int* __restrict__ mask,
                         int* __restrict__ prun, float* __restrict__ loss_vec, int t)
{
    int b = threadIdx.x;
    int active = (b < B) ? 1 : 0;
    int ni = 0, nm = 0;
    if (active) {
        int id = idx_in[b];
        if (t == 0) { nm = 1; ni = id; }
        else {
            int om = mask[b];
            ni = id * om;
            int prev = pos[b] * om;
            nm = (ni != prev) ? 1 : 0;
        }
    }
    float v = active ? loss_term[b] : 0.f;
    #pragma unroll
    for (int off = 32; off > 0; off >>= 1) v += __shfl_xor(v, off);
    float S = v * (1.0f / (float)B);
    if (active) {
        pos[b] = ni;
        mask[b] = nm;
        if (nm) { prun[b] = ni; loss_vec[b] += S; }
    }
}

// ---------------- finalize ----------------
__global__ void k_finalize(const float* __restrict__ loss_vec, const int* __restrict__ p1r,
                           const int* __restrict__ p2r, float* __restrict__ out)
{
    int b = threadIdx.x;
    float v = (b < B) ? loss_vec[b] : 0.f;
    #pragma unroll
    for (int off = 32; off > 0; off >>= 1) v += __shfl_xor(v, off);
    if (b == 0) out[0] = v / (float)(B * TSTEPS);
    if (b < B) {
        out[1 + b] = (float)p1r[b];
        out[1 + B + b] = (float)p2r[b];
    }
}

}  // namespace

extern "C" void kernel_launch(void* const* d_in, const int* in_sizes, int n_in,
                              void* d_out, int out_size, void* d_ws, size_t ws_size,
                              hipStream_t stream)
{
    const float* U      = (const float*)d_in[0];
    const int*   d_mask = (const int*)d_in[1];
    const int*   span   = (const int*)d_in[2];
    const float* W_ih   = (const float*)d_in[3];
    const float* W_hh   = (const float*)d_in[4];
    const float* b_ih   = (const float*)d_in[5];
    const float* b_hh   = (const float*)d_in[6];
    const float* Ws_lin = (const float*)d_in[7];
    const float* Ws_m1  = (const float*)d_in[8];
    const float* bs_m1  = (const float*)d_in[9];
    const float* Ws_m2  = (const float*)d_in[10];
    const float* bs_m2  = (const float*)d_in[11];
    const float* Ws_m12 = (const float*)d_in[12];
    const float* bs_m12 = (const float*)d_in[13];
    const float* We_lin = (const float*)d_in[14];
    const float* We_m1  = (const float*)d_in[15];
    const float* be_m1  = (const float*)d_in[16];
    const float* We_m2  = (const float*)d_in[17];
    const float* be_m2  = (const float*)d_in[18];
    const float* We_m12 = (const float*)d_in[19];
    const float* be_m12 = (const float*)d_in[20];

    // ---- workspace layout ----
    float* ws = (float*)d_ws;
    size_t o = 0;
    float* m2b   = ws + o; o += (size_t)BM * H;
    float* alphab= ws + o; o += BM;
    float* u_cat = ws + o; o += B * FOURH;
    float* gbuf  = ws + o; o += B * FOURH;
    float* hbuf  = ws + o; o += B * H;
    float* cbuf  = ws + o; o += B * H;
    float* rbuf  = ws + o; o += B * H;
    float* rWb   = ws + o; o += B * HP;
    float* loss_term = ws + o; o += B;
    float* loss_vec  = ws + o; o += B;
    int* ib = (int*)(ws + o); o += 8 * B;
    int* idxb   = ib + 0 * B;
    int* s_i    = ib + 1 * B;
    int* e_i    = ib + 2 * B;
    int* mask_s = ib + 3 * B;
    int* mask_e = ib + 4 * B;
    int* p1r    = ib + 5 * B;
    int* p2r    = ib + 6 * B;
    size_t o_common = (o + 3) & ~(size_t)3;

    // tier 3 (fp32 fallback): m1b fp32
    float* m1b = ws + o_common;

    // tier 2: transposed rW weights + fp16 region
    size_t p = o_common;
    float* Wt_s = ws + p; p += (size_t)H * HP;
    float* Wt_e = ws + p; p += (size_t)H * HP;
    _Float16* hs = (_Float16*)(ws + p);
    size_t q = 0;
    _Float16* Uh  = hs + q; q += (size_t)BM * TWOH;
    _Float16* W1s = hs + q; q += (size_t)HP * TWOH;
    _Float16* W1e = hs + q; q += (size_t)HP * TWOH;
    _Float16* W2s = hs + q; q += (size_t)HP * H;
    _Float16* W2e = hs + q; q += (size_t)HP * H;
    _Float16* m1b16 = hs + q; q += (size_t)BM * H;
    q = (q + 7) & ~(size_t)7;
    const size_t need2 = p * sizeof(float) + q * sizeof(_Float16);

    const int tier = (ws_size >= need2) ? 2 : 3;

    k_init<<<1, 256, 0, stream>>>(d_mask, hbuf, cbuf, loss_vec, s_i, e_i, p1r, p2r);

    if (tier == 2) {
        // rebuild every call (ws re-poisoned by harness)
        k_cvtH<<<BM * TWOH / 4 / 256, 256, 0, stream>>>(U, TWOH, TWOH, Uh);
        k_cvtH<<<HP * TWOH / 4 / 256, 256, 0, stream>>>(Ws_m1, THREEH, TWOH, W1s);
        k_cvtH<<<HP * TWOH / 4 / 256, 256, 0, stream>>>(We_m1, THREEH, TWOH, W1e);
        k_cvtH<<<HP * H / 4 / 256, 256, 0, stream>>>(Ws_m2, H, H, W2s);
        k_cvtH<<<HP * H / 4 / 256, 256, 0, stream>>>(We_m2, H, H, W2e);
        k_transp<<<HP * H / 256, 256, 0, stream>>>(Ws_m1, Wt_s);
        k_transp<<<HP * H / 256, 256, 0, stream>>>(We_m1, Wt_e);

        dim3 gH(HP / 256, BM / 128);  // (16, 150)
        for (int t = 0; t < TSTEPS; ++t) {
            k_gather<<<64, 256, 0, stream>>>(U, s_i, e_i, u_cat);
            k_lstm_gemm<<<128, 256, 0, stream>>>(u_cat, hbuf, W_ih, W_hh, b_ih, b_hh, gbuf);
            k_lstm_gates<<<32, 256, 0, stream>>>(gbuf, hbuf, cbuf);

            // ---- start pointer ----
            k_r<<<32, 256, 0, stream>>>(hbuf, u_cat, Ws_lin, rbuf);
            k_rW2<<<dim3(HP / 256, B), 256, 0, stream>>>(rbuf, Wt_s, bs_m1, rWb);
            gemmH2<3><<<gH, 512, 0, stream>>>(Uh, W1s, TWOH, rWb, nullptr, m1b16);
            gemmH2<1><<<gH, 512, 0, stream>>>(m1b16, W2s, H, bs_m2, m2b, nullptr);
            k_alpha2<<<BM / 4, 256, 0, stream>>>(m1b16, m2b, Ws_m12, bs_m12, d_mask, alphab);
            k_softmax<<<B, 256, 0, stream>>>(alphab, span, 0, loss_term, idxb);
            k_update<<<1, 64, 0, stream>>>(idxb, loss_term, s_i, mask_s, p1r, loss_vec, t);

            k_gather<<<64, 256, 0, stream>>>(U, s_i, e_i, u_cat);

            // ---- end pointer ----
            k_r<<<32, 256, 0, stream>>>(hbuf, u_cat, We_lin, rbuf);
            k_rW2<<<dim3(HP / 256, B), 256, 0, stream>>>(rbuf, Wt_e, be_m1, rWb);
            gemmH2<3><<<gH, 512, 0, stream>>>(Uh, W1e, TWOH, rWb, nullptr, m1b16);
            gemmH2<1><<<gH, 512, 0, stream>>>(m1b16, W2e, H, be_m2, m2b, nullptr);
            k_alpha2<<<BM / 4, 256, 0, stream>>>(m1b16, m2b, We_m12, be_m12, d_mask, alphab);
            k_softmax<<<B, 256, 0, stream>>>(alphab, span, 1, loss_term, idxb);
            k_update<<<1, 64, 0, stream>>>(idxb, loss_term, e_i, mask_e, p2r, loss_vec, t);
        }
    } else {
        // ---- tier 3: round-2 fp32 path (known-pass) ----
        dim3 gemm_grid(HP / 64, BM / 64);
        for (int t = 0; t < TSTEPS; ++t) {
            k_gather<<<64, 256, 0, stream>>>(U, s_i, e_i, u_cat);
            k_lstm_gemm<<<128, 256, 0, stream>>>(u_cat, hbuf, W_ih, W_hh, b_ih, b_hh, gbuf);
            k_lstm_gates<<<32, 256, 0, stream>>>(gbuf, hbuf, cbuf);

            k_r<<<32, 256, 0, stream>>>(hbuf, u_cat, Ws_lin, rbuf);
            k_rW<<<512, 256, 0, stream>>>(rbuf, Ws_m1, bs_m1, rWb);
            gemm64<2><<<gemm_grid, 256, 0, stream>>>(U, TWOH, Ws_m1, THREEH, rWb, m1b, TWOH, H);
            gemm64<1><<<gemm_grid, 256, 0, stream>>>(m1b, H, Ws_m2, H, bs_m2, m2b, H, H);
            k_alpha<<<BM / 4, 256, 0, stream>>>(m1b, m2b, Ws_m12, bs_m12, d_mask, alphab);
            k_softmax<<<B, 256, 0, stream>>>(alphab, span, 0, loss_term, idxb);
            k_update<<<1, 64, 0, stream>>>(idxb, loss_term, s_i, mask_s, p1r, loss_vec, t);

            k_gather<<<64, 256, 0, stream>>>(U, s_i, e_i, u_cat);

            k_r<<<32, 256, 0, stream>>>(hbuf, u_cat, We_lin, rbuf);
            k_rW<<<512, 256, 0, stream>>>(rbuf, We_m1, be_m1, rWb);
            gemm64<2><<<gemm_grid, 256, 0, stream>>>(U, TWOH, We_m1, THREEH, rWb, m1b, TWOH, H);
            gemm64<1><<<gemm_grid, 256, 0, stream>>>(m1b, H, We_m2, H, be_m2, m2b, H, H);
            k_alpha<<<BM / 4, 256, 0, stream>>>(m1b, m2b, We_m12, be_m12, d_mask, alphab);
            k_softmax<<<B, 256, 0, stream>>>(alphab, span, 1, loss_term, idxb);
            k_update<<<1, 64, 0, stream>>>(idxb, loss_term, e_i, mask_e, p2r, loss_vec, t);
        }
    }

    k_finalize<<<1, 64, 0, stream>>>(loss_vec, p1r, p2r, (float*)d_out);
}

// Round 7
// 3431.153 us; speedup vs baseline: 1.8498x; 1.0106x over previous
//
#include <hip/hip_runtime.h>
#include <math.h>

namespace {

typedef unsigned short u16;
typedef __attribute__((ext_vector_type(4))) float f32x4;
typedef __attribute__((ext_vector_type(8))) _Float16 f16x8;
typedef __attribute__((ext_vector_type(4))) _Float16 f16x4;

constexpr int B = 32;
constexpr int M = 600;
constexpr int H = 256;
constexpr int TSTEPS = 4;
constexpr int HP = 4096;          // H*P
constexpr int BM = B * M;         // 19200
constexpr int TWOH = 512;
constexpr int THREEH = 768;
constexpr int FOURH = 1024;
constexpr int FIVEH = 1280;

__device__ __forceinline__ float sigf(float x) { return 1.0f / (1.0f + expf(-x)); }

__device__ __forceinline__ void gload16(const u16* g, u16* l) {
    __builtin_amdgcn_global_load_lds(
        (const __attribute__((address_space(1))) void*)g,
        (__attribute__((address_space(3))) void*)l, 16, 0, 0);
}

// ---------------- init ----------------
__global__ void k_init(const int* __restrict__ d_mask,
                       float* __restrict__ h, float* __restrict__ c,
                       float* __restrict__ loss_vec,
                       int* __restrict__ s_i, int* __restrict__ e_i,
                       int* __restrict__ p1r, int* __restrict__ p2r)
{
    int tid = threadIdx.x;
    for (int i = tid; i < B * H; i += 256) { h[i] = 0.f; c[i] = 0.f; }
    if (tid < B) {
        loss_vec[tid] = 0.f;
        s_i[tid] = 0;
        int s = 0;
        const int* row = d_mask + tid * M;
        for (int m = 0; m < M; ++m) s += row[m];
        e_i[tid] = s - 1;
        p1r[tid] = 0; p2r[tid] = 0;
    }
}

// ---------------- gather u_cat = [U[b, s_i], U[b, e_i]] ----------------
__global__ __launch_bounds__(256) void k_gather(
    const float* __restrict__ U, const int* __restrict__ s_i,
    const int* __restrict__ e_i, float* __restrict__ u_cat)
{
    int idx = blockIdx.x * 256 + threadIdx.x;   // B*512 threads
    int b = idx >> 9, k = idx & 511;
    u_cat[b * FOURH + k]       = U[((size_t)b * M + s_i[b]) * TWOH + k];
    u_cat[b * FOURH + 512 + k] = U[((size_t)b * M + e_i[b]) * TWOH + k];
}

// ---------------- LSTM ----------------
__global__ __launch_bounds__(256) void k_lstm_gemm(
    const float* __restrict__ u_cat, const float* __restrict__ h,
    const float* __restrict__ W_ih, const float* __restrict__ W_hh,
    const float* __restrict__ b_ih, const float* __restrict__ b_hh,
    float* __restrict__ g)
{
    int idx = blockIdx.x * 256 + threadIdx.x;   // B*1024 threads
    int b = idx >> 10, j = idx & 1023;
    float acc = 0.f;
    const float4* x4 = (const float4*)(u_cat + b * FOURH);
    const float4* wi4 = (const float4*)(W_ih + (size_t)j * FOURH);
    #pragma unroll 4
    for (int k = 0; k < FOURH / 4; ++k) {
        float4 a = x4[k], w = wi4[k];
        acc += a.x * w.x + a.y * w.y + a.z * w.z + a.w * w.w;
    }
    const float4* h4 = (const float4*)(h + b * H);
    const float4* wh4 = (const float4*)(W_hh + (size_t)j * H);
    #pragma unroll 4
    for (int k = 0; k < H / 4; ++k) {
        float4 a = h4[k], w = wh4[k];
        acc += a.x * w.x + a.y * w.y + a.z * w.z + a.w * w.w;
    }
    g[idx] = acc + b_ih[j] + b_hh[j];
}

__global__ __launch_bounds__(256) void k_lstm_gates(
    const float* __restrict__ g, float* __restrict__ h, float* __restrict__ c)
{
    int idx = blockIdx.x * 256 + threadIdx.x;   // B*H
    int b = idx >> 8, i = idx & (H - 1);
    const float* gr = g + b * FOURH;
    float gi = gr[i], gf = gr[H + i], gg = gr[2 * H + i], go = gr[3 * H + i];
    float cn = sigf(gf) * c[idx] + sigf(gi) * tanhf(gg);
    c[idx] = cn;
    h[idx] = sigf(go) * tanhf(cn);
}

// ---------------- r = tanh(concat([h, u_cat]) @ W_lin.T) ----------------
__global__ __launch_bounds__(256) void k_r(
    const float* __restrict__ h, const float* __restrict__ u_cat,
    const float* __restrict__ W_lin, float* __restrict__ r)
{
    int idx = blockIdx.x * 256 + threadIdx.x;   // B*H
    int b = idx >> 8, i = idx & (H - 1);
    const float* w = W_lin + (size_t)i * FIVEH;
    float acc = 0.f;
    const float4* h4 = (const float4*)(h + b * H);
    const float4* w4 = (const float4*)w;
    #pragma unroll 4
    for (int k = 0; k < H / 4; ++k) {
        float4 a = h4[k], ww = w4[k];
        acc += a.x * ww.x + a.y * ww.y + a.z * ww.z + a.w * ww.w;
    }
    const float4* x4 = (const float4*)(u_cat + b * FOURH);
    const float4* w4b = (const float4*)(w + H);
    #pragma unroll 4
    for (int k = 0; k < FOURH / 4; ++k) {
        float4 a = x4[k], ww = w4b[k];
        acc += a.x * ww.x + a.y * ww.y + a.z * ww.z + a.w * ww.w;
    }
    r[idx] = tanhf(acc);
}

// ---------------- old strided rW (tier 3) ----------------
__global__ __launch_bounds__(256) void k_rW(
    const float* __restrict__ r, const float* __restrict__ W1,
    const float* __restrict__ b1, float* __restrict__ rW)
{
    int idx = blockIdx.x * 256 + threadIdx.x;   // B*HP
    int b = idx >> 12, j = idx & (HP - 1);
    const float4* r4 = (const float4*)(r + b * H);
    const float4* w4 = (const float4*)(W1 + (size_t)j * THREEH + TWOH);
    float acc = 0.f;
    #pragma unroll 4
    for (int k = 0; k < H / 4; ++k) {
        float4 a = r4[k], w = w4[k];
        acc += a.x * w.x + a.y * w.y + a.z * w.z + a.w * w.w;
    }
    rW[idx] = acc + b1[j];
}

// ---------------- coalesced rW via transposed weight (tier 2) ----------------
__global__ __launch_bounds__(256) void k_rW2(
    const float* __restrict__ r, const float* __restrict__ Wt,
    const float* __restrict__ b1, float* __restrict__ rW)
{
    const int b = blockIdx.y;
    const int j = blockIdx.x * 256 + threadIdx.x;
    __shared__ float sr[256];
    sr[threadIdx.x] = r[b * H + threadIdx.x];
    __syncthreads();
    float acc = b1[j];
    #pragma unroll 4
    for (int k = 0; k < H; ++k) acc += sr[k] * Wt[(size_t)k * HP + j];
    rW[(size_t)b * HP + j] = acc;
}

// ---------------- transpose W1[:, 512:768] -> Wt[256][4096] ----------------
__global__ __launch_bounds__(256) void k_transp(
    const float* __restrict__ W, float* __restrict__ Wt)
{
    int idx = blockIdx.x * 256 + threadIdx.x;   // HP*H
    int k = idx >> 12, j = idx & (HP - 1);
    Wt[idx] = W[(size_t)j * THREEH + TWOH + k];
}

// ---------------- fp32 -> fp16 converter ----------------
__global__ __launch_bounds__(256) void k_cvtH(
    const float* __restrict__ src, int ld, int Kc, _Float16* __restrict__ dst)
{
    int i4 = blockIdx.x * 256 + threadIdx.x;    // over N*Kc/4
    int perrow = Kc >> 2;
    int row = i4 / perrow;
    int kc = (i4 - row * perrow) << 2;
    float4 v = *(const float4*)(src + (size_t)row * ld + kc);
    f16x4 o;
    o[0] = (_Float16)v.x; o[1] = (_Float16)v.y; o[2] = (_Float16)v.z; o[3] = (_Float16)v.w;
    *(f16x4*)(dst + (size_t)row * Kc + kc) = o;
}

// ---------- fp16 MFMA GEMM, double-buffered + XOR-swizzled LDS: C = A @ B^T ----------
// Tile 128x256, BK=32, 512 threads (2x4 wave grid). Row r's four 16B k-groups are
// stored at physical slot  kg ^ ((r>>1)&3)  — writer permutes which global k-group
// each lane fetches (coalescing unchanged: same 64B row segments), reader XORs the
// same term. 16 fragment-read lanes then hit all 8 four-bank groups (2-way = free)
// instead of ~8-way aliasing at row-stride 64B. Accumulation order unchanged.
// EPI=1: +bias[col], max over 16-col groups -> Cf [rows x 256] fp32      (m2)
// EPI=3: +rW[row/M][col], max over 16-col groups -> Ch fp16 [rows x 256] (m1)
template <int EPI>
__global__ __launch_bounds__(512, 4) void gemmH3(
    const _Float16* __restrict__ A, const _Float16* __restrict__ Bw,
    int K, const float* __restrict__ extra,
    float* __restrict__ Cf, _Float16* __restrict__ Ch)
{
    __shared__ __align__(16) u16 sA[2][128 * 32];
    __shared__ __align__(16) u16 sB[2][256 * 32];
    const int tid = threadIdx.x;
    const int w = tid >> 6, lane = tid & 63;
    const int row0 = blockIdx.y * 128, col0 = blockIdx.x * 256;
    const int wm = w & 1, wn = w >> 1;          // 2x4 wave grid

    // staging: thread t owns LDS 16B slot t (row t>>2, phys slot t&3); it fetches the
    // global k-group  (t&3) ^ ((row>>1)&3)  so reads can de-swizzle.
    const int srow = tid >> 2;                  // 0..127
    const int kgA = (tid & 3) ^ ((srow >> 1) & 3);
    const size_t gA  = (size_t)(row0 + srow) * K + kgA * 8;
    const size_t gB0 = (size_t)(col0 + srow) * K + kgA * 8;       // (srow+128)>>1 keeps same &3
    const size_t gB1 = (size_t)(col0 + 128 + srow) * K + kgA * 8;

    f32x4 acc[4][4] = {};

    // prologue: fill buffer 0
    gload16((const u16*)(A  + gA),  &sA[0][tid * 8]);
    gload16((const u16*)(Bw + gB0), &sB[0][tid * 8]);
    gload16((const u16*)(Bw + gB1), &sB[0][(tid + 512) * 8]);

    const int iters = K >> 5;
    const int mrow = lane & 15;
    const int kg = lane >> 4;                   // 0..3
    const int slot = kg ^ ((mrow >> 1) & 3);    // de-swizzle (wave/frag offsets are ≡0 mod 4 after >>1)
    const int eoff = slot << 3;                 // element offset within 32-elem row

    for (int it = 0; it < iters; ++it) {
        const int cur = it & 1;
        __syncthreads();                        // drains loads into buf[cur]
        if (it + 1 < iters) {                   // prefetch k+1 into alt buffer (async)
            const int k0n = (it + 1) << 5;
            gload16((const u16*)(A  + gA  + k0n), &sA[1 - cur][tid * 8]);
            gload16((const u16*)(Bw + gB0 + k0n), &sB[1 - cur][tid * 8]);
            gload16((const u16*)(Bw + gB1 + k0n), &sB[1 - cur][(tid + 512) * 8]);
        }
        const u16* pa = &sA[cur][(wm * 64 + mrow) * 32 + eoff];
        const u16* pb = &sB[cur][(wn * 64 + mrow) * 32 + eoff];
        f16x8 fa[4], fb[4];
        #pragma unroll
        for (int f = 0; f < 4; ++f) {
            fa[f] = *(const f16x8*)(pa + f * 16 * 32);
            fb[f] = *(const f16x8*)(pb + f * 16 * 32);
        }
        #pragma unroll
        for (int i = 0; i < 4; ++i) {
            #pragma unroll
            for (int j = 0; j < 4; ++j) {
                acc[i][j] = __builtin_amdgcn_mfma_f32_16x16x32_f16(fa[i], fb[j], acc[i][j], 0, 0, 0);
            }
        }
    }

    // epilogue — C/D layout: col = lane&15, row = (lane>>4)*4 + reg
    const int cq = lane & 15, rq = lane >> 4;
    if (EPI == 1) {
        #pragma unroll
        for (int j = 0; j < 4; ++j) {
            int col = col0 + wn * 64 + j * 16 + cq;
            int gcol = (col0 >> 4) + wn * 4 + j;
            float bv = extra[col];
            #pragma unroll
            for (int i = 0; i < 4; ++i) {
                #pragma unroll
                for (int rr = 0; rr < 4; ++rr) {
                    float v = acc[i][j][rr] + bv;
                    v = fmaxf(v, __shfl_xor(v, 1));
                    v = fmaxf(v, __shfl_xor(v, 2));
                    v = fmaxf(v, __shfl_xor(v, 4));
                    v = fmaxf(v, __shfl_xor(v, 8));
                    if (cq == 0) {
                        int row = row0 + wm * 64 + i * 16 + rq * 4 + rr;
                        Cf[(size_t)row * H + gcol] = v;
                    }
                }
            }
        }
    } else {  // EPI == 3
        #pragma unroll
        for (int j = 0; j < 4; ++j) {
            int col = col0 + wn * 64 + j * 16 + cq;
            int gcol = (col0 >> 4) + wn * 4 + j;
            #pragma unroll
            for (int i = 0; i < 4; ++i) {
                #pragma unroll
                for (int rr = 0; rr < 4; ++rr) {
                    int row = row0 + wm * 64 + i * 16 + rq * 4 + rr;
                    int b = row / M;
                    float v = acc[i][j][rr] + extra[(size_t)b * HP + col];
                    v = fmaxf(v, __shfl_xor(v, 1));
                    v = fmaxf(v, __shfl_xor(v, 2));
                    v = fmaxf(v, __shfl_xor(v, 4));
                    v = fmaxf(v, __shfl_xor(v, 8));
                    if (cq == 0)
                        Ch[(size_t)row * H + gcol] = (_Float16)v;
                }
            }
        }
    }
}

// ---------------- tier 3 fp32 GEMM (round-2, known-pass) ----------------
template <int EPI>
__global__ __launch_bounds__(256) void gemm64(
    const float* __restrict__ Ag, int lda,
    const float* __restrict__ Bg, int ldb,
    const float* __restrict__ extra,
    float* __restrict__ C, int K, int ldc)
{
    __shared__ float As[16][68];
    __shared__ float Bs[16][68];
    const int tid = threadIdx.x;
    const int tx = tid & 15;
    const int ty = tid >> 4;
    const int row0 = blockIdx.y * 64;
    const int col0 = blockIdx.x * 64;
    const int lr = tid >> 2;
    const int lk = (tid & 3) << 2;
    const float* Aload = Ag + (size_t)(row0 + lr) * lda + lk;
    const float* Bload = Bg + (size_t)(col0 + lr) * ldb + lk;
    float acc[4][4] = {};
    for (int k0 = 0; k0 < K; k0 += 16) {
        float4 av = *(const float4*)(Aload + k0);
        float4 bv = *(const float4*)(Bload + k0);
        __syncthreads();
        As[lk + 0][lr] = av.x; As[lk + 1][lr] = av.y; As[lk + 2][lr] = av.z; As[lk + 3][lr] = av.w;
        Bs[lk + 0][lr] = bv.x; Bs[lk + 1][lr] = bv.y; Bs[lk + 2][lr] = bv.z; Bs[lk + 3][lr] = bv.w;
        __syncthreads();
        #pragma unroll
        for (int k = 0; k < 16; ++k) {
            float4 a4 = *(const float4*)(&As[k][ty << 2]);
            float4 b4 = *(const float4*)(&Bs[k][tx << 2]);
            acc[0][0] += a4.x * b4.x; acc[0][1] += a4.x * b4.y; acc[0][2] += a4.x * b4.z; acc[0][3] += a4.x * b4.w;
            acc[1][0] += a4.y * b4.x; acc[1][1] += a4.y * b4.y; acc[1][2] += a4.y * b4.z; acc[1][3] += a4.y * b4.w;
            acc[2][0] += a4.z * b4.x; acc[2][1] += a4.z * b4.y; acc[2][2] += a4.z * b4.z; acc[2][3] += a4.z * b4.w;
            acc[3][0] += a4.w * b4.x; acc[3][1] += a4.w * b4.y; acc[3][2] += a4.w * b4.z; acc[3][3] += a4.w * b4.w;
        }
    }
    if (EPI == 1) {
        const int cb = col0 + (tx << 2);
        float b0 = extra[cb], b1v = extra[cb + 1], b2v = extra[cb + 2], b3v = extra[cb + 3];
        #pragma unroll
        for (int i = 0; i < 4; ++i) {
            float mth = fmaxf(fmaxf(acc[i][0] + b0, acc[i][1] + b1v),
                              fmaxf(acc[i][2] + b2v, acc[i][3] + b3v));
            float r1 = fmaxf(mth, __shfl_xor(mth, 1));
            float r2 = fmaxf(r1, __shfl_xor(r1, 2));
            if ((tx & 3) == 0)
                C[(size_t)(row0 + (ty << 2) + i) * ldc + (col0 >> 4) + (tx >> 2)] = r2;
        }
    } else if (EPI == 2) {
        const int cb = col0 + (tx << 2);
        #pragma unroll
        for (int i = 0; i < 4; ++i) {
            int row = row0 + (ty << 2) + i;
            int b = row / M;
            const float* rw = extra + (size_t)b * HP + cb;
            float mth = fmaxf(fmaxf(acc[i][0] + rw[0], acc[i][1] + rw[1]),
                              fmaxf(acc[i][2] + rw[2], acc[i][3] + rw[3]));
            float r1 = fmaxf(mth, __shfl_xor(mth, 1));
            float r2 = fmaxf(r1, __shfl_xor(r1, 2));
            if ((tx & 3) == 0)
                C[(size_t)row * ldc + (col0 >> 4) + (tx >> 2)] = r2;
        }
    }
}

// ---------------- alpha (tier 3: fp32 m1) ----------------
__global__ __launch_bounds__(256) void k_alpha(
    const float* __restrict__ m1, const float* __restrict__ m2,
    const float* __restrict__ W12, const float* __restrict__ b12,
    const int* __restrict__ d_mask, float* __restrict__ alpha)
{
    __shared__ float Ws[16 * 512];
    const int tid = threadIdx.x;
    for (int i = tid; i < 16 * 512; i += 256) Ws[i] = W12[i];
    __syncthreads();
    const int wave = tid >> 6, lane = tid & 63;
    const int bm = blockIdx.x * 4 + wave;
    const float* r1 = m1 + (size_t)bm * H;
    const float* r2 = m2 + (size_t)bm * H;
    float acc[16] = {};
    #pragma unroll
    for (int q = 0; q < 4; ++q) {
        int k = lane + (q << 6);
        float x = r1[k];
        #pragma unroll
        for (int p = 0; p < 16; ++p) acc[p] += x * Ws[p * 512 + k];
    }
    #pragma unroll
    for (int q = 0; q < 4; ++q) {
        int k = lane + (q << 6);
        float x = r2[k];
        #pragma unroll
        for (int p = 0; p < 16; ++p) acc[p] += x * Ws[p * 512 + 256 + k];
    }
    #pragma unroll
    for (int p = 0; p < 16; ++p) {
        float v = acc[p];
        v += __shfl_xor(v, 1);  v += __shfl_xor(v, 2);  v += __shfl_xor(v, 4);
        v += __shfl_xor(v, 8);  v += __shfl_xor(v, 16); v += __shfl_xor(v, 32);
        acc[p] = v;
    }
    if (lane == 0) {
        float mx = -INFINITY;
        #pragma unroll
        for (int p = 0; p < 16; ++p) mx = fmaxf(mx, acc[p] + b12[p]);
        alpha[bm] = d_mask[bm] ? mx : -1e30f;
    }
}

// ---------------- alpha (tier 2: m1 fp16, m2 fp32) ----------------
__global__ __launch_bounds__(256) void k_alpha2(
    const _Float16* __restrict__ m1, const float* __restrict__ m2,
    const float* __restrict__ W12, const float* __restrict__ b12,
    const int* __restrict__ d_mask, float* __restrict__ alpha)
{
    __shared__ float Ws[16 * 512];
    const int tid = threadIdx.x;
    for (int i = tid; i < 16 * 512; i += 256) Ws[i] = W12[i];
    __syncthreads();
    const int wave = tid >> 6, lane = tid & 63;
    const int bm = blockIdx.x * 4 + wave;
    const _Float16* r1 = m1 + (size_t)bm * H;
    const float* r2 = m2 + (size_t)bm * H;
    float acc[16] = {};
    #pragma unroll
    for (int q = 0; q < 4; ++q) {
        int k = lane + (q << 6);
        float x = (float)r1[k];
        #pragma unroll
        for (int p = 0; p < 16; ++p) acc[p] += x * Ws[p * 512 + k];
    }
    #pragma unroll
    for (int q = 0; q < 4; ++q) {
        int k = lane + (q << 6);
        float x = r2[k];
        #pragma unroll
        for (int p = 0; p < 16; ++p) acc[p] += x * Ws[p * 512 + 256 + k];
    }
    #pragma unroll
    for (int p = 0; p < 16; ++p) {
        float v = acc[p];
        v += __shfl_xor(v, 1);  v += __shfl_xor(v, 2);  v += __shfl_xor(v, 4);
        v += __shfl_xor(v, 8);  v += __shfl_xor(v, 16); v += __shfl_xor(v, 32);
        acc[p] = v;
    }
    if (lane == 0) {
        float mx = -INFINITY;
        #pragma unroll
        for (int p = 0; p < 16; ++p) mx = fmaxf(mx, acc[p] + b12[p]);
        alpha[bm] = d_mask[bm] ? mx : -1e30f;
    }
}

// ---------------- per-b: argmax + logsumexp + loss term ----------------
__global__ __launch_bounds__(256) void k_softmax(
    const float* __restrict__ alpha, const int* __restrict__ span, int phase,
    float* __restrict__ loss_term, int* __restrict__ idx_out)
{
    __shared__ float sv[256];
    __shared__ int si[256];
    const int b = blockIdx.x, tid = threadIdx.x;
    const float* row = alpha + b * M;
    float best = -INFINITY; int bidx = 0;
    for (int m = tid; m < M; m += 256) {
        float v = row[m];
        if (v > best) { best = v; bidx = m; }
    }
    sv[tid] = best; si[tid] = bidx;
    __syncthreads();
    for (int s = 128; s > 0; s >>= 1) {
        if (tid < s) {
            float v2 = sv[tid + s]; int i2 = si[tid + s];
            if (v2 > sv[tid] || (v2 == sv[tid] && i2 < si[tid])) { sv[tid] = v2; si[tid] = i2; }
        }
        __syncthreads();
    }
    float bmax = sv[0]; int amax = si[0];
    __syncthreads();
    float ps = 0.f;
    for (int m = tid; m < M; m += 256) ps += expf(row[m] - bmax);
    sv[tid] = ps;
    __syncthreads();
    for (int s = 128; s > 0; s >>= 1) {
        if (tid < s) sv[tid] += sv[tid + s];
        __syncthreads();
    }
    if (tid == 0) {
        float lse = bmax + logf(sv[0]);
        int tgt = span[b * 2 + phase];
        loss_term[b] = -(row[tgt] - lse);
        idx_out[b] = amax;
    }
}

// ---------------- sticky-mask pointer update + loss ----------------
__global__ void k_update(const int* __restrict__ idx_in, const float* __restrict__ loss_term,
                         int* __restrict__ pos, int* __restrict__ mask,
                         int* __restrict__ prun, float* __restrict__ loss_vec, int t)
{
    int b = threadIdx.x;
    int active = (b < B) ? 1 : 0;
    int ni = 0, nm = 0;
    if (active) {
        int id = idx_in[b];
        if (t == 0) { nm = 1; ni = id; }
        else {
            int om = mask[b];
            ni = id * om;
            int prev = pos[b] * om;
            nm = (ni != prev) ? 1 : 0;
        }
    }
    float v = active ? loss_term[b] : 0.f;
    #pragma unroll
    for (int off = 32; off > 0; off >>= 1) v += __shfl_xor(v, off);
    float S = v * (1.0f / (float)B);
    if (active) {
        pos[b] = ni;
        mask[b] = nm;
        if (nm) { prun[b] = ni; loss_vec[b] += S; }
    }
}

// ---------------- finalize ----------------
__global__ void k_finalize(const float* __restrict__ loss_vec, const int* __restrict__ p1r,
                           const int* __restrict__ p2r, float* __restrict__ out)
{
    int b = threadIdx.x;
    float v = (b < B) ? loss_vec[b] : 0.f;
    #pragma unroll
    for (int off = 32; off > 0; off >>= 1) v += __shfl_xor(v, off);
    if (b == 0) out[0] = v / (float)(B * TSTEPS);
    if (b < B) {
        out[1 + b] = (float)p1r[b];
        out[1 + B + b] = (float)p2r[b];
    }
}

}  // namespace

extern "C" void kernel_launch(void* const* d_in, const int* in_sizes, int n_in,
                              void* d_out, int out_size, void* d_ws, size_t ws_size,
                              hipStream_t stream)
{
    const float* U      = (const float*)d_in[0];
    const int*   d_mask = (const int*)d_in[1];
    const int*   span   = (const int*)d_in[2];
    const float* W_ih   = (const float*)d_in[3];
    const float* W_hh   = (const float*)d_in[4];
    const float* b_ih   = (const float*)d_in[5];
    const float* b_hh   = (const float*)d_in[6];
    const float* Ws_lin = (const float*)d_in[7];
    const float* Ws_m1  = (const float*)d_in[8];
    const float* bs_m1  = (const float*)d_in[9];
    const float* Ws_m2  = (const float*)d_in[10];
    const float* bs_m2  = (const float*)d_in[11];
    const float* Ws_m12 = (const float*)d_in[12];
    const float* bs_m12 = (const float*)d_in[13];
    const float* We_lin = (const float*)d_in[14];
    const float* We_m1  = (const float*)d_in[15];
    const float* be_m1  = (const float*)d_in[16];
    const float* We_m2  = (const float*)d_in[17];
    const float* be_m2  = (const float*)d_in[18];
    const float* We_m12 = (const float*)d_in[19];
    const float* be_m12 = (const float*)d_in[20];

    // ---- workspace layout ----
    float* ws = (float*)d_ws;
    size_t o = 0;
    float* m2b   = ws + o; o += (size_t)BM * H;
    float* alphab= ws + o; o += BM;
    float* u_cat = ws + o; o += B * FOURH;
    float* gbuf  = ws + o; o += B * FOURH;
    float* hbuf  = ws + o; o += B * H;
    float* cbuf  = ws + o; o += B * H;
    float* rbuf  = ws + o; o += B * H;
    float* rWb   = ws + o; o += B * HP;
    float* loss_term = ws + o; o += B;
    float* loss_vec  = ws + o; o += B;
    int* ib = (int*)(ws + o); o += 8 * B;
    int* idxb   = ib + 0 * B;
    int* s_i    = ib + 1 * B;
    int* e_i    = ib + 2 * B;
    int* mask_s = ib + 3 * B;
    int* mask_e = ib + 4 * B;
    int* p1r    = ib + 5 * B;
    int* p2r    = ib + 6 * B;
    size_t o_common = (o + 3) & ~(size_t)3;

    // tier 3 (fp32 fallback): m1b fp32
    float* m1b = ws + o_common;

    // tier 2: transposed rW weights + fp16 region
    size_t p = o_common;
    float* Wt_s = ws + p; p += (size_t)H * HP;
    float* Wt_e = ws + p; p += (size_t)H * HP;
    _Float16* hs = (_Float16*)(ws + p);
    size_t q = 0;
    _Float16* Uh  = hs + q; q += (size_t)BM * TWOH;
    _Float16* W1s = hs + q; q += (size_t)HP * TWOH;
    _Float16* W1e = hs + q; q += (size_t)HP * TWOH;
    _Float16* W2s = hs + q; q += (size_t)HP * H;
    _Float16* W2e = hs + q; q += (size_t)HP * H;
    _Float16* m1b16 = hs + q; q += (size_t)BM * H;
    q = (q + 7) & ~(size_t)7;
    const size_t need2 = p * sizeof(float) + q * sizeof(_Float16);

    const int tier = (ws_size >= need2) ? 2 : 3;

    k_init<<<1, 256, 0, stream>>>(d_mask, hbuf, cbuf, loss_vec, s_i, e_i, p1r, p2r);

    if (tier == 2) {
        // rebuild every call (ws re-poisoned by harness)
        k_cvtH<<<BM * TWOH / 4 / 256, 256, 0, stream>>>(U, TWOH, TWOH, Uh);
        k_cvtH<<<HP * TWOH / 4 / 256, 256, 0, stream>>>(Ws_m1, THREEH, TWOH, W1s);
        k_cvtH<<<HP * TWOH / 4 / 256, 256, 0, stream>>>(We_m1, THREEH, TWOH, W1e);
        k_cvtH<<<HP * H / 4 / 256, 256, 0, stream>>>(Ws_m2, H, H, W2s);
        k_cvtH<<<HP * H / 4 / 256, 256, 0, stream>>>(We_m2, H, H, W2e);
        k_transp<<<HP * H / 256, 256, 0, stream>>>(Ws_m1, Wt_s);
        k_transp<<<HP * H / 256, 256, 0, stream>>>(We_m1, Wt_e);

        dim3 gH(HP / 256, BM / 128);  // (16, 150)
        for (int t = 0; t < TSTEPS; ++t) {
            k_gather<<<64, 256, 0, stream>>>(U, s_i, e_i, u_cat);
            k_lstm_gemm<<<128, 256, 0, stream>>>(u_cat, hbuf, W_ih, W_hh, b_ih, b_hh, gbuf);
            k_lstm_gates<<<32, 256, 0, stream>>>(gbuf, hbuf, cbuf);

            // ---- start pointer ----
            k_r<<<32, 256, 0, stream>>>(hbuf, u_cat, Ws_lin, rbuf);
            k_rW2<<<dim3(HP / 256, B), 256, 0, stream>>>(rbuf, Wt_s, bs_m1, rWb);
            gemmH3<3><<<gH, 512, 0, stream>>>(Uh, W1s, TWOH, rWb, nullptr, m1b16);
            gemmH3<1><<<gH, 512, 0, stream>>>(m1b16, W2s, H, bs_m2, m2b, nullptr);
            k_alpha2<<<BM / 4, 256, 0, stream>>>(m1b16, m2b, Ws_m12, bs_m12, d_mask, alphab);
            k_softmax<<<B, 256, 0, stream>>>(alphab, span, 0, loss_term, idxb);
            k_update<<<1, 64, 0, stream>>>(idxb, loss_term, s_i, mask_s, p1r, loss_vec, t);

            k_gather<<<64, 256, 0, stream>>>(U, s_i, e_i, u_cat);

            // ---- end pointer ----
            k_r<<<32, 256, 0, stream>>>(hbuf, u_cat, We_lin, rbuf);
            k_rW2<<<dim3(HP / 256, B), 256, 0, stream>>>(rbuf, Wt_e, be_m1, rWb);
            gemmH3<3><<<gH, 512, 0, stream>>>(Uh, W1e, TWOH, rWb, nullptr, m1b16);
            gemmH3<1><<<gH, 512, 0, stream>>>(m1b16, W2e, H, be_m2, m2b, nullptr);
            k_alpha2<<<BM / 4, 256, 0, stream>>>(m1b16, m2b, We_m12, be_m12, d_mask, alphab);
            k_softmax<<<B, 256, 0, stream>>>(alphab, span, 1, loss_term, idxb);
            k_update<<<1, 64, 0, stream>>>(idxb, loss_term, e_i, mask_e, p2r, loss_vec, t);
        }
    } else {
        // ---- tier 3: round-2 fp32 path (known-pass) ----
        dim3 gemm_grid(HP / 64, BM / 64);
        for (int t = 0; t < TSTEPS; ++t) {
            k_gather<<<64, 256, 0, stream>>>(U, s_i, e_i, u_cat);
            k_lstm_gemm<<<128, 256, 0, stream>>>(u_cat, hbuf, W_ih, W_hh, b_ih, b_hh, gbuf);
            k_lstm_gates<<<32, 256, 0, stream>>>(gbuf, hbuf, cbuf);

            k_r<<<32, 256, 0, stream>>>(hbuf, u_cat, Ws_lin, rbuf);
            k_rW<<<512, 256, 0, stream>>>(rbuf, Ws_m1, bs_m1, rWb);
            gemm64<2><<<gemm_grid, 256, 0, stream>>>(U, TWOH, Ws_m1, THREEH, rWb, m1b, TWOH, H);
            gemm64<1><<<gemm_grid, 256, 0, stream>>>(m1b, H, Ws_m2, H, bs_m2, m2b, H, H);
            k_alpha<<<BM / 4, 256, 0, stream>>>(m1b, m2b, Ws_m12, bs_m12, d_mask, alphab);
            k_softmax<<<B, 256, 0, stream>>>(alphab, span, 0, loss_term, idxb);
            k_update<<<1, 64, 0, stream>>>(idxb, loss_term, s_i, mask_s, p1r, loss_vec, t);

            k_gather<<<64, 256, 0, stream>>>(U, s_i, e_i, u_cat);

            k_r<<<32, 256, 0, stream>>>(hbuf, u_cat, We_lin, rbuf);
            k_rW<<<512, 256, 0, stream>>>(rbuf, We_m1, be_m1, rWb);
            gemm64<2><<<gemm_grid, 256, 0, stream>>>(U, TWOH, We_m1, THREEH, rWb, m1b, TWOH, H);
            gemm64<1><<<gemm_grid, 256, 0, stream>>>(m1b, H, We_m2, H, be_m2, m2b, H, H);
            k_alpha<<<BM / 4, 256, 0, stream>>>(m1b, m2b, We_m12, be_m12, d_mask, alphab);
            k_softmax<<<B, 256, 0, stream>>>(alphab, span, 1, loss_term, idxb);
            k_update<<<1, 64, 0, stream>>>(idxb, loss_term, e_i, mask_e, p2r, loss_vec, t);
        }
    }

    k_finalize<<<1, 64, 0, stream>>>(loss_vec, p1r, p2r, (float*)d_out);
}

// Round 8
// 3410.903 us; speedup vs baseline: 1.8608x; 1.0059x over previous
//
#include <hip/hip_runtime.h>
#include <math.h>

namespace {

typedef unsigned short u16;
typedef __attribute__((ext_vector_type(4))) float f32x4;
typedef __attribute__((ext_vector_type(8))) _Float16 f16x8;
typedef __attribute__((ext_vector_type(4))) _Float16 f16x4;

constexpr int B = 32;
constexpr int M = 600;
constexpr int H = 256;
constexpr int TSTEPS = 4;
constexpr int HP = 4096;          // H*P
constexpr int BM = B * M;         // 19200
constexpr int TWOH = 512;
constexpr int THREEH = 768;
constexpr int FOURH = 1024;
constexpr int FIVEH = 1280;

__device__ __forceinline__ float sigf(float x) { return 1.0f / (1.0f + expf(-x)); }

__device__ __forceinline__ void gload16(const u16* g, u16* l) {
    __builtin_amdgcn_global_load_lds(
        (const __attribute__((address_space(1))) void*)g,
        (__attribute__((address_space(3))) void*)l, 16, 0, 0);
}

// ---------------- init ----------------
__global__ void k_init(const int* __restrict__ d_mask,
                       float* __restrict__ h, float* __restrict__ c,
                       float* __restrict__ loss_vec,
                       int* __restrict__ s_i, int* __restrict__ e_i,
                       int* __restrict__ p1r, int* __restrict__ p2r)
{
    int tid = threadIdx.x;
    for (int i = tid; i < B * H; i += 256) { h[i] = 0.f; c[i] = 0.f; }
    if (tid < B) {
        loss_vec[tid] = 0.f;
        s_i[tid] = 0;
        int s = 0;
        const int* row = d_mask + tid * M;
        for (int m = 0; m < M; ++m) s += row[m];
        e_i[tid] = s - 1;
        p1r[tid] = 0; p2r[tid] = 0;
    }
}

// ---------------- gather u_cat = [U[b, s_i], U[b, e_i]] ----------------
__global__ __launch_bounds__(256) void k_gather(
    const float* __restrict__ U, const int* __restrict__ s_i,
    const int* __restrict__ e_i, float* __restrict__ u_cat)
{
    int idx = blockIdx.x * 256 + threadIdx.x;   // B*512 threads
    int b = idx >> 9, k = idx & 511;
    u_cat[b * FOURH + k]       = U[((size_t)b * M + s_i[b]) * TWOH + k];
    u_cat[b * FOURH + 512 + k] = U[((size_t)b * M + e_i[b]) * TWOH + k];
}

// ---------------- LSTM ----------------
__global__ __launch_bounds__(256) void k_lstm_gemm(
    const float* __restrict__ u_cat, const float* __restrict__ h,
    const float* __restrict__ W_ih, const float* __restrict__ W_hh,
    const float* __restrict__ b_ih, const float* __restrict__ b_hh,
    float* __restrict__ g)
{
    int idx = blockIdx.x * 256 + threadIdx.x;   // B*1024 threads
    int b = idx >> 10, j = idx & 1023;
    float acc = 0.f;
    const float4* x4 = (const float4*)(u_cat + b * FOURH);
    const float4* wi4 = (const float4*)(W_ih + (size_t)j * FOURH);
    #pragma unroll 4
    for (int k = 0; k < FOURH / 4; ++k) {
        float4 a = x4[k], w = wi4[k];
        acc += a.x * w.x + a.y * w.y + a.z * w.z + a.w * w.w;
    }
    const float4* h4 = (const float4*)(h + b * H);
    const float4* wh4 = (const float4*)(W_hh + (size_t)j * H);
    #pragma unroll 4
    for (int k = 0; k < H / 4; ++k) {
        float4 a = h4[k], w = wh4[k];
        acc += a.x * w.x + a.y * w.y + a.z * w.z + a.w * w.w;
    }
    g[idx] = acc + b_ih[j] + b_hh[j];
}

__global__ __launch_bounds__(256) void k_lstm_gates(
    const float* __restrict__ g, float* __restrict__ h, float* __restrict__ c)
{
    int idx = blockIdx.x * 256 + threadIdx.x;   // B*H
    int b = idx >> 8, i = idx & (H - 1);
    const float* gr = g + b * FOURH;
    float gi = gr[i], gf = gr[H + i], gg = gr[2 * H + i], go = gr[3 * H + i];
    float cn = sigf(gf) * c[idx] + sigf(gi) * tanhf(gg);
    c[idx] = cn;
    h[idx] = sigf(go) * tanhf(cn);
}

// ---------------- r = tanh(concat([h, u_cat]) @ W_lin.T) ----------------
__global__ __launch_bounds__(256) void k_r(
    const float* __restrict__ h, const float* __restrict__ u_cat,
    const float* __restrict__ W_lin, float* __restrict__ r)
{
    int idx = blockIdx.x * 256 + threadIdx.x;   // B*H
    int b = idx >> 8, i = idx & (H - 1);
    const float* w = W_lin + (size_t)i * FIVEH;
    float acc = 0.f;
    const float4* h4 = (const float4*)(h + b * H);
    const float4* w4 = (const float4*)w;
    #pragma unroll 4
    for (int k = 0; k < H / 4; ++k) {
        float4 a = h4[k], ww = w4[k];
        acc += a.x * ww.x + a.y * ww.y + a.z * ww.z + a.w * ww.w;
    }
    const float4* x4 = (const float4*)(u_cat + b * FOURH);
    const float4* w4b = (const float4*)(w + H);
    #pragma unroll 4
    for (int k = 0; k < FOURH / 4; ++k) {
        float4 a = x4[k], ww = w4b[k];
        acc += a.x * ww.x + a.y * ww.y + a.z * ww.z + a.w * ww.w;
    }
    r[idx] = tanhf(acc);
}

// ---------------- old strided rW (tier 3) ----------------
__global__ __launch_bounds__(256) void k_rW(
    const float* __restrict__ r, const float* __restrict__ W1,
    const float* __restrict__ b1, float* __restrict__ rW)
{
    int idx = blockIdx.x * 256 + threadIdx.x;   // B*HP
    int b = idx >> 12, j = idx & (HP - 1);
    const float4* r4 = (const float4*)(r + b * H);
    const float4* w4 = (const float4*)(W1 + (size_t)j * THREEH + TWOH);
    float acc = 0.f;
    #pragma unroll 4
    for (int k = 0; k < H / 4; ++k) {
        float4 a = r4[k], w = w4[k];
        acc += a.x * w.x + a.y * w.y + a.z * w.z + a.w * w.w;
    }
    rW[idx] = acc + b1[j];
}

// ---------------- coalesced rW via transposed weight (tiers 15/2) ----------------
__global__ __launch_bounds__(256) void k_rW2(
    const float* __restrict__ r, const float* __restrict__ Wt,
    const float* __restrict__ b1, float* __restrict__ rW)
{
    const int b = blockIdx.y;
    const int j = blockIdx.x * 256 + threadIdx.x;
    __shared__ float sr[256];
    sr[threadIdx.x] = r[b * H + threadIdx.x];
    __syncthreads();
    float acc = b1[j];
    #pragma unroll 4
    for (int k = 0; k < H; ++k) acc += sr[k] * Wt[(size_t)k * HP + j];
    rW[(size_t)b * HP + j] = acc;
}

// ---------------- transpose W1[:, 512:768] -> Wt[256][4096] ----------------
__global__ __launch_bounds__(256) void k_transp(
    const float* __restrict__ W, float* __restrict__ Wt)
{
    int idx = blockIdx.x * 256 + threadIdx.x;   // HP*H
    int k = idx >> 12, j = idx & (HP - 1);
    Wt[idx] = W[(size_t)j * THREEH + TWOH + k];
}

// ---------------- fp32 -> fp16 converter ----------------
__global__ __launch_bounds__(256) void k_cvtH(
    const float* __restrict__ src, int ld, int Kc, _Float16* __restrict__ dst)
{
    int i4 = blockIdx.x * 256 + threadIdx.x;    // over N*Kc/4
    int perrow = Kc >> 2;
    int row = i4 / perrow;
    int kc = (i4 - row * perrow) << 2;
    float4 v = *(const float4*)(src + (size_t)row * ld + kc);
    f16x4 o;
    o[0] = (_Float16)v.x; o[1] = (_Float16)v.y; o[2] = (_Float16)v.z; o[3] = (_Float16)v.w;
    *(f16x4*)(dst + (size_t)row * Kc + kc) = o;
}

// ---------- fp16 MFMA GEMM, double-buffered + XOR-swizzled LDS: C = A @ B^T ----------
// Tile 128x256, BK=32, 512 threads (2x4 wave grid). XOR k-slot swizzle kills LDS
// bank conflicts (verified: SQ_LDS_BANK_CONFLICT 9.8M -> 0, r7).
// EPI=1: +bias[col], max over 16-col groups -> Cf [rows x 256] fp32      (m2)
// EPI=3: +rW[row/M][col], max over 16-col groups -> Ch fp16 [rows x 256] (m1, tier2)
// EPI=4: plain store fp16 C [rows x 4096] into Ch                        (tier-15 precompute)
template <int EPI>
__global__ __launch_bounds__(512, 4) void gemmH3(
    const _Float16* __restrict__ A, const _Float16* __restrict__ Bw,
    int K, const float* __restrict__ extra,
    float* __restrict__ Cf, _Float16* __restrict__ Ch)
{
    __shared__ __align__(16) u16 sA[2][128 * 32];
    __shared__ __align__(16) u16 sB[2][256 * 32];
    const int tid = threadIdx.x;
    const int w = tid >> 6, lane = tid & 63;
    const int row0 = blockIdx.y * 128, col0 = blockIdx.x * 256;
    const int wm = w & 1, wn = w >> 1;          // 2x4 wave grid

    const int srow = tid >> 2;                  // 0..127
    const int kgA = (tid & 3) ^ ((srow >> 1) & 3);
    const size_t gA  = (size_t)(row0 + srow) * K + kgA * 8;
    const size_t gB0 = (size_t)(col0 + srow) * K + kgA * 8;
    const size_t gB1 = (size_t)(col0 + 128 + srow) * K + kgA * 8;

    f32x4 acc[4][4] = {};

    gload16((const u16*)(A  + gA),  &sA[0][tid * 8]);
    gload16((const u16*)(Bw + gB0), &sB[0][tid * 8]);
    gload16((const u16*)(Bw + gB1), &sB[0][(tid + 512) * 8]);

    const int iters = K >> 5;
    const int mrow = lane & 15;
    const int kg = lane >> 4;
    const int slot = kg ^ ((mrow >> 1) & 3);
    const int eoff = slot << 3;

    for (int it = 0; it < iters; ++it) {
        const int cur = it & 1;
        __syncthreads();
        if (it + 1 < iters) {
            const int k0n = (it + 1) << 5;
            gload16((const u16*)(A  + gA  + k0n), &sA[1 - cur][tid * 8]);
            gload16((const u16*)(Bw + gB0 + k0n), &sB[1 - cur][tid * 8]);
            gload16((const u16*)(Bw + gB1 + k0n), &sB[1 - cur][(tid + 512) * 8]);
        }
        const u16* pa = &sA[cur][(wm * 64 + mrow) * 32 + eoff];
        const u16* pb = &sB[cur][(wn * 64 + mrow) * 32 + eoff];
        f16x8 fa[4], fb[4];
        #pragma unroll
        for (int f = 0; f < 4; ++f) {
            fa[f] = *(const f16x8*)(pa + f * 16 * 32);
            fb[f] = *(const f16x8*)(pb + f * 16 * 32);
        }
        #pragma unroll
        for (int i = 0; i < 4; ++i) {
            #pragma unroll
            for (int j = 0; j < 4; ++j) {
                acc[i][j] = __builtin_amdgcn_mfma_f32_16x16x32_f16(fa[i], fb[j], acc[i][j], 0, 0, 0);
            }
        }
    }

    // epilogue — C/D layout: col = lane&15, row = (lane>>4)*4 + reg
    const int cq = lane & 15, rq = lane >> 4;
    if (EPI == 4) {
        #pragma unroll
        for (int i = 0; i < 4; ++i) {
            #pragma unroll
            for (int j = 0; j < 4; ++j) {
                int col = col0 + wn * 64 + j * 16 + cq;
                #pragma unroll
                for (int rr = 0; rr < 4; ++rr) {
                    int row = row0 + wm * 64 + i * 16 + rq * 4 + rr;
                    Ch[(size_t)row * HP + col] = (_Float16)acc[i][j][rr];
                }
            }
        }
    } else if (EPI == 1) {
        #pragma unroll
        for (int j = 0; j < 4; ++j) {
            int col = col0 + wn * 64 + j * 16 + cq;
            int gcol = (col0 >> 4) + wn * 4 + j;
            float bv = extra[col];
            #pragma unroll
            for (int i = 0; i < 4; ++i) {
                #pragma unroll
                for (int rr = 0; rr < 4; ++rr) {
                    float v = acc[i][j][rr] + bv;
                    v = fmaxf(v, __shfl_xor(v, 1));
                    v = fmaxf(v, __shfl_xor(v, 2));
                    v = fmaxf(v, __shfl_xor(v, 4));
                    v = fmaxf(v, __shfl_xor(v, 8));
                    if (cq == 0) {
                        int row = row0 + wm * 64 + i * 16 + rq * 4 + rr;
                        Cf[(size_t)row * H + gcol] = v;
                    }
                }
            }
        }
    } else {  // EPI == 3
        #pragma unroll
        for (int j = 0; j < 4; ++j) {
            int col = col0 + wn * 64 + j * 16 + cq;
            int gcol = (col0 >> 4) + wn * 4 + j;
            #pragma unroll
            for (int i = 0; i < 4; ++i) {
                #pragma unroll
                for (int rr = 0; rr < 4; ++rr) {
                    int row = row0 + wm * 64 + i * 16 + rq * 4 + rr;
                    int b = row / M;
                    float v = acc[i][j][rr] + extra[(size_t)b * HP + col];
                    v = fmaxf(v, __shfl_xor(v, 1));
                    v = fmaxf(v, __shfl_xor(v, 2));
                    v = fmaxf(v, __shfl_xor(v, 4));
                    v = fmaxf(v, __shfl_xor(v, 8));
                    if (cq == 0)
                        Ch[(size_t)row * H + gcol] = (_Float16)v;
                }
            }
        }
    }
}

// ---------------- tier 15: m1 = max16(A_f16 + rW) -> fp16 (HBM stream) ----------------
__global__ __launch_bounds__(256) void k_m1A16(
    const _Float16* __restrict__ A, const float* __restrict__ rW,
    _Float16* __restrict__ m1)
{
    int idx = blockIdx.x * 256 + threadIdx.x;   // bm*H + h
    int bm = idx >> 8;
    int h = idx & (H - 1);
    int b = bm / M;
    const f16x8* a8 = (const f16x8*)(A + (size_t)bm * HP + (h << 4));
    const float4* r4 = (const float4*)(rW + (size_t)b * HP + (h << 4));
    f16x8 a0 = a8[0], a1 = a8[1];
    float4 ra = r4[0], rb = r4[1], rc = r4[2], rd = r4[3];
    float mx;
    mx = fmaxf(fmaxf(fmaxf((float)a0[0] + ra.x, (float)a0[1] + ra.y),
                     fmaxf((float)a0[2] + ra.z, (float)a0[3] + ra.w)),
         fmaxf(fmaxf((float)a0[4] + rb.x, (float)a0[5] + rb.y),
               fmaxf((float)a0[6] + rb.z, (float)a0[7] + rb.w)));
    mx = fmaxf(mx,
         fmaxf(fmaxf(fmaxf((float)a1[0] + rc.x, (float)a1[1] + rc.y),
                     fmaxf((float)a1[2] + rc.z, (float)a1[3] + rc.w)),
               fmaxf(fmaxf((float)a1[4] + rd.x, (float)a1[5] + rd.y),
                     fmaxf((float)a1[6] + rd.z, (float)a1[7] + rd.w))));
    m1[idx] = (_Float16)mx;
}

// ---------------- tier 3 fp32 GEMM (round-2, known-pass) ----------------
template <int EPI>
__global__ __launch_bounds__(256) void gemm64(
    const float* __restrict__ Ag, int lda,
    const float* __restrict__ Bg, int ldb,
    const float* __restrict__ extra,
    float* __restrict__ C, int K, int ldc)
{
    __shared__ float As[16][68];
    __shared__ float Bs[16][68];
    const int tid = threadIdx.x;
    const int tx = tid & 15;
    const int ty = tid >> 4;
    const int row0 = blockIdx.y * 64;
    const int col0 = blockIdx.x * 64;
    const int lr = tid >> 2;
    const int lk = (tid & 3) << 2;
    const float* Aload = Ag + (size_t)(row0 + lr) * lda + lk;
    const float* Bload = Bg + (size_t)(col0 + lr) * ldb + lk;
    float acc[4][4] = {};
    for (int k0 = 0; k0 < K; k0 += 16) {
        float4 av = *(const float4*)(Aload + k0);
        float4 bv = *(const float4*)(Bload + k0);
        __syncthreads();
        As[lk + 0][lr] = av.x; As[lk + 1][lr] = av.y; As[lk + 2][lr] = av.z; As[lk + 3][lr] = av.w;
        Bs[lk + 0][lr] = bv.x; Bs[lk + 1][lr] = bv.y; Bs[lk + 2][lr] = bv.z; Bs[lk + 3][lr] = bv.w;
        __syncthreads();
        #pragma unroll
        for (int k = 0; k < 16; ++k) {
            float4 a4 = *(const float4*)(&As[k][ty << 2]);
            float4 b4 = *(const float4*)(&Bs[k][tx << 2]);
            acc[0][0] += a4.x * b4.x; acc[0][1] += a4.x * b4.y; acc[0][2] += a4.x * b4.z; acc[0][3] += a4.x * b4.w;
            acc[1][0] += a4.y * b4.x; acc[1][1] += a4.y * b4.y; acc[1][2] += a4.y * b4.z; acc[1][3] += a4.y * b4.w;
            acc[2][0] += a4.z * b4.x; acc[2][1] += a4.z * b4.y; acc[2][2] += a4.z * b4.z; acc[2][3] += a4.z * b4.w;
            acc[3][0] += a4.w * b4.x; acc[3][1] += a4.w * b4.y; acc[3][2] += a4.w * b4.z; acc[3][3] += a4.w * b4.w;
        }
    }
    if (EPI == 1) {
        const int cb = col0 + (tx << 2);
        float b0 = extra[cb], b1v = extra[cb + 1], b2v = extra[cb + 2], b3v = extra[cb + 3];
        #pragma unroll
        for (int i = 0; i < 4; ++i) {
            float mth = fmaxf(fmaxf(acc[i][0] + b0, acc[i][1] + b1v),
                              fmaxf(acc[i][2] + b2v, acc[i][3] + b3v));
            float r1 = fmaxf(mth, __shfl_xor(mth, 1));
            float r2 = fmaxf(r1, __shfl_xor(r1, 2));
            if ((tx & 3) == 0)
                C[(size_t)(row0 + (ty << 2) + i) * ldc + (col0 >> 4) + (tx >> 2)] = r2;
        }
    } else if (EPI == 2) {
        const int cb = col0 + (tx << 2);
        #pragma unroll
        for (int i = 0; i < 4; ++i) {
            int row = row0 + (ty << 2) + i;
            int b = row / M;
            const float* rw = extra + (size_t)b * HP + cb;
            float mth = fmaxf(fmaxf(acc[i][0] + rw[0], acc[i][1] + rw[1]),
                              fmaxf(acc[i][2] + rw[2], acc[i][3] + rw[3]));
            float r1 = fmaxf(mth, __shfl_xor(mth, 1));
            float r2 = fmaxf(r1, __shfl_xor(r1, 2));
            if ((tx & 3) == 0)
                C[(size_t)row * ldc + (col0 >> 4) + (tx >> 2)] = r2;
        }
    }
}

// ---------------- alpha (tier 3: fp32 m1) ----------------
__global__ __launch_bounds__(256) void k_alpha(
    const float* __restrict__ m1, const float* __restrict__ m2,
    const float* __restrict__ W12, const float* __restrict__ b12,
    const int* __restrict__ d_mask, float* __restrict__ alpha)
{
    __shared__ float Ws[16 * 512];
    const int tid = threadIdx.x;
    for (int i = tid; i < 16 * 512; i += 256) Ws[i] = W12[i];
    __syncthreads();
    const int wave = tid >> 6, lane = tid & 63;
    const int bm = blockIdx.x * 4 + wave;
    const float* r1 = m1 + (size_t)bm * H;
    const float* r2 = m2 + (size_t)bm * H;
    float acc[16] = {};
    #pragma unroll
    for (int q = 0; q < 4; ++q) {
        int k = lane + (q << 6);
        float x = r1[k];
        #pragma unroll
        for (int p = 0; p < 16; ++p) acc[p] += x * Ws[p * 512 + k];
    }
    #pragma unroll
    for (int q = 0; q < 4; ++q) {
        int k = lane + (q << 6);
        float x = r2[k];
        #pragma unroll
        for (int p = 0; p < 16; ++p) acc[p] += x * Ws[p * 512 + 256 + k];
    }
    #pragma unroll
    for (int p = 0; p < 16; ++p) {
        float v = acc[p];
        v += __shfl_xor(v, 1);  v += __shfl_xor(v, 2);  v += __shfl_xor(v, 4);
        v += __shfl_xor(v, 8);  v += __shfl_xor(v, 16); v += __shfl_xor(v, 32);
        acc[p] = v;
    }
    if (lane == 0) {
        float mx = -INFINITY;
        #pragma unroll
        for (int p = 0; p < 16; ++p) mx = fmaxf(mx, acc[p] + b12[p]);
        alpha[bm] = d_mask[bm] ? mx : -1e30f;
    }
}

// ---------------- alpha (tiers 15/2: m1 fp16, m2 fp32) ----------------
__global__ __launch_bounds__(256) void k_alpha2(
    const _Float16* __restrict__ m1, const float* __restrict__ m2,
    const float* __restrict__ W12, const float* __restrict__ b12,
    const int* __restrict__ d_mask, float* __restrict__ alpha)
{
    __shared__ float Ws[16 * 512];
    const int tid = threadIdx.x;
    for (int i = tid; i < 16 * 512; i += 256) Ws[i] = W12[i];
    __syncthreads();
    const int wave = tid >> 6, lane = tid & 63;
    const int bm = blockIdx.x * 4 + wave;
    const _Float16* r1 = m1 + (size_t)bm * H;
    const float* r2 = m2 + (size_t)bm * H;
    float acc[16] = {};
    #pragma unroll
    for (int q = 0; q < 4; ++q) {
        int k = lane + (q << 6);
        float x = (float)r1[k];
        #pragma unroll
        for (int p = 0; p < 16; ++p) acc[p] += x * Ws[p * 512 + k];
    }
    #pragma unroll
    for (int q = 0; q < 4; ++q) {
        int k = lane + (q << 6);
        float x = r2[k];
        #pragma unroll
        for (int p = 0; p < 16; ++p) acc[p] += x * Ws[p * 512 + 256 + k];
    }
    #pragma unroll
    for (int p = 0; p < 16; ++p) {
        float v = acc[p];
        v += __shfl_xor(v, 1);  v += __shfl_xor(v, 2);  v += __shfl_xor(v, 4);
        v += __shfl_xor(v, 8);  v += __shfl_xor(v, 16); v += __shfl_xor(v, 32);
        acc[p] = v;
    }
    if (lane == 0) {
        float mx = -INFINITY;
        #pragma unroll
        for (int p = 0; p < 16; ++p) mx = fmaxf(mx, acc[p] + b12[p]);
        alpha[bm] = d_mask[bm] ? mx : -1e30f;
    }
}

// ---------------- per-b: argmax + logsumexp + loss term ----------------
__global__ __launch_bounds__(256) void k_softmax(
    const float* __restrict__ alpha, const int* __restrict__ span, int phase,
    float* __restrict__ loss_term, int* __restrict__ idx_out)
{
    __shared__ float sv[256];
    __shared__ int si[256];
    const int b = blockIdx.x, tid = threadIdx.x;
    const float* row = alpha + b * M;
    float best = -INFINITY; int bidx = 0;
    for (int m = tid; m < M; m += 256) {
        float v = row[m];
        if (v > best) { best = v; bidx = m; }
    }
    sv[tid] = best; si[tid] = bidx;
    __syncthreads();
    for (int s = 128; s > 0; s >>= 1) {
        if (tid < s) {
            float v2 = sv[tid + s]; int i2 = si[tid + s];
            if (v2 > sv[tid] || (v2 == sv[tid] && i2 < si[tid])) { sv[tid] = v2; si[tid] = i2; }
        }
        __syncthreads();
    }
    float bmax = sv[0]; int amax = si[0];
    __syncthreads();
    float ps = 0.f;
    for (int m = tid; m < M; m += 256) ps += expf(row[m] - bmax);
    sv[tid] = ps;
    __syncthreads();
    for (int s = 128; s > 0; s >>= 1) {
        if (tid < s) sv[tid] += sv[tid + s];
        __syncthreads();
    }
    if (tid == 0) {
        float lse = bmax + logf(sv[0]);
        int tgt = span[b * 2 + phase];
        loss_term[b] = -(row[tgt] - lse);
        idx_out[b] = amax;
    }
}

// ---------------- sticky-mask pointer update + loss ----------------
__global__ void k_update(const int* __restrict__ idx_in, const float* __restrict__ loss_term,
                         int* __restrict__ pos, int* __restrict__ mask,
                         int* __restrict__ prun, float* __restrict__ loss_vec, int t)
{
    int b = threadIdx.x;
    int active = (b < B) ? 1 : 0;
    int ni = 0, nm = 0;
    if (active) {
        int id = idx_in[b];
        if (t == 0) { nm = 1; ni = id; }
        else {
            int om = mask[b];
            ni = id * om;
            int prev = pos[b] * om;
            nm = (ni != prev) ? 1 : 0;
        }
    }
    float v = active ? loss_term[b] : 0.f;
    #pragma unroll
    for (int off = 32; off > 0; off >>= 1) v += __shfl_xor(v, off);
    float S = v * (1.0f / (float)B);
    if (active) {
        pos[b] = ni;
        mask[b] = nm;
        if (nm) { prun[b] = ni; loss_vec[b] += S; }
    }
}

// ---------------- finalize ----------------
__global__ void k_finalize(const float* __restrict__ loss_vec, const int* __restrict__ p1r,
                           const int* __restrict__ p2r, float* __restrict__ out)
{
    int b = threadIdx.x;
    float v = (b < B) ? loss_vec[b] : 0.f;
    #pragma unroll
    for (int off = 32; off > 0; off >>= 1) v += __shfl_xor(v, off);
    if (b == 0) out[0] = v / (float)(B * TSTEPS);
    if (b < B) {
        out[1 + b] = (float)p1r[b];
        out[1 + B + b] = (float)p2r[b];
    }
}

}  // namespace

extern "C" void kernel_launch(void* const* d_in, const int* in_sizes, int n_in,
                              void* d_out, int out_size, void* d_ws, size_t ws_size,
                              hipStream_t stream)
{
    const float* U      = (const float*)d_in[0];
    const int*   d_mask = (const int*)d_in[1];
    const int*   span   = (const int*)d_in[2];
    const float* W_ih   = (const float*)d_in[3];
    const float* W_hh   = (const float*)d_in[4];
    const float* b_ih   = (const float*)d_in[5];
    const float* b_hh   = (const float*)d_in[6];
    const float* Ws_lin = (const float*)d_in[7];
    const float* Ws_m1  = (const float*)d_in[8];
    const float* bs_m1  = (const float*)d_in[9];
    const float* Ws_m2  = (const float*)d_in[10];
    const float* bs_m2  = (const float*)d_in[11];
    const float* Ws_m12 = (const float*)d_in[12];
    const float* bs_m12 = (const float*)d_in[13];
    const float* We_lin = (const float*)d_in[14];
    const float* We_m1  = (const float*)d_in[15];
    const float* be_m1  = (const float*)d_in[16];
    const float* We_m2  = (const float*)d_in[17];
    const float* be_m2  = (const float*)d_in[18];
    const float* We_m12 = (const float*)d_in[19];
    const float* be_m12 = (const float*)d_in[20];

    // ---- workspace layout ----
    float* ws = (float*)d_ws;
    size_t o = 0;
    float* m2b   = ws + o; o += (size_t)BM * H;
    float* alphab= ws + o; o += BM;
    float* u_cat = ws + o; o += B * FOURH;
    float* gbuf  = ws + o; o += B * FOURH;
    float* hbuf  = ws + o; o += B * H;
    float* cbuf  = ws + o; o += B * H;
    float* rbuf  = ws + o; o += B * H;
    float* rWb   = ws + o; o += B * HP;
    float* loss_term = ws + o; o += B;
    float* loss_vec  = ws + o; o += B;
    int* ib = (int*)(ws + o); o += 8 * B;
    int* idxb   = ib + 0 * B;
    int* s_i    = ib + 1 * B;
    int* e_i    = ib + 2 * B;
    int* mask_s = ib + 3 * B;
    int* mask_e = ib + 4 * B;
    int* p1r    = ib + 5 * B;
    int* p2r    = ib + 6 * B;
    size_t o_common = (o + 3) & ~(size_t)3;

    // tier 3 (fp32 fallback): m1b fp32
    float* m1b = ws + o_common;

    // tiers 15/2: transposed rW weights + fp16 region
    size_t p = o_common;
    float* Wt_s = ws + p; p += (size_t)H * HP;
    float* Wt_e = ws + p; p += (size_t)H * HP;
    _Float16* hs = (_Float16*)(ws + p);
    size_t q = 0;
    _Float16* Uh  = hs + q; q += (size_t)BM * TWOH;
    _Float16* W1s = hs + q; q += (size_t)HP * TWOH;
    _Float16* W1e = hs + q; q += (size_t)HP * TWOH;
    _Float16* W2s = hs + q; q += (size_t)HP * H;
    _Float16* W2e = hs + q; q += (size_t)HP * H;
    _Float16* m1b16 = hs + q; q += (size_t)BM * H;
    q = (q + 7) & ~(size_t)7;
    const size_t need2 = p * sizeof(float) + q * sizeof(_Float16);
    _Float16* A_s16 = hs + q;
    _Float16* A_e16 = A_s16 + (size_t)BM * HP;
    const size_t need15 = need2 + 2 * (size_t)BM * HP * sizeof(_Float16);

    const int tier = (ws_size >= need15) ? 15 : (ws_size >= need2) ? 2 : 3;

    k_init<<<1, 256, 0, stream>>>(d_mask, hbuf, cbuf, loss_vec, s_i, e_i, p1r, p2r);

    if (tier <= 15) {
        // rebuild every call (ws re-poisoned by harness)
        k_cvtH<<<BM * TWOH / 4 / 256, 256, 0, stream>>>(U, TWOH, TWOH, Uh);
        k_cvtH<<<HP * TWOH / 4 / 256, 256, 0, stream>>>(Ws_m1, THREEH, TWOH, W1s);
        k_cvtH<<<HP * TWOH / 4 / 256, 256, 0, stream>>>(We_m1, THREEH, TWOH, W1e);
        k_cvtH<<<HP * H / 4 / 256, 256, 0, stream>>>(Ws_m2, H, H, W2s);
        k_cvtH<<<HP * H / 4 / 256, 256, 0, stream>>>(We_m2, H, H, W2e);
        k_transp<<<HP * H / 256, 256, 0, stream>>>(Ws_m1, Wt_s);
        k_transp<<<HP * H / 256, 256, 0, stream>>>(We_m1, Wt_e);

        dim3 gH(HP / 256, BM / 128);  // (16, 150)
        if (tier == 15) {
            // iteration-invariant A = U @ W1u.T, stored fp16 (2x157 MB)
            gemmH3<4><<<gH, 512, 0, stream>>>(Uh, W1s, TWOH, nullptr, nullptr, A_s16);
            gemmH3<4><<<gH, 512, 0, stream>>>(Uh, W1e, TWOH, nullptr, nullptr, A_e16);
        }

        for (int t = 0; t < TSTEPS; ++t) {
            k_gather<<<64, 256, 0, stream>>>(U, s_i, e_i, u_cat);
            k_lstm_gemm<<<128, 256, 0, stream>>>(u_cat, hbuf, W_ih, W_hh, b_ih, b_hh, gbuf);
            k_lstm_gates<<<32, 256, 0, stream>>>(gbuf, hbuf, cbuf);

            // ---- start pointer ----
            k_r<<<32, 256, 0, stream>>>(hbuf, u_cat, Ws_lin, rbuf);
            k_rW2<<<dim3(HP / 256, B), 256, 0, stream>>>(rbuf, Wt_s, bs_m1, rWb);
            if (tier == 15)
                k_m1A16<<<BM * H / 256, 256, 0, stream>>>(A_s16, rWb, m1b16);
            else
                gemmH3<3><<<gH, 512, 0, stream>>>(Uh, W1s, TWOH, rWb, nullptr, m1b16);
            gemmH3<1><<<gH, 512, 0, stream>>>(m1b16, W2s, H, bs_m2, m2b, nullptr);
            k_alpha2<<<BM / 4, 256, 0, stream>>>(m1b16, m2b, Ws_m12, bs_m12, d_mask, alphab);
            k_softmax<<<B, 256, 0, stream>>>(alphab, span, 0, loss_term, idxb);
            k_update<<<1, 64, 0, stream>>>(idxb, loss_term, s_i, mask_s, p1r, loss_vec, t);

            k_gather<<<64, 256, 0, stream>>>(U, s_i, e_i, u_cat);

            // ---- end pointer ----
            k_r<<<32, 256, 0, stream>>>(hbuf, u_cat, We_lin, rbuf);
            k_rW2<<<dim3(HP / 256, B), 256, 0, stream>>>(rbuf, Wt_e, be_m1, rWb);
            if (tier == 15)
                k_m1A16<<<BM * H / 256, 256, 0, stream>>>(A_e16, rWb, m1b16);
            else
                gemmH3<3><<<gH, 512, 0, stream>>>(Uh, W1e, TWOH, rWb, nullptr, m1b16);
            gemmH3<1><<<gH, 512, 0, stream>>>(m1b16, W2e, H, be_m2, m2b, nullptr);
            k_alpha2<<<BM / 4, 256, 0, stream>>>(m1b16, m2b, We_m12, be_m12, d_mask, alphab);
            k_softmax<<<B, 256, 0, stream>>>(alphab, span, 1, loss_term, idxb);
            k_update<<<1, 64, 0, stream>>>(idxb, loss_term, e_i, mask_e, p2r, loss_vec, t);
        }
    } else {
        // ---- tier 3: round-2 fp32 path (known-pass) ----
        dim3 gemm_grid(HP / 64, BM / 64);
        for (int t = 0; t < TSTEPS; ++t) {
            k_gather<<<64, 256, 0, stream>>>(U, s_i, e_i, u_cat);
            k_lstm_gemm<<<128, 256, 0, stream>>>(u_cat, hbuf, W_ih, W_hh, b_ih, b_hh, gbuf);
            k_lstm_gates<<<32, 256, 0, stream>>>(gbuf, hbuf, cbuf);

            k_r<<<32, 256, 0, stream>>>(hbuf, u_cat, Ws_lin, rbuf);
            k_rW<<<512, 256, 0, stream>>>(rbuf, Ws_m1, bs_m1, rWb);
            gemm64<2><<<gemm_grid, 256, 0, stream>>>(U, TWOH, Ws_m1, THREEH, rWb, m1b, TWOH, H);
            gemm64<1><<<gemm_grid, 256, 0, stream>>>(m1b, H, Ws_m2, H, bs_m2, m2b, H, H);
            k_alpha<<<BM / 4, 256, 0, stream>>>(m1b, m2b, Ws_m12, bs_m12, d_mask, alphab);
            k_softmax<<<B, 256, 0, stream>>>(alphab, span, 0, loss_term, idxb);
            k_update<<<1, 64, 0, stream>>>(idxb, loss_term, s_i, mask_s, p1r, loss_vec, t);

            k_gather<<<64, 256, 0, stream>>>(U, s_i, e_i, u_cat);

            k_r<<<32, 256, 0, stream>>>(hbuf, u_cat, We_lin, rbuf);
            k_rW<<<512, 256, 0, stream>>>(rbuf, We_m1, be_m1, rWb);
            gemm64<2><<<gemm_grid, 256, 0, stream>>>(U, TWOH, We_m1, THREEH, rWb, m1b, TWOH, H);
            gemm64<1><<<gemm_grid, 256, 0, stream>>>(m1b, H, We_m2, H, be_m2, m2b, H, H);
            k_alpha<<<BM / 4, 256, 0, stream>>>(m1b, m2b, We_m12, be_m12, d_mask, alphab);
            k_softmax<<<B, 256, 0, stream>>>(alphab, span, 1, loss_term, idxb);
            k_update<<<1, 64, 0, stream>>>(idxb, loss_term, e_i, mask_e, p2r, loss_vec, t);
        }
    }

    k_finalize<<<1, 64, 0, stream>>>(loss_vec, p1r, p2r, (float*)d_out);
}

// Round 9
// 3246.733 us; speedup vs baseline: 1.9549x; 1.0506x over previous
//
#include <hip/hip_runtime.h>
#include <math.h>

namespace {

typedef unsigned short u16;
typedef __attribute__((ext_vector_type(4))) float f32x4;
typedef __attribute__((ext_vector_type(8))) _Float16 f16x8;
typedef __attribute__((ext_vector_type(4))) _Float16 f16x4;

constexpr int B = 32;
constexpr int M = 600;
constexpr int H = 256;
constexpr int TSTEPS = 4;
constexpr int HP = 4096;          // H*P
constexpr int BM = B * M;         // 19200
constexpr int TWOH = 512;
constexpr int THREEH = 768;
constexpr int FOURH = 1024;
constexpr int FIVEH = 1280;
constexpr int NTILES = BM / 128;  // 150 row tiles

__device__ __forceinline__ float sigf(float x) { return 1.0f / (1.0f + expf(-x)); }

__device__ __forceinline__ void gload16(const u16* g, u16* l) {
    __builtin_amdgcn_global_load_lds(
        (const __attribute__((address_space(1))) void*)g,
        (__attribute__((address_space(3))) void*)l, 16, 0, 0);
}

// ---------------- init ----------------
__global__ void k_init(const int* __restrict__ d_mask,
                       float* __restrict__ h, float* __restrict__ c,
                       float* __restrict__ loss_vec,
                       int* __restrict__ s_i, int* __restrict__ e_i,
                       int* __restrict__ p1r, int* __restrict__ p2r)
{
    int tid = threadIdx.x;
    for (int i = tid; i < B * H; i += 256) { h[i] = 0.f; c[i] = 0.f; }
    if (tid < B) {
        loss_vec[tid] = 0.f;
        s_i[tid] = 0;
        int s = 0;
        const int* row = d_mask + tid * M;
        for (int m = 0; m < M; ++m) s += row[m];
        e_i[tid] = s - 1;
        p1r[tid] = 0; p2r[tid] = 0;
    }
}

// ---------------- per-128-row-tile skip flags (1 = fully masked) ----------------
__global__ __launch_bounds__(128) void k_flags(const int* __restrict__ d_mask,
                                               int* __restrict__ flags)
{
    int bm = blockIdx.x * 128 + threadIdx.x;
    int cnt = __syncthreads_count(d_mask[bm]);
    if (threadIdx.x == 0) flags[blockIdx.x] = (cnt == 0) ? 1 : 0;
}

// ---------------- gather u_cat = [U[b, s_i], U[b, e_i]] ----------------
__global__ __launch_bounds__(256) void k_gather(
    const float* __restrict__ U, const int* __restrict__ s_i,
    const int* __restrict__ e_i, float* __restrict__ u_cat)
{
    int idx = blockIdx.x * 256 + threadIdx.x;   // B*512 threads
    int b = idx >> 9, k = idx & 511;
    u_cat[b * FOURH + k]       = U[((size_t)b * M + s_i[b]) * TWOH + k];
    u_cat[b * FOURH + 512 + k] = U[((size_t)b * M + e_i[b]) * TWOH + k];
}

// ---------------- LSTM ----------------
__global__ __launch_bounds__(256) void k_lstm_gemm(
    const float* __restrict__ u_cat, const float* __restrict__ h,
    const float* __restrict__ W_ih, const float* __restrict__ W_hh,
    const float* __restrict__ b_ih, const float* __restrict__ b_hh,
    float* __restrict__ g)
{
    int idx = blockIdx.x * 256 + threadIdx.x;   // B*1024 threads
    int b = idx >> 10, j = idx & 1023;
    float acc = 0.f;
    const float4* x4 = (const float4*)(u_cat + b * FOURH);
    const float4* wi4 = (const float4*)(W_ih + (size_t)j * FOURH);
    #pragma unroll 4
    for (int k = 0; k < FOURH / 4; ++k) {
        float4 a = x4[k], w = wi4[k];
        acc += a.x * w.x + a.y * w.y + a.z * w.z + a.w * w.w;
    }
    const float4* h4 = (const float4*)(h + b * H);
    const float4* wh4 = (const float4*)(W_hh + (size_t)j * H);
    #pragma unroll 4
    for (int k = 0; k < H / 4; ++k) {
        float4 a = h4[k], w = wh4[k];
        acc += a.x * w.x + a.y * w.y + a.z * w.z + a.w * w.w;
    }
    g[idx] = acc + b_ih[j] + b_hh[j];
}

__global__ __launch_bounds__(256) void k_lstm_gates(
    const float* __restrict__ g, float* __restrict__ h, float* __restrict__ c)
{
    int idx = blockIdx.x * 256 + threadIdx.x;   // B*H
    int b = idx >> 8, i = idx & (H - 1);
    const float* gr = g + b * FOURH;
    float gi = gr[i], gf = gr[H + i], gg = gr[2 * H + i], go = gr[3 * H + i];
    float cn = sigf(gf) * c[idx] + sigf(gi) * tanhf(gg);
    c[idx] = cn;
    h[idx] = sigf(go) * tanhf(cn);
}

// ---------------- r = tanh(concat([h, u_cat]) @ W_lin.T) ----------------
__global__ __launch_bounds__(256) void k_r(
    const float* __restrict__ h, const float* __restrict__ u_cat,
    const float* __restrict__ W_lin, float* __restrict__ r)
{
    int idx = blockIdx.x * 256 + threadIdx.x;   // B*H
    int b = idx >> 8, i = idx & (H - 1);
    const float* w = W_lin + (size_t)i * FIVEH;
    float acc = 0.f;
    const float4* h4 = (const float4*)(h + b * H);
    const float4* w4 = (const float4*)w;
    #pragma unroll 4
    for (int k = 0; k < H / 4; ++k) {
        float4 a = h4[k], ww = w4[k];
        acc += a.x * ww.x + a.y * ww.y + a.z * ww.z + a.w * ww.w;
    }
    const float4* x4 = (const float4*)(u_cat + b * FOURH);
    const float4* w4b = (const float4*)(w + H);
    #pragma unroll 4
    for (int k = 0; k < FOURH / 4; ++k) {
        float4 a = x4[k], ww = w4b[k];
        acc += a.x * ww.x + a.y * ww.y + a.z * ww.z + a.w * ww.w;
    }
    r[idx] = tanhf(acc);
}

// ---------------- old strided rW (tier 3) ----------------
__global__ __launch_bounds__(256) void k_rW(
    const float* __restrict__ r, const float* __restrict__ W1,
    const float* __restrict__ b1, float* __restrict__ rW)
{
    int idx = blockIdx.x * 256 + threadIdx.x;   // B*HP
    int b = idx >> 12, j = idx & (HP - 1);
    const float4* r4 = (const float4*)(r + b * H);
    const float4* w4 = (const float4*)(W1 + (size_t)j * THREEH + TWOH);
    float acc = 0.f;
    #pragma unroll 4
    for (int k = 0; k < H / 4; ++k) {
        float4 a = r4[k], w = w4[k];
        acc += a.x * w.x + a.y * w.y + a.z * w.z + a.w * w.w;
    }
    rW[idx] = acc + b1[j];
}

// ---------------- coalesced rW via transposed weight (tier 2) ----------------
__global__ __launch_bounds__(256) void k_rW2(
    const float* __restrict__ r, const float* __restrict__ Wt,
    const float* __restrict__ b1, float* __restrict__ rW)
{
    const int b = blockIdx.y;
    const int j = blockIdx.x * 256 + threadIdx.x;
    __shared__ float sr[256];
    sr[threadIdx.x] = r[b * H + threadIdx.x];
    __syncthreads();
    float acc = b1[j];
    #pragma unroll 4
    for (int k = 0; k < H; ++k) acc += sr[k] * Wt[(size_t)k * HP + j];
    rW[(size_t)b * HP + j] = acc;
}

// ---------------- transpose W1[:, 512:768] -> Wt[256][4096] ----------------
__global__ __launch_bounds__(256) void k_transp(
    const float* __restrict__ W, float* __restrict__ Wt)
{
    int idx = blockIdx.x * 256 + threadIdx.x;   // HP*H
    int k = idx >> 12, j = idx & (HP - 1);
    Wt[idx] = W[(size_t)j * THREEH + TWOH + k];
}

// ---------------- fp32 -> fp16 converter ----------------
__global__ __launch_bounds__(256) void k_cvtH(
    const float* __restrict__ src, int ld, int Kc, _Float16* __restrict__ dst)
{
    int i4 = blockIdx.x * 256 + threadIdx.x;    // over N*Kc/4
    int perrow = Kc >> 2;
    int row = i4 / perrow;
    int kc = (i4 - row * perrow) << 2;
    float4 v = *(const float4*)(src + (size_t)row * ld + kc);
    f16x4 o;
    o[0] = (_Float16)v.x; o[1] = (_Float16)v.y; o[2] = (_Float16)v.z; o[3] = (_Float16)v.w;
    *(f16x4*)(dst + (size_t)row * Kc + kc) = o;
}

// ---- fp16 MFMA GEMM: 128x128 tile, BK=32, 256 threads (2x2 waves of 64x64) ----
// Double-buffered LDS + XOR k-slot swizzle (conflict-free, verified r7). 4 blocks/CU
// (32KB LDS, <=4 waves/SIMD) = 4 independent barrier domains per CU vs r8's 2 —
// targets the barrier-drain stall (18% MfmaUtil, nothing saturated).
// skip[tile]=1 -> fully-masked row tile, early exit (values only reach output
// through alpha=-1e30 masking).
// EPI=1: +bias[col], max over 16-col groups -> Cf [rows x 256] fp32      (m2)
// EPI=3: +rW[row/M][col], max over 16-col groups -> Ch fp16 [rows x 256] (m1)
template <int EPI>
__global__ __launch_bounds__(256, 4) void gemmJ(
    const _Float16* __restrict__ A, const _Float16* __restrict__ Bw,
    int K, const float* __restrict__ extra, const int* __restrict__ skip,
    float* __restrict__ Cf, _Float16* __restrict__ Ch)
{
    if (skip[blockIdx.y]) return;
    __shared__ __align__(16) u16 sA[2][128 * 32];
    __shared__ __align__(16) u16 sB[2][128 * 32];
    const int tid = threadIdx.x;
    const int w = tid >> 6, lane = tid & 63;
    const int row0 = blockIdx.y * 128, col0 = blockIdx.x * 128;
    const int wm = w & 1, wn = w >> 1;          // 2x2 wave grid, 64x64 each

    // staging: 512 16B-slots per operand; thread t owns slots t and t+256.
    // slot s: row = s>>2, phys kslot = s&3, fetches global kg = (s&3)^((row>>1)&3)
    const int r1g = tid >> 2,        k1 = (tid & 3) ^ ((r1g >> 1) & 3);
    const int r2g = (tid + 256) >> 2, k2 = ((tid + 256) & 3) ^ ((r2g >> 1) & 3);
    const size_t gA1 = (size_t)(row0 + r1g) * K + k1 * 8;
    const size_t gA2 = (size_t)(row0 + r2g) * K + k2 * 8;
    const size_t gB1 = (size_t)(col0 + r1g) * K + k1 * 8;
    const size_t gB2 = (size_t)(col0 + r2g) * K + k2 * 8;

    f32x4 acc[4][4] = {};

    gload16((const u16*)(A  + gA1), &sA[0][tid * 8]);
    gload16((const u16*)(A  + gA2), &sA[0][(tid + 256) * 8]);
    gload16((const u16*)(Bw + gB1), &sB[0][tid * 8]);
    gload16((const u16*)(Bw + gB2), &sB[0][(tid + 256) * 8]);

    const int iters = K >> 5;
    const int mrow = lane & 15;
    const int kg = lane >> 4;
    const int slot = kg ^ ((mrow >> 1) & 3);    // de-swizzle (frag/wave row offsets ≡0 mod 8)
    const int eoff = slot << 3;

    for (int it = 0; it < iters; ++it) {
        const int cur = it & 1;
        __syncthreads();                        // drains loads into buf[cur]
        if (it + 1 < iters) {                   // prefetch k+1 into alt buffer
            const int k0n = (it + 1) << 5;
            gload16((const u16*)(A  + gA1 + k0n), &sA[1 - cur][tid * 8]);
            gload16((const u16*)(A  + gA2 + k0n), &sA[1 - cur][(tid + 256) * 8]);
            gload16((const u16*)(Bw + gB1 + k0n), &sB[1 - cur][tid * 8]);
            gload16((const u16*)(Bw + gB2 + k0n), &sB[1 - cur][(tid + 256) * 8]);
        }
        const u16* pa = &sA[cur][(wm * 64 + mrow) * 32 + eoff];
        const u16* pb = &sB[cur][(wn * 64 + mrow) * 32 + eoff];
        f16x8 fa[4], fb[4];
        #pragma unroll
        for (int f = 0; f < 4; ++f) {
            fa[f] = *(const f16x8*)(pa + f * 16 * 32);
            fb[f] = *(const f16x8*)(pb + f * 16 * 32);
        }
        #pragma unroll
        for (int i = 0; i < 4; ++i) {
            #pragma unroll
            for (int j = 0; j < 4; ++j) {
                acc[i][j] = __builtin_amdgcn_mfma_f32_16x16x32_f16(fa[i], fb[j], acc[i][j], 0, 0, 0);
            }
        }
    }

    // epilogue — C/D layout: col = lane&15, row = (lane>>4)*4 + reg
    const int cq = lane & 15, rq = lane >> 4;
    if (EPI == 1) {
        #pragma unroll
        for (int j = 0; j < 4; ++j) {
            int col = col0 + wn * 64 + j * 16 + cq;
            int gcol = (col0 >> 4) + wn * 4 + j;
            float bv = extra[col];
            #pragma unroll
            for (int i = 0; i < 4; ++i) {
                #pragma unroll
                for (int rr = 0; rr < 4; ++rr) {
                    float v = acc[i][j][rr] + bv;
                    v = fmaxf(v, __shfl_xor(v, 1));
                    v = fmaxf(v, __shfl_xor(v, 2));
                    v = fmaxf(v, __shfl_xor(v, 4));
                    v = fmaxf(v, __shfl_xor(v, 8));
                    if (cq == 0) {
                        int row = row0 + wm * 64 + i * 16 + rq * 4 + rr;
                        Cf[(size_t)row * H + gcol] = v;
                    }
                }
            }
        }
    } else {  // EPI == 3
        #pragma unroll
        for (int j = 0; j < 4; ++j) {
            int col = col0 + wn * 64 + j * 16 + cq;
            int gcol = (col0 >> 4) + wn * 4 + j;
            #pragma unroll
            for (int i = 0; i < 4; ++i) {
                #pragma unroll
                for (int rr = 0; rr < 4; ++rr) {
                    int row = row0 + wm * 64 + i * 16 + rq * 4 + rr;
                    int b = row / M;
                    float v = acc[i][j][rr] + extra[(size_t)b * HP + col];
                    v = fmaxf(v, __shfl_xor(v, 1));
                    v = fmaxf(v, __shfl_xor(v, 2));
                    v = fmaxf(v, __shfl_xor(v, 4));
                    v = fmaxf(v, __shfl_xor(v, 8));
                    if (cq == 0)
                        Ch[(size_t)row * H + gcol] = (_Float16)v;
                }
            }
        }
    }
}

// ---------------- tier 3 fp32 GEMM (round-2, known-pass) ----------------
template <int EPI>
__global__ __launch_bounds__(256) void gemm64(
    const float* __restrict__ Ag, int lda,
    const float* __restrict__ Bg, int ldb,
    const float* __restrict__ extra,
    float* __restrict__ C, int K, int ldc)
{
    __shared__ float As[16][68];
    __shared__ float Bs[16][68];
    const int tid = threadIdx.x;
    const int tx = tid & 15;
    const int ty = tid >> 4;
    const int row0 = blockIdx.y * 64;
    const int col0 = blockIdx.x * 64;
    const int lr = tid >> 2;
    const int lk = (tid & 3) << 2;
    const float* Aload = Ag + (size_t)(row0 + lr) * lda + lk;
    const float* Bload = Bg + (size_t)(col0 + lr) * ldb + lk;
    float acc[4][4] = {};
    for (int k0 = 0; k0 < K; k0 += 16) {
        float4 av = *(const float4*)(Aload + k0);
        float4 bv = *(const float4*)(Bload + k0);
        __syncthreads();
        As[lk + 0][lr] = av.x; As[lk + 1][lr] = av.y; As[lk + 2][lr] = av.z; As[lk + 3][lr] = av.w;
        Bs[lk + 0][lr] = bv.x; Bs[lk + 1][lr] = bv.y; Bs[lk + 2][lr] = bv.z; Bs[lk + 3][lr] = bv.w;
        __syncthreads();
        #pragma unroll
        for (int k = 0; k < 16; ++k) {
            float4 a4 = *(const float4*)(&As[k][ty << 2]);
            float4 b4 = *(const float4*)(&Bs[k][tx << 2]);
            acc[0][0] += a4.x * b4.x; acc[0][1] += a4.x * b4.y; acc[0][2] += a4.x * b4.z; acc[0][3] += a4.x * b4.w;
            acc[1][0] += a4.y * b4.x; acc[1][1] += a4.y * b4.y; acc[1][2] += a4.y * b4.z; acc[1][3] += a4.y * b4.w;
            acc[2][0] += a4.z * b4.x; acc[2][1] += a4.z * b4.y; acc[2][2] += a4.z * b4.z; acc[2][3] += a4.z * b4.w;
            acc[3][0] += a4.w * b4.x; acc[3][1] += a4.w * b4.y; acc[3][2] += a4.w * b4.z; acc[3][3] += a4.w * b4.w;
        }
    }
    if (EPI == 1) {
        const int cb = col0 + (tx << 2);
        float b0 = extra[cb], b1v = extra[cb + 1], b2v = extra[cb + 2], b3v = extra[cb + 3];
        #pragma unroll
        for (int i = 0; i < 4; ++i) {
            float mth = fmaxf(fmaxf(acc[i][0] + b0, acc[i][1] + b1v),
                              fmaxf(acc[i][2] + b2v, acc[i][3] + b3v));
            float r1 = fmaxf(mth, __shfl_xor(mth, 1));
            float r2 = fmaxf(r1, __shfl_xor(r1, 2));
            if ((tx & 3) == 0)
                C[(size_t)(row0 + (ty << 2) + i) * ldc + (col0 >> 4) + (tx >> 2)] = r2;
        }
    } else if (EPI == 2) {
        const int cb = col0 + (tx << 2);
        #pragma unroll
        for (int i = 0; i < 4; ++i) {
            int row = row0 + (ty << 2) + i;
            int b = row / M;
            const float* rw = extra + (size_t)b * HP + cb;
            float mth = fmaxf(fmaxf(acc[i][0] + rw[0], acc[i][1] + rw[1]),
                              fmaxf(acc[i][2] + rw[2], acc[i][3] + rw[3]));
            float r1 = fmaxf(mth, __shfl_xor(mth, 1));
            float r2 = fmaxf(r1, __shfl_xor(r1, 2));
            if ((tx & 3) == 0)
                C[(size_t)row * ldc + (col0 >> 4) + (tx >> 2)] = r2;
        }
    }
}

// ---------------- alpha (tier 3: fp32 m1) ----------------
__global__ __launch_bounds__(256) void k_alpha(
    const float* __restrict__ m1, const float* __restrict__ m2,
    const float* __restrict__ W12, const float* __restrict__ b12,
    const int* __restrict__ d_mask, float* __restrict__ alpha)
{
    __shared__ float Ws[16 * 512];
    const int tid = threadIdx.x;
    for (int i = tid; i < 16 * 512; i += 256) Ws[i] = W12[i];
    __syncthreads();
    const int wave = tid >> 6, lane = tid & 63;
    const int bm = blockIdx.x * 4 + wave;
    const float* r1 = m1 + (size_t)bm * H;
    const float* r2 = m2 + (size_t)bm * H;
    float acc[16] = {};
    #pragma unroll
    for (int q = 0; q < 4; ++q) {
        int k = lane + (q << 6);
        float x = r1[k];
        #pragma unroll
        for (int p = 0; p < 16; ++p) acc[p] += x * Ws[p * 512 + k];
    }
    #pragma unroll
    for (int q = 0; q < 4; ++q) {
        int k = lane + (q << 6);
        float x = r2[k];
        #pragma unroll
        for (int p = 0; p < 16; ++p) acc[p] += x * Ws[p * 512 + 256 + k];
    }
    #pragma unroll
    for (int p = 0; p < 16; ++p) {
        float v = acc[p];
        v += __shfl_xor(v, 1);  v += __shfl_xor(v, 2);  v += __shfl_xor(v, 4);
        v += __shfl_xor(v, 8);  v += __shfl_xor(v, 16); v += __shfl_xor(v, 32);
        acc[p] = v;
    }
    if (lane == 0) {
        float mx = -INFINITY;
        #pragma unroll
        for (int p = 0; p < 16; ++p) mx = fmaxf(mx, acc[p] + b12[p]);
        alpha[bm] = d_mask[bm] ? mx : -1e30f;
    }
}

// ---------------- alpha (tier 2: m1 fp16, m2 fp32; per-row mask skip) ----------------
__global__ __launch_bounds__(256) void k_alpha2(
    const _Float16* __restrict__ m1, const float* __restrict__ m2,
    const float* __restrict__ W12, const float* __restrict__ b12,
    const int* __restrict__ d_mask, float* __restrict__ alpha)
{
    __shared__ float Ws[16 * 512];
    const int tid = threadIdx.x;
    for (int i = tid; i < 16 * 512; i += 256) Ws[i] = W12[i];
    __syncthreads();                      // no barriers below (mask branch is safe)
    const int wave = tid >> 6, lane = tid & 63;
    const int bm = blockIdx.x * 4 + wave;
    if (!d_mask[bm]) {
        if (lane == 0) alpha[bm] = -1e30f;
        return;
    }
    const _Float16* r1 = m1 + (size_t)bm * H;
    const float* r2 = m2 + (size_t)bm * H;
    float acc[16] = {};
    #pragma unroll
    for (int q = 0; q < 4; ++q) {
        int k = lane + (q << 6);
        float x = (float)r1[k];
        #pragma unroll
        for (int p = 0; p < 16; ++p) acc[p] += x * Ws[p * 512 + k];
    }
    #pragma unroll
    for (int q = 0; q < 4; ++q) {
        int k = lane + (q << 6);
        float x = r2[k];
        #pragma unroll
        for (int p = 0; p < 16; ++p) acc[p] += x * Ws[p * 512 + 256 + k];
    }
    #pragma unroll
    for (int p = 0; p < 16; ++p) {
        float v = acc[p];
        v += __shfl_xor(v, 1);  v += __shfl_xor(v, 2);  v += __shfl_xor(v, 4);
        v += __shfl_xor(v, 8);  v += __shfl_xor(v, 16); v += __shfl_xor(v, 32);
        acc[p] = v;
    }
    if (lane == 0) {
        float mx = -INFINITY;
        #pragma unroll
        for (int p = 0; p < 16; ++p) mx = fmaxf(mx, acc[p] + b12[p]);
        alpha[bm] = mx;
    }
}

// ---------------- per-b: argmax + logsumexp + loss term ----------------
__global__ __launch_bounds__(256) void k_softmax(
    const float* __restrict__ alpha, const int* __restrict__ span, int phase,
    float* __restrict__ loss_term, int* __restrict__ idx_out)
{
    __shared__ float sv[256];
    __shared__ int si[256];
    const int b = blockIdx.x, tid = threadIdx.x;
    const float* row = alpha + b * M;
    float best = -INFINITY; int bidx = 0;
    for (int m = tid; m < M; m += 256) {
        float v = row[m];
        if (v > best) { best = v; bidx = m; }
    }
    sv[tid] = best; si[tid] = bidx;
    __syncthreads();
    for (int s = 128; s > 0; s >>= 1) {
        if (tid < s) {
            float v2 = sv[tid + s]; int i2 = si[tid + s];
            if (v2 > sv[tid] || (v2 == sv[tid] && i2 < si[tid])) { sv[tid] = v2; si[tid] = i2; }
        }
        __syncthreads();
    }
    float bmax = sv[0]; int amax = si[0];
    __syncthreads();
    float ps = 0.f;
    for (int m = tid; m < M; m += 256) ps += expf(row[m] - bmax);
    sv[tid] = ps;
    __syncthreads();
    for (int s = 128; s > 0; s >>= 1) {
        if (tid < s) sv[tid] += sv[tid + s];
        __syncthreads();
    }
    if (tid == 0) {
        float lse = bmax + logf(sv[0]);
        int tgt = span[b * 2 + phase];
        loss_term[b] = -(row[tgt] - lse);
        idx_out[b] = amax;
    }
}

// ---------------- sticky-mask pointer update + loss ----------------
__global__ void k_update(const int* __restrict__ idx_in, const float* __restrict__ loss_term,
                         int* __restrict__ pos, int* __restrict__ mask,
                         int* __restrict__ prun, float* __restrict__ loss_vec, int t)
{
    int b = threadIdx.x;
    int active = (b < B) ? 1 : 0;
    int ni = 0, nm = 0;
    if (active) {
        int id = idx_in[b];
        if (t == 0) { nm = 1; ni = id; }
        else {
            int om = mask[b];
            ni = id * om;
            int prev = pos[b] * om;
            nm = (ni != prev) ? 1 : 0;
        }
    }
    float v = active ? loss_term[b] : 0.f;
    #pragma unroll
    for (int off = 32; off > 0; off >>= 1) v += __shfl_xor(v, off);
    float S = v * (1.0f / (float)B);
    if (active) {
        pos[b] = ni;
        mask[b] = nm;
        if (nm) { prun[b] = ni; loss_vec[b] += S; }
    }
}

// ---------------- finalize ----------------
__global__ void k_finalize(const float* __restrict__ loss_vec, const int* __restrict__ p1r,
                           const int* __restrict__ p2r, float* __restrict__ out)
{
    int b = threadIdx.x;
    float v = (b < B) ? loss_vec[b] : 0.f;
    #pragma unroll
    for (int off = 32; off > 0; off >>= 1) v += __shfl_xor(v, off);
    if (b == 0) out[0] = v / (float)(B * TSTEPS);
    if (b < B) {
        out[1 + b] = (float)p1r[b];
        out[1 + B + b] = (float)p2r[b];
    }
}

}  // namespace

extern "C" void kernel_launch(void* const* d_in, const int* in_sizes, int n_in,
                              void* d_out, int out_size, void* d_ws, size_t ws_size,
                              hipStream_t stream)
{
    const float* U      = (const float*)d_in[0];
    const int*   d_mask = (const int*)d_in[1];
    const int*   span   = (const int*)d_in[2];
    const float* W_ih   = (const float*)d_in[3];
    const float* W_hh   = (const float*)d_in[4];
    const float* b_ih   = (const float*)d_in[5];
    const float* b_hh   = (const float*)d_in[6];
    const float* Ws_lin = (const float*)d_in[7];
    const float* Ws_m1  = (const float*)d_in[8];
    const float* bs_m1  = (const float*)d_in[9];
    const float* Ws_m2  = (const float*)d_in[10];
    const float* bs_m2  = (const float*)d_in[11];
    const float* Ws_m12 = (const float*)d_in[12];
    const float* bs_m12 = (const float*)d_in[13];
    const float* We_lin = (const float*)d_in[14];
    const float* We_m1  = (const float*)d_in[15];
    const float* be_m1  = (const float*)d_in[16];
    const float* We_m2  = (const float*)d_in[17];
    const float* be_m2  = (const float*)d_in[18];
    const float* We_m12 = (const float*)d_in[19];
    const float* be_m12 = (const float*)d_in[20];

    // ---- workspace layout ----
    float* ws = (float*)d_ws;
    size_t o = 0;
    float* m2b   = ws + o; o += (size_t)BM * H;
    float* alphab= ws + o; o += BM;
    float* u_cat = ws + o; o += B * FOURH;
    float* gbuf  = ws + o; o += B * FOURH;
    float* hbuf  = ws + o; o += B * H;
    float* cbuf  = ws + o; o += B * H;
    float* rbuf  = ws + o; o += B * H;
    float* rWb   = ws + o; o += B * HP;
    float* loss_term = ws + o; o += B;
    float* loss_vec  = ws + o; o += B;
    int* ib = (int*)(ws + o); o += 8 * B + 160;   // int block + 150 tile flags
    int* idxb   = ib + 0 * B;
    int* s_i    = ib + 1 * B;
    int* e_i    = ib + 2 * B;
    int* mask_s = ib + 3 * B;
    int* mask_e = ib + 4 * B;
    int* p1r    = ib + 5 * B;
    int* p2r    = ib + 6 * B;
    int* flags  = ib + 8 * B;
    size_t o_common = (o + 3) & ~(size_t)3;

    // tier 3 (fp32 fallback): m1b fp32
    float* m1b = ws + o_common;

    // tier 2: transposed rW weights + fp16 region
    size_t p = o_common;
    float* Wt_s = ws + p; p += (size_t)H * HP;
    float* Wt_e = ws + p; p += (size_t)H * HP;
    _Float16* hs = (_Float16*)(ws + p);
    size_t q = 0;
    _Float16* Uh  = hs + q; q += (size_t)BM * TWOH;
    _Float16* W1s = hs + q; q += (size_t)HP * TWOH;
    _Float16* W1e = hs + q; q += (size_t)HP * TWOH;
    _Float16* W2s = hs + q; q += (size_t)HP * H;
    _Float16* W2e = hs + q; q += (size_t)HP * H;
    _Float16* m1b16 = hs + q; q += (size_t)BM * H;
    q = (q + 7) & ~(size_t)7;
    const size_t need2 = p * sizeof(float) + q * sizeof(_Float16);

    const int tier = (ws_size >= need2) ? 2 : 3;

    k_init<<<1, 256, 0, stream>>>(d_mask, hbuf, cbuf, loss_vec, s_i, e_i, p1r, p2r);

    if (tier == 2) {
        // rebuild every call (ws re-poisoned by harness)
        k_flags<<<NTILES, 128, 0, stream>>>(d_mask, flags);
        k_cvtH<<<BM * TWOH / 4 / 256, 256, 0, stream>>>(U, TWOH, TWOH, Uh);
        k_cvtH<<<HP * TWOH / 4 / 256, 256, 0, stream>>>(Ws_m1, THREEH, TWOH, W1s);
        k_cvtH<<<HP * TWOH / 4 / 256, 256, 0, stream>>>(We_m1, THREEH, TWOH, W1e);
        k_cvtH<<<HP * H / 4 / 256, 256, 0, stream>>>(Ws_m2, H, H, W2s);
        k_cvtH<<<HP * H / 4 / 256, 256, 0, stream>>>(We_m2, H, H, W2e);
        k_transp<<<HP * H / 256, 256, 0, stream>>>(Ws_m1, Wt_s);
        k_transp<<<HP * H / 256, 256, 0, stream>>>(We_m1, Wt_e);

        dim3 gJ(HP / 128, NTILES);  // (32, 150)
        for (int t = 0; t < TSTEPS; ++t) {
            k_gather<<<64, 256, 0, stream>>>(U, s_i, e_i, u_cat);
            k_lstm_gemm<<<128, 256, 0, stream>>>(u_cat, hbuf, W_ih, W_hh, b_ih, b_hh, gbuf);
            k_lstm_gates<<<32, 256, 0, stream>>>(gbuf, hbuf, cbuf);

            // ---- start pointer ----
            k_r<<<32, 256, 0, stream>>>(hbuf, u_cat, Ws_lin, rbuf);
            k_rW2<<<dim3(HP / 256, B), 256, 0, stream>>>(rbuf, Wt_s, bs_m1, rWb);
            gemmJ<3><<<gJ, 256, 0, stream>>>(Uh, W1s, TWOH, rWb, flags, nullptr, m1b16);
            gemmJ<1><<<gJ, 256, 0, stream>>>(m1b16, W2s, H, bs_m2, flags, m2b, nullptr);
            k_alpha2<<<BM / 4, 256, 0, stream>>>(m1b16, m2b, Ws_m12, bs_m12, d_mask, alphab);
            k_softmax<<<B, 256, 0, stream>>>(alphab, span, 0, loss_term, idxb);
            k_update<<<1, 64, 0, stream>>>(idxb, loss_term, s_i, mask_s, p1r, loss_vec, t);

            k_gather<<<64, 256, 0, stream>>>(U, s_i, e_i, u_cat);

            // ---- end pointer ----
            k_r<<<32, 256, 0, stream>>>(hbuf, u_cat, We_lin, rbuf);
            k_rW2<<<dim3(HP / 256, B), 256, 0, stream>>>(rbuf, Wt_e, be_m1, rWb);
            gemmJ<3><<<gJ, 256, 0, stream>>>(Uh, W1e, TWOH, rWb, flags, nullptr, m1b16);
            gemmJ<1><<<gJ, 256, 0, stream>>>(m1b16, W2e, H, be_m2, flags, m2b, nullptr);
            k_alpha2<<<BM / 4, 256, 0, stream>>>(m1b16, m2b, We_m12, be_m12, d_mask, alphab);
            k_softmax<<<B, 256, 0, stream>>>(alphab, span, 1, loss_term, idxb);
            k_update<<<1, 64, 0, stream>>>(idxb, loss_term, e_i, mask_e, p2r, loss_vec, t);
        }
    } else {
        // ---- tier 3: round-2 fp32 path (known-pass) ----
        dim3 gemm_grid(HP / 64, BM / 64);
        for (int t = 0; t < TSTEPS; ++t) {
            k_gather<<<64, 256, 0, stream>>>(U, s_i, e_i, u_cat);
            k_lstm_gemm<<<128, 256, 0, stream>>>(u_cat, hbuf, W_ih, W_hh, b_ih, b_hh, gbuf);
            k_lstm_gates<<<32, 256, 0, stream>>>(gbuf, hbuf, cbuf);

            k_r<<<32, 256, 0, stream>>>(hbuf, u_cat, Ws_lin, rbuf);
            k_rW<<<512, 256, 0, stream>>>(rbuf, Ws_m1, bs_m1, rWb);
            gemm64<2><<<gemm_grid, 256, 0, stream>>>(U, TWOH, Ws_m1, THREEH, rWb, m1b, TWOH, H);
            gemm64<1><<<gemm_grid, 256, 0, stream>>>(m1b, H, Ws_m2, H, bs_m2, m2b, H, H);
            k_alpha<<<BM / 4, 256, 0, stream>>>(m1b, m2b, Ws_m12, bs_m12, d_mask, alphab);
            k_softmax<<<B, 256, 0, stream>>>(alphab, span, 0, loss_term, idxb);
            k_update<<<1, 64, 0, stream>>>(idxb, loss_term, s_i, mask_s, p1r, loss_vec, t);

            k_gather<<<64, 256, 0, stream>>>(U, s_i, e_i, u_cat);

            k_r<<<32, 256, 0, stream>>>(hbuf, u_cat, We_lin, rbuf);
            k_rW<<<512, 256, 0, stream>>>(rbuf, We_m1, be_m1, rWb);
            gemm64<2><<<gemm_grid, 256, 0, stream>>>(U, TWOH, We_m1, THREEH, rWb, m1b, TWOH, H);
            gemm64<1><<<gemm_grid, 256, 0, stream>>>(m1b, H, We_m2, H, be_m2, m2b, H, H);
            k_alpha<<<BM / 4, 256, 0, stream>>>(m1b, m2b, We_m12, be_m12, d_mask, alphab);
            k_softmax<<<B, 256, 0, stream>>>(alphab, span, 1, loss_term, idxb);
            k_update<<<1, 64, 0, stream>>>(idxb, loss_term, e_i, mask_e, p2r, loss_vec, t);
        }
    }

    k_finalize<<<1, 64, 0, stream>>>(loss_vec, p1r, p2r, (float*)d_out);
}

// Round 10
// 2804.195 us; speedup vs baseline: 2.2634x; 1.1578x over previous
//
#include <hip/hip_runtime.h>
#include <math.h>

namespace {

typedef unsigned short u16;
typedef __attribute__((ext_vector_type(4))) float f32x4;
typedef __attribute__((ext_vector_type(8))) _Float16 f16x8;
typedef __attribute__((ext_vector_type(4))) _Float16 f16x4;

constexpr int B = 32;
constexpr int M = 600;
constexpr int H = 256;
constexpr int TSTEPS = 4;
constexpr int HP = 4096;          // H*P
constexpr int BM = B * M;         // 19200
constexpr int TWOH = 512;
constexpr int THREEH = 768;
constexpr int FOURH = 1024;
constexpr int FIVEH = 1280;
constexpr int NTILES = BM / 128;  // 150 row tiles

__device__ __forceinline__ float sigf(float x) { return 1.0f / (1.0f + expf(-x)); }

__device__ __forceinline__ void gload16(const u16* g, u16* l) {
    __builtin_amdgcn_global_load_lds(
        (const __attribute__((address_space(1))) void*)g,
        (__attribute__((address_space(3))) void*)l, 16, 0, 0);
}

// ---------------- init ----------------
__global__ void k_init(const int* __restrict__ d_mask,
                       float* __restrict__ h, float* __restrict__ c,
                       float* __restrict__ loss_vec,
                       int* __restrict__ s_i, int* __restrict__ e_i,
                       int* __restrict__ p1r, int* __restrict__ p2r)
{
    int tid = threadIdx.x;
    for (int i = tid; i < B * H; i += 256) { h[i] = 0.f; c[i] = 0.f; }
    if (tid < B) {
        loss_vec[tid] = 0.f;
        s_i[tid] = 0;
        int s = 0;
        const int* row = d_mask + tid * M;
        for (int m = 0; m < M; ++m) s += row[m];
        e_i[tid] = s - 1;
        p1r[tid] = 0; p2r[tid] = 0;
    }
}

// ---------------- per-128-row-tile skip flags (1 = fully masked) ----------------
__global__ __launch_bounds__(128) void k_flags(const int* __restrict__ d_mask,
                                               int* __restrict__ flags)
{
    int bm = blockIdx.x * 128 + threadIdx.x;
    int cnt = __syncthreads_count(d_mask[bm]);
    if (threadIdx.x == 0) flags[blockIdx.x] = (cnt == 0) ? 1 : 0;
}

// ---------------- gather u_cat = [U[b, s_i], U[b, e_i]] ----------------
__global__ __launch_bounds__(256) void k_gather(
    const float* __restrict__ U, const int* __restrict__ s_i,
    const int* __restrict__ e_i, float* __restrict__ u_cat)
{
    int idx = blockIdx.x * 256 + threadIdx.x;   // B*512 threads
    int b = idx >> 9, k = idx & 511;
    u_cat[b * FOURH + k]       = U[((size_t)b * M + s_i[b]) * TWOH + k];
    u_cat[b * FOURH + 512 + k] = U[((size_t)b * M + e_i[b]) * TWOH + k];
}

// ---------------- LSTM ----------------
__global__ __launch_bounds__(256) void k_lstm_gemm(
    const float* __restrict__ u_cat, const float* __restrict__ h,
    const float* __restrict__ W_ih, const float* __restrict__ W_hh,
    const float* __restrict__ b_ih, const float* __restrict__ b_hh,
    float* __restrict__ g)
{
    int idx = blockIdx.x * 256 + threadIdx.x;   // B*1024 threads
    int b = idx >> 10, j = idx & 1023;
    float acc = 0.f;
    const float4* x4 = (const float4*)(u_cat + b * FOURH);
    const float4* wi4 = (const float4*)(W_ih + (size_t)j * FOURH);
    #pragma unroll 4
    for (int k = 0; k < FOURH / 4; ++k) {
        float4 a = x4[k], w = wi4[k];
        acc += a.x * w.x + a.y * w.y + a.z * w.z + a.w * w.w;
    }
    const float4* h4 = (const float4*)(h + b * H);
    const float4* wh4 = (const float4*)(W_hh + (size_t)j * H);
    #pragma unroll 4
    for (int k = 0; k < H / 4; ++k) {
        float4 a = h4[k], w = wh4[k];
        acc += a.x * w.x + a.y * w.y + a.z * w.z + a.w * w.w;
    }
    g[idx] = acc + b_ih[j] + b_hh[j];
}

__global__ __launch_bounds__(256) void k_lstm_gates(
    const float* __restrict__ g, float* __restrict__ h, float* __restrict__ c)
{
    int idx = blockIdx.x * 256 + threadIdx.x;   // B*H
    int b = idx >> 8, i = idx & (H - 1);
    const float* gr = g + b * FOURH;
    float gi = gr[i], gf = gr[H + i], gg = gr[2 * H + i], go = gr[3 * H + i];
    float cn = sigf(gf) * c[idx] + sigf(gi) * tanhf(gg);
    c[idx] = cn;
    h[idx] = sigf(go) * tanhf(cn);
}

// ---------------- r = tanh(concat([h, u_cat]) @ W_lin.T) ----------------
__global__ __launch_bounds__(256) void k_r(
    const float* __restrict__ h, const float* __restrict__ u_cat,
    const float* __restrict__ W_lin, float* __restrict__ r)
{
    int idx = blockIdx.x * 256 + threadIdx.x;   // B*H
    int b = idx >> 8, i = idx & (H - 1);
    const float* w = W_lin + (size_t)i * FIVEH;
    float acc = 0.f;
    const float4* h4 = (const float4*)(h + b * H);
    const float4* w4 = (const float4*)w;
    #pragma unroll 4
    for (int k = 0; k < H / 4; ++k) {
        float4 a = h4[k], ww = w4[k];
        acc += a.x * ww.x + a.y * ww.y + a.z * ww.z + a.w * ww.w;
    }
    const float4* x4 = (const float4*)(u_cat + b * FOURH);
    const float4* w4b = (const float4*)(w + H);
    #pragma unroll 4
    for (int k = 0; k < FOURH / 4; ++k) {
        float4 a = x4[k], ww = w4b[k];
        acc += a.x * ww.x + a.y * ww.y + a.z * ww.z + a.w * ww.w;
    }
    r[idx] = tanhf(acc);
}

// ---------------- old strided rW (tier 3) ----------------
__global__ __launch_bounds__(256) void k_rW(
    const float* __restrict__ r, const float* __restrict__ W1,
    const float* __restrict__ b1, float* __restrict__ rW)
{
    int idx = blockIdx.x * 256 + threadIdx.x;   // B*HP
    int b = idx >> 12, j = idx & (HP - 1);
    const float4* r4 = (const float4*)(r + b * H);
    const float4* w4 = (const float4*)(W1 + (size_t)j * THREEH + TWOH);
    float acc = 0.f;
    #pragma unroll 4
    for (int k = 0; k < H / 4; ++k) {
        float4 a = r4[k], w = w4[k];
        acc += a.x * w.x + a.y * w.y + a.z * w.z + a.w * w.w;
    }
    rW[idx] = acc + b1[j];
}

// ---------------- coalesced rW via transposed weight (tiers 15s/2) ----------------
__global__ __launch_bounds__(256) void k_rW2(
    const float* __restrict__ r, const float* __restrict__ Wt,
    const float* __restrict__ b1, float* __restrict__ rW)
{
    const int b = blockIdx.y;
    const int j = blockIdx.x * 256 + threadIdx.x;
    __shared__ float sr[256];
    sr[threadIdx.x] = r[b * H + threadIdx.x];
    __syncthreads();
    float acc = b1[j];
    #pragma unroll 4
    for (int k = 0; k < H; ++k) acc += sr[k] * Wt[(size_t)k * HP + j];
    rW[(size_t)b * HP + j] = acc;
}

// ---------------- transpose W1[:, 512:768] -> Wt[256][4096] ----------------
__global__ __launch_bounds__(256) void k_transp(
    const float* __restrict__ W, float* __restrict__ Wt)
{
    int idx = blockIdx.x * 256 + threadIdx.x;   // HP*H
    int k = idx >> 12, j = idx & (HP - 1);
    Wt[idx] = W[(size_t)j * THREEH + TWOH + k];
}

// ---------------- fp32 -> fp16 converter ----------------
__global__ __launch_bounds__(256) void k_cvtH(
    const float* __restrict__ src, int ld, int Kc, _Float16* __restrict__ dst)
{
    int i4 = blockIdx.x * 256 + threadIdx.x;    // over N*Kc/4
    int perrow = Kc >> 2;
    int row = i4 / perrow;
    int kc = (i4 - row * perrow) << 2;
    float4 v = *(const float4*)(src + (size_t)row * ld + kc);
    f16x4 o;
    o[0] = (_Float16)v.x; o[1] = (_Float16)v.y; o[2] = (_Float16)v.z; o[3] = (_Float16)v.w;
    *(f16x4*)(dst + (size_t)row * Kc + kc) = o;
}

// ---- fp16 MFMA GEMM: 128x128 tile, BK=32, 256 threads (2x2 waves of 64x64) ----
// Double-buffered LDS + XOR k-slot swizzle (conflict-free, verified r7).
// skip[tile]=1 -> fully-masked row tile, early exit.
// EPI=1: +bias[col], max over 16-col groups -> Cf [rows x 256] fp32      (m2)
// EPI=3: +rW[row/M][col], max over 16-col groups -> Ch fp16 [rows x 256] (m1)
// EPI=4: plain store fp16 C [rows x 4096] into Ch                        (tier-15s precompute)
template <int EPI>
__global__ __launch_bounds__(256, 4) void gemmJ(
    const _Float16* __restrict__ A, const _Float16* __restrict__ Bw,
    int K, const float* __restrict__ extra, const int* __restrict__ skip,
    float* __restrict__ Cf, _Float16* __restrict__ Ch)
{
    if (skip[blockIdx.y]) return;
    __shared__ __align__(16) u16 sA[2][128 * 32];
    __shared__ __align__(16) u16 sB[2][128 * 32];
    const int tid = threadIdx.x;
    const int w = tid >> 6, lane = tid & 63;
    const int row0 = blockIdx.y * 128, col0 = blockIdx.x * 128;
    const int wm = w & 1, wn = w >> 1;          // 2x2 wave grid, 64x64 each

    const int r1g = tid >> 2,        k1 = (tid & 3) ^ ((r1g >> 1) & 3);
    const int r2g = (tid + 256) >> 2, k2 = ((tid + 256) & 3) ^ ((r2g >> 1) & 3);
    const size_t gA1 = (size_t)(row0 + r1g) * K + k1 * 8;
    const size_t gA2 = (size_t)(row0 + r2g) * K + k2 * 8;
    const size_t gB1 = (size_t)(col0 + r1g) * K + k1 * 8;
    const size_t gB2 = (size_t)(col0 + r2g) * K + k2 * 8;

    f32x4 acc[4][4] = {};

    gload16((const u16*)(A  + gA1), &sA[0][tid * 8]);
    gload16((const u16*)(A  + gA2), &sA[0][(tid + 256) * 8]);
    gload16((const u16*)(Bw + gB1), &sB[0][tid * 8]);
    gload16((const u16*)(Bw + gB2), &sB[0][(tid + 256) * 8]);

    const int iters = K >> 5;
    const int mrow = lane & 15;
    const int kg = lane >> 4;
    const int slot = kg ^ ((mrow >> 1) & 3);
    const int eoff = slot << 3;

    for (int it = 0; it < iters; ++it) {
        const int cur = it & 1;
        __syncthreads();
        if (it + 1 < iters) {
            const int k0n = (it + 1) << 5;
            gload16((const u16*)(A  + gA1 + k0n), &sA[1 - cur][tid * 8]);
            gload16((const u16*)(A  + gA2 + k0n), &sA[1 - cur][(tid + 256) * 8]);
            gload16((const u16*)(Bw + gB1 + k0n), &sB[1 - cur][tid * 8]);
            gload16((const u16*)(Bw + gB2 + k0n), &sB[1 - cur][(tid + 256) * 8]);
        }
        const u16* pa = &sA[cur][(wm * 64 + mrow) * 32 + eoff];
        const u16* pb = &sB[cur][(wn * 64 + mrow) * 32 + eoff];
        f16x8 fa[4], fb[4];
        #pragma unroll
        for (int f = 0; f < 4; ++f) {
            fa[f] = *(const f16x8*)(pa + f * 16 * 32);
            fb[f] = *(const f16x8*)(pb + f * 16 * 32);
        }
        #pragma unroll
        for (int i = 0; i < 4; ++i) {
            #pragma unroll
            for (int j = 0; j < 4; ++j) {
                acc[i][j] = __builtin_amdgcn_mfma_f32_16x16x32_f16(fa[i], fb[j], acc[i][j], 0, 0, 0);
            }
        }
    }

    // epilogue — C/D layout: col = lane&15, row = (lane>>4)*4 + reg
    const int cq = lane & 15, rq = lane >> 4;
    if (EPI == 4) {
        #pragma unroll
        for (int i = 0; i < 4; ++i) {
            #pragma unroll
            for (int j = 0; j < 4; ++j) {
                int col = col0 + wn * 64 + j * 16 + cq;
                #pragma unroll
                for (int rr = 0; rr < 4; ++rr) {
                    int row = row0 + wm * 64 + i * 16 + rq * 4 + rr;
                    Ch[(size_t)row * HP + col] = (_Float16)acc[i][j][rr];
                }
            }
        }
    } else if (EPI == 1) {
        #pragma unroll
        for (int j = 0; j < 4; ++j) {
            int col = col0 + wn * 64 + j * 16 + cq;
            int gcol = (col0 >> 4) + wn * 4 + j;
            float bv = extra[col];
            #pragma unroll
            for (int i = 0; i < 4; ++i) {
                #pragma unroll
                for (int rr = 0; rr < 4; ++rr) {
                    float v = acc[i][j][rr] + bv;
                    v = fmaxf(v, __shfl_xor(v, 1));
                    v = fmaxf(v, __shfl_xor(v, 2));
                    v = fmaxf(v, __shfl_xor(v, 4));
                    v = fmaxf(v, __shfl_xor(v, 8));
                    if (cq == 0) {
                        int row = row0 + wm * 64 + i * 16 + rq * 4 + rr;
                        Cf[(size_t)row * H + gcol] = v;
                    }
                }
            }
        }
    } else {  // EPI == 3
        #pragma unroll
        for (int j = 0; j < 4; ++j) {
            int col = col0 + wn * 64 + j * 16 + cq;
            int gcol = (col0 >> 4) + wn * 4 + j;
            #pragma unroll
            for (int i = 0; i < 4; ++i) {
                #pragma unroll
                for (int rr = 0; rr < 4; ++rr) {
                    int row = row0 + wm * 64 + i * 16 + rq * 4 + rr;
                    int b = row / M;
                    float v = acc[i][j][rr] + extra[(size_t)b * HP + col];
                    v = fmaxf(v, __shfl_xor(v, 1));
                    v = fmaxf(v, __shfl_xor(v, 2));
                    v = fmaxf(v, __shfl_xor(v, 4));
                    v = fmaxf(v, __shfl_xor(v, 8));
                    if (cq == 0)
                        Ch[(size_t)row * H + gcol] = (_Float16)v;
                }
            }
        }
    }
}

// ------- tier 15s: m1 = max16(A_f16 + rW) -> fp16 (HBM stream, s-phase only) -------
__global__ __launch_bounds__(256) void k_m1A16(
    const _Float16* __restrict__ A, const float* __restrict__ rW,
    _Float16* __restrict__ m1)
{
    int idx = blockIdx.x * 256 + threadIdx.x;   // bm*H + h
    int bm = idx >> 8;
    int h = idx & (H - 1);
    int b = bm / M;
    const f16x8* a8 = (const f16x8*)(A + (size_t)bm * HP + (h << 4));
    const float4* r4 = (const float4*)(rW + (size_t)b * HP + (h << 4));
    f16x8 a0 = a8[0], a1 = a8[1];
    float4 ra = r4[0], rb = r4[1], rc = r4[2], rd = r4[3];
    float mx;
    mx = fmaxf(fmaxf(fmaxf((float)a0[0] + ra.x, (float)a0[1] + ra.y),
                     fmaxf((float)a0[2] + ra.z, (float)a0[3] + ra.w)),
         fmaxf(fmaxf((float)a0[4] + rb.x, (float)a0[5] + rb.y),
               fmaxf((float)a0[6] + rb.z, (float)a0[7] + rb.w)));
    mx = fmaxf(mx,
         fmaxf(fmaxf(fmaxf((float)a1[0] + rc.x, (float)a1[1] + rc.y),
                     fmaxf((float)a1[2] + rc.z, (float)a1[3] + rc.w)),
               fmaxf(fmaxf((float)a1[4] + rd.x, (float)a1[5] + rd.y),
                     fmaxf((float)a1[6] + rd.z, (float)a1[7] + rd.w))));
    m1[idx] = (_Float16)mx;
}

// ---------------- tier 3 fp32 GEMM (round-2, known-pass) ----------------
template <int EPI>
__global__ __launch_bounds__(256) void gemm64(
    const float* __restrict__ Ag, int lda,
    const float* __restrict__ Bg, int ldb,
    const float* __restrict__ extra,
    float* __restrict__ C, int K, int ldc)
{
    __shared__ float As[16][68];
    __shared__ float Bs[16][68];
    const int tid = threadIdx.x;
    const int tx = tid & 15;
    const int ty = tid >> 4;
    const int row0 = blockIdx.y * 64;
    const int col0 = blockIdx.x * 64;
    const int lr = tid >> 2;
    const int lk = (tid & 3) << 2;
    const float* Aload = Ag + (size_t)(row0 + lr) * lda + lk;
    const float* Bload = Bg + (size_t)(col0 + lr) * ldb + lk;
    float acc[4][4] = {};
    for (int k0 = 0; k0 < K; k0 += 16) {
        float4 av = *(const float4*)(Aload + k0);
        float4 bv = *(const float4*)(Bload + k0);
        __syncthreads();
        As[lk + 0][lr] = av.x; As[lk + 1][lr] = av.y; As[lk + 2][lr] = av.z; As[lk + 3][lr] = av.w;
        Bs[lk + 0][lr] = bv.x; Bs[lk + 1][lr] = bv.y; Bs[lk + 2][lr] = bv.z; Bs[lk + 3][lr] = bv.w;
        __syncthreads();
        #pragma unroll
        for (int k = 0; k < 16; ++k) {
            float4 a4 = *(const float4*)(&As[k][ty << 2]);
            float4 b4 = *(const float4*)(&Bs[k][tx << 2]);
            acc[0][0] += a4.x * b4.x; acc[0][1] += a4.x * b4.y; acc[0][2] += a4.x * b4.z; acc[0][3] += a4.x * b4.w;
            acc[1][0] += a4.y * b4.x; acc[1][1] += a4.y * b4.y; acc[1][2] += a4.y * b4.z; acc[1][3] += a4.y * b4.w;
            acc[2][0] += a4.z * b4.x; acc[2][1] += a4.z * b4.y; acc[2][2] += a4.z * b4.z; acc[2][3] += a4.z * b4.w;
            acc[3][0] += a4.w * b4.x; acc[3][1] += a4.w * b4.y; acc[3][2] += a4.w * b4.z; acc[3][3] += a4.w * b4.w;
        }
    }
    if (EPI == 1) {
        const int cb = col0 + (tx << 2);
        float b0 = extra[cb], b1v = extra[cb + 1], b2v = extra[cb + 2], b3v = extra[cb + 3];
        #pragma unroll
        for (int i = 0; i < 4; ++i) {
            float mth = fmaxf(fmaxf(acc[i][0] + b0, acc[i][1] + b1v),
                              fmaxf(acc[i][2] + b2v, acc[i][3] + b3v));
            float r1 = fmaxf(mth, __shfl_xor(mth, 1));
            float r2 = fmaxf(r1, __shfl_xor(r1, 2));
            if ((tx & 3) == 0)
                C[(size_t)(row0 + (ty << 2) + i) * ldc + (col0 >> 4) + (tx >> 2)] = r2;
        }
    } else if (EPI == 2) {
        const int cb = col0 + (tx << 2);
        #pragma unroll
        for (int i = 0; i < 4; ++i) {
            int row = row0 + (ty << 2) + i;
            int b = row / M;
            const float* rw = extra + (size_t)b * HP + cb;
            float mth = fmaxf(fmaxf(acc[i][0] + rw[0], acc[i][1] + rw[1]),
                              fmaxf(acc[i][2] + rw[2], acc[i][3] + rw[3]));
            float r1 = fmaxf(mth, __shfl_xor(mth, 1));
            float r2 = fmaxf(r1, __shfl_xor(r1, 2));
            if ((tx & 3) == 0)
                C[(size_t)row * ldc + (col0 >> 4) + (tx >> 2)] = r2;
        }
    }
}

// ---------------- alpha (tier 3: fp32 m1) ----------------
__global__ __launch_bounds__(256) void k_alpha(
    const float* __restrict__ m1, const float* __restrict__ m2,
    const float* __restrict__ W12, const float* __restrict__ b12,
    const int* __restrict__ d_mask, float* __restrict__ alpha)
{
    __shared__ float Ws[16 * 512];
    const int tid = threadIdx.x;
    for (int i = tid; i < 16 * 512; i += 256) Ws[i] = W12[i];
    __syncthreads();
    const int wave = tid >> 6, lane = tid & 63;
    const int bm = blockIdx.x * 4 + wave;
    const float* r1 = m1 + (size_t)bm * H;
    const float* r2 = m2 + (size_t)bm * H;
    float acc[16] = {};
    #pragma unroll
    for (int q = 0; q < 4; ++q) {
        int k = lane + (q << 6);
        float x = r1[k];
        #pragma unroll
        for (int p = 0; p < 16; ++p) acc[p] += x * Ws[p * 512 + k];
    }
    #pragma unroll
    for (int q = 0; q < 4; ++q) {
        int k = lane + (q << 6);
        float x = r2[k];
        #pragma unroll
        for (int p = 0; p < 16; ++p) acc[p] += x * Ws[p * 512 + 256 + k];
    }
    #pragma unroll
    for (int p = 0; p < 16; ++p) {
        float v = acc[p];
        v += __shfl_xor(v, 1);  v += __shfl_xor(v, 2);  v += __shfl_xor(v, 4);
        v += __shfl_xor(v, 8);  v += __shfl_xor(v, 16); v += __shfl_xor(v, 32);
        acc[p] = v;
    }
    if (lane == 0) {
        float mx = -INFINITY;
        #pragma unroll
        for (int p = 0; p < 16; ++p) mx = fmaxf(mx, acc[p] + b12[p]);
        alpha[bm] = d_mask[bm] ? mx : -1e30f;
    }
}

// ---------------- alpha (tiers 15s/2: m1 fp16, m2 fp32; per-row mask skip) --------
__global__ __launch_bounds__(256) void k_alpha2(
    const _Float16* __restrict__ m1, const float* __restrict__ m2,
    const float* __restrict__ W12, const float* __restrict__ b12,
    const int* __restrict__ d_mask, float* __restrict__ alpha)
{
    __shared__ float Ws[16 * 512];
    const int tid = threadIdx.x;
    for (int i = tid; i < 16 * 512; i += 256) Ws[i] = W12[i];
    __syncthreads();                      // no barriers below (mask branch is safe)
    const int wave = tid >> 6, lane = tid & 63;
    const int bm = blockIdx.x * 4 + wave;
    if (!d_mask[bm]) {
        if (lane == 0) alpha[bm] = -1e30f;
        return;
    }
    const _Float16* r1 = m1 + (size_t)bm * H;
    const float* r2 = m2 + (size_t)bm * H;
    float acc[16] = {};
    #pragma unroll
    for (int q = 0; q < 4; ++q) {
        int k = lane + (q << 6);
        float x = (float)r1[k];
        #pragma unroll
        for (int p = 0; p < 16; ++p) acc[p] += x * Ws[p * 512 + k];
    }
    #pragma unroll
    for (int q = 0; q < 4; ++q) {
        int k = lane + (q << 6);
        float x = r2[k];
        #pragma unroll
        for (int p = 0; p < 16; ++p) acc[p] += x * Ws[p * 512 + 256 + k];
    }
    #pragma unroll
    for (int p = 0; p < 16; ++p) {
        float v = acc[p];
        v += __shfl_xor(v, 1);  v += __shfl_xor(v, 2);  v += __shfl_xor(v, 4);
        v += __shfl_xor(v, 8);  v += __shfl_xor(v, 16); v += __shfl_xor(v, 32);
        acc[p] = v;
    }
    if (lane == 0) {
        float mx = -INFINITY;
        #pragma unroll
        for (int p = 0; p < 16; ++p) mx = fmaxf(mx, acc[p] + b12[p]);
        alpha[bm] = mx;
    }
}

// ---------------- per-b: argmax + logsumexp + loss term ----------------
__global__ __launch_bounds__(256) void k_softmax(
    const float* __restrict__ alpha, const int* __restrict__ span, int phase,
    float* __restrict__ loss_term, int* __restrict__ idx_out)
{
    __shared__ float sv[256];
    __shared__ int si[256];
    const int b = blockIdx.x, tid = threadIdx.x;
    const float* row = alpha + b * M;
    float best = -INFINITY; int bidx = 0;
    for (int m = tid; m < M; m += 256) {
        float v = row[m];
        if (v > best) { best = v; bidx = m; }
    }
    sv[tid] = best; si[tid] = bidx;
    __syncthreads();
    for (int s = 128; s > 0; s >>= 1) {
        if (tid < s) {
            float v2 = sv[tid + s]; int i2 = si[tid + s];
            if (v2 > sv[tid] || (v2 == sv[tid] && i2 < si[tid])) { sv[tid] = v2; si[tid] = i2; }
        }
        __syncthreads();
    }
    float bmax = sv[0]; int amax = si[0];
    __syncthreads();
    float ps = 0.f;
    for (int m = tid; m < M; m += 256) ps += expf(row[m] - bmax);
    sv[tid] = ps;
    __syncthreads();
    for (int s = 128; s > 0; s >>= 1) {
        if (tid < s) sv[tid] += sv[tid + s];
        __syncthreads();
    }
    if (tid == 0) {
        float lse = bmax + logf(sv[0]);
        int tgt = span[b * 2 + phase];
        loss_term[b] = -(row[tgt] - lse);
        idx_out[b] = amax;
    }
}

// ---------------- sticky-mask pointer update + loss ----------------
__global__ void k_update(const int* __restrict__ idx_in, const float* __restrict__ loss_term,
                         int* __restrict__ pos, int* __restrict__ mask,
                         int* __restrict__ prun, float* __restrict__ loss_vec, int t)
{
    int b = threadIdx.x;
    int active = (b < B) ? 1 : 0;
    int ni = 0, nm = 0;
    if (active) {
        int id = idx_in[b];
        if (t == 0) { nm = 1; ni = id; }
        else {
            int om = mask[b];
            ni = id * om;
            int prev = pos[b] * om;
            nm = (ni != prev) ? 1 : 0;
        }
    }
    float v = active ? loss_term[b] : 0.f;
    #pragma unroll
    for (int off = 32; off > 0; off >>= 1) v += __shfl_xor(v, off);
    float S = v * (1.0f / (float)B);
    if (active) {
        pos[b] = ni;
        mask[b] = nm;
        if (nm) { prun[b] = ni; loss_vec[b] += S; }
    }
}

// ---------------- finalize ----------------
__global__ void k_finalize(const float* __restrict__ loss_vec, const int* __restrict__ p1r,
                           const int* __restrict__ p2r, float* __restrict__ out)
{
    int b = threadIdx.x;
    float v = (b < B) ? loss_vec[b] : 0.f;
    #pragma unroll
    for (int off = 32; off > 0; off >>= 1) v += __shfl_xor(v, off);
    if (b == 0) out[0] = v / (float)(B * TSTEPS);
    if (b < B) {
        out[1 + b] = (float)p1r[b];
        out[1 + B + b] = (float)p2r[b];
    }
}

}  // namespace

extern "C" void kernel_launch(void* const* d_in, const int* in_sizes, int n_in,
                              void* d_out, int out_size, void* d_ws, size_t ws_size,
                              hipStream_t stream)
{
    const float* U      = (const float*)d_in[0];
    const int*   d_mask = (const int*)d_in[1];
    const int*   span   = (const int*)d_in[2];
    const float* W_ih   = (const float*)d_in[3];
    const float* W_hh   = (const float*)d_in[4];
    const float* b_ih   = (const float*)d_in[5];
    const float* b_hh   = (const float*)d_in[6];
    const float* Ws_lin = (const float*)d_in[7];
    const float* Ws_m1  = (const float*)d_in[8];
    const float* bs_m1  = (const float*)d_in[9];
    const float* Ws_m2  = (const float*)d_in[10];
    const float* bs_m2  = (const float*)d_in[11];
    const float* Ws_m12 = (const float*)d_in[12];
    const float* bs_m12 = (const float*)d_in[13];
    const float* We_lin = (const float*)d_in[14];
    const float* We_m1  = (const float*)d_in[15];
    const float* be_m1  = (const float*)d_in[16];
    const float* We_m2  = (const float*)d_in[17];
    const float* be_m2  = (const float*)d_in[18];
    const float* We_m12 = (const float*)d_in[19];
    const float* be_m12 = (const float*)d_in[20];

    // ---- workspace layout ----
    float* ws = (float*)d_ws;
    size_t o = 0;
    float* m2b   = ws + o; o += (size_t)BM * H;
    float* alphab= ws + o; o += BM;
    float* u_cat = ws + o; o += B * FOURH;
    float* gbuf  = ws + o; o += B * FOURH;
    float* hbuf  = ws + o; o += B * H;
    float* cbuf  = ws + o; o += B * H;
    float* rbuf  = ws + o; o += B * H;
    float* rWb   = ws + o; o += B * HP;
    float* loss_term = ws + o; o += B;
    float* loss_vec  = ws + o; o += B;
    int* ib = (int*)(ws + o); o += 8 * B + 160;   // int block + 150 tile flags
    int* idxb   = ib + 0 * B;
    int* s_i    = ib + 1 * B;
    int* e_i    = ib + 2 * B;
    int* mask_s = ib + 3 * B;
    int* mask_e = ib + 4 * B;
    int* p1r    = ib + 5 * B;
    int* p2r    = ib + 6 * B;
    int* flags  = ib + 8 * B;
    size_t o_common = (o + 3) & ~(size_t)3;

    // tier 3 (fp32 fallback): m1b fp32
    float* m1b = ws + o_common;

    // tiers 15s/2: transposed rW weights + fp16 region
    size_t p = o_common;
    float* Wt_s = ws + p; p += (size_t)H * HP;
    float* Wt_e = ws + p; p += (size_t)H * HP;
    _Float16* hs = (_Float16*)(ws + p);
    size_t q = 0;
    _Float16* Uh  = hs + q; q += (size_t)BM * TWOH;
    _Float16* W1s = hs + q; q += (size_t)HP * TWOH;
    _Float16* W1e = hs + q; q += (size_t)HP * TWOH;
    _Float16* W2s = hs + q; q += (size_t)HP * H;
    _Float16* W2e = hs + q; q += (size_t)HP * H;
    _Float16* m1b16 = hs + q; q += (size_t)BM * H;
    q = (q + 7) & ~(size_t)7;
    const size_t need2 = p * sizeof(float) + q * sizeof(_Float16);
    _Float16* A_s16 = hs + q;                    // s-side only (157 MB)
    const size_t need15s = need2 + (size_t)BM * HP * sizeof(_Float16);

    const int tier = (ws_size >= need15s) ? 15 : (ws_size >= need2) ? 2 : 3;

    k_init<<<1, 256, 0, stream>>>(d_mask, hbuf, cbuf, loss_vec, s_i, e_i, p1r, p2r);

    if (tier <= 15) {
        // rebuild every call (ws re-poisoned by harness)
        k_flags<<<NTILES, 128, 0, stream>>>(d_mask, flags);
        k_cvtH<<<BM * TWOH / 4 / 256, 256, 0, stream>>>(U, TWOH, TWOH, Uh);
        k_cvtH<<<HP * TWOH / 4 / 256, 256, 0, stream>>>(Ws_m1, THREEH, TWOH, W1s);
        k_cvtH<<<HP * TWOH / 4 / 256, 256, 0, stream>>>(We_m1, THREEH, TWOH, W1e);
        k_cvtH<<<HP * H / 4 / 256, 256, 0, stream>>>(Ws_m2, H, H, W2s);
        k_cvtH<<<HP * H / 4 / 256, 256, 0, stream>>>(We_m2, H, H, W2e);
        k_transp<<<HP * H / 256, 256, 0, stream>>>(Ws_m1, Wt_s);
        k_transp<<<HP * H / 256, 256, 0, stream>>>(We_m1, Wt_e);

        dim3 gJ(HP / 128, NTILES);  // (32, 150)
        if (tier == 15) {
            // iteration-invariant A_s = U @ Ws_m1[:, :512].T, fp16 (157 MB).
            // Skipped tiles stay poison: benign finite fp16, flows only into masked rows.
            gemmJ<4><<<gJ, 256, 0, stream>>>(Uh, W1s, TWOH, nullptr, flags, nullptr, A_s16);
        }

        for (int t = 0; t < TSTEPS; ++t) {
            k_gather<<<64, 256, 0, stream>>>(U, s_i, e_i, u_cat);
            k_lstm_gemm<<<128, 256, 0, stream>>>(u_cat, hbuf, W_ih, W_hh, b_ih, b_hh, gbuf);
            k_lstm_gates<<<32, 256, 0, stream>>>(gbuf, hbuf, cbuf);

            // ---- start pointer ----
            k_r<<<32, 256, 0, stream>>>(hbuf, u_cat, Ws_lin, rbuf);
            k_rW2<<<dim3(HP / 256, B), 256, 0, stream>>>(rbuf, Wt_s, bs_m1, rWb);
            if (tier == 15)
                k_m1A16<<<BM * H / 256, 256, 0, stream>>>(A_s16, rWb, m1b16);
            else
                gemmJ<3><<<gJ, 256, 0, stream>>>(Uh, W1s, TWOH, rWb, flags, nullptr, m1b16);
            gemmJ<1><<<gJ, 256, 0, stream>>>(m1b16, W2s, H, bs_m2, flags, m2b, nullptr);
            k_alpha2<<<BM / 4, 256, 0, stream>>>(m1b16, m2b, Ws_m12, bs_m12, d_mask, alphab);
            k_softmax<<<B, 256, 0, stream>>>(alphab, span, 0, loss_term, idxb);
            k_update<<<1, 64, 0, stream>>>(idxb, loss_term, s_i, mask_s, p1r, loss_vec, t);

            k_gather<<<64, 256, 0, stream>>>(U, s_i, e_i, u_cat);

            // ---- end pointer ----
            k_r<<<32, 256, 0, stream>>>(hbuf, u_cat, We_lin, rbuf);
            k_rW2<<<dim3(HP / 256, B), 256, 0, stream>>>(rbuf, Wt_e, be_m1, rWb);
            gemmJ<3><<<gJ, 256, 0, stream>>>(Uh, W1e, TWOH, rWb, flags, nullptr, m1b16);
            gemmJ<1><<<gJ, 256, 0, stream>>>(m1b16, W2e, H, be_m2, flags, m2b, nullptr);
            k_alpha2<<<BM / 4, 256, 0, stream>>>(m1b16, m2b, We_m12, be_m12, d_mask, alphab);
            k_softmax<<<B, 256, 0, stream>>>(alphab, span, 1, loss_term, idxb);
            k_update<<<1, 64, 0, stream>>>(idxb, loss_term, e_i, mask_e, p2r, loss_vec, t);
        }
    } else {
        // ---- tier 3: round-2 fp32 path (known-pass) ----
        dim3 gemm_grid(HP / 64, BM / 64);
        for (int t = 0; t < TSTEPS; ++t) {
            k_gather<<<64, 256, 0, stream>>>(U, s_i, e_i, u_cat);
            k_lstm_gemm<<<128, 256, 0, stream>>>(u_cat, hbuf, W_ih, W_hh, b_ih, b_hh, gbuf);
            k_lstm_gates<<<32, 256, 0, stream>>>(gbuf, hbuf, cbuf);

            k_r<<<32, 256, 0, stream>>>(hbuf, u_cat, Ws_lin, rbuf);
            k_rW<<<512, 256, 0, stream>>>(rbuf, Ws_m1, bs_m1, rWb);
            gemm64<2><<<gemm_grid, 256, 0, stream>>>(U, TWOH, Ws_m1, THREEH, rWb, m1b, TWOH, H);
            gemm64<1><<<gemm_grid, 256, 0, stream>>>(m1b, H, Ws_m2, H, bs_m2, m2b, H, H);
            k_alpha<<<BM / 4, 256, 0, stream>>>(m1b, m2b, Ws_m12, bs_m12, d_mask, alphab);
            k_softmax<<<B, 256, 0, stream>>>(alphab, span, 0, loss_term, idxb);
            k_update<<<1, 64, 0, stream>>>(idxb, loss_term, s_i, mask_s, p1r, loss_vec, t);

            k_gather<<<64, 256, 0, stream>>>(U, s_i, e_i, u_cat);

            k_r<<<32, 256, 0, stream>>>(hbuf, u_cat, We_lin, rbuf);
            k_rW<<<512, 256, 0, stream>>>(rbuf, We_m1, be_m1, rWb);
            gemm64<2><<<gemm_grid, 256, 0, stream>>>(U, TWOH, We_m1, THREEH, rWb, m1b, TWOH, H);
            gemm64<1><<<gemm_grid, 256, 0, stream>>>(m1b, H, We_m2, H, be_m2, m2b, H, H);
            k_alpha<<<BM / 4, 256, 0, stream>>>(m1b, m2b, We_m12, be_m12, d_mask, alphab);
            k_softmax<<<B, 256, 0, stream>>>(alphab, span, 1, loss_term, idxb);
            k_update<<<1, 64, 0, stream>>>(idxb, loss_term, e_i, mask_e, p2r, loss_vec, t);
        }
    }

    k_finalize<<<1, 64, 0, stream>>>(loss_vec, p1r, p2r, (float*)d_out);
}